// Round 10
// baseline (1028.075 us; speedup 1.0000x reference)
//
#include <hip/hip_runtime.h>
#include <hip/hip_bf16.h>
#include <cstdint>

#define B_    2
#define S_    1024
#define H_    2048
#define NH_   32
#define NKV_  8
#define HD_   64
#define T_    (B_*S_)
#define E_    16
#define ED_   1024
#define TOPK_ 4
#define WIN_  128
#define LIMIT_ 7.0f
#define ALPHA_ 1.702f
#define EPS_   1e-6f
#define SCALE_ 0.125f  /* HD^-0.5 */
#define SPLIT_ 2048.0f
#define INV_SPLIT_ 4.8828125e-4f
#define MAXT_ 48      /* max MoE row-tiles of 256: 32 + 16 */

typedef _Float16 half8 __attribute__((ext_vector_type(8)));
typedef _Float16 half4v __attribute__((ext_vector_type(4)));
typedef float floatx4 __attribute__((ext_vector_type(4)));

#define MF16(a,b,c) __builtin_amdgcn_mfma_f32_16x16x32_f16(a,b,c,0,0,0)

__device__ __forceinline__ void gload16(const void* g, void* l) {
    __builtin_amdgcn_global_load_lds((const __attribute__((address_space(1))) void*)g,
                                     (__attribute__((address_space(3))) void*)l, 16, 0, 0);
}

// bijective chunked XCD swizzle (nwg % 8 == 0)
__device__ __forceinline__ int xcd_swz(int bid, int nwg) {
    int cpx = nwg >> 3;
    return (bid & 7) * cpx + (bid >> 3);
}

// ================= C init: C = bias (+res) =================
__global__ __launch_bounds__(256) void k_initc(const float* __restrict__ bias,
                                               const float* __restrict__ res,
                                               float* __restrict__ C, int N, int n4) {
    int i = blockIdx.x * 256 + threadIdx.x;
    if (i >= n4) return;
    int c4 = (i % (N >> 2)) << 2;
    float4 v = *(const float4*)(bias + c4);
    if (res) {
        float4 r = ((const float4*)res)[i];
        v.x += r.x; v.y += r.y; v.z += r.z; v.w += r.w;
    }
    ((float4*)C)[i] = v;
}

// ===== split-fp16 GEMM, split-K=4, double-buffered LDS + counted vmcnt =====
__global__ __launch_bounds__(256) void k_gemm_spk(const _Float16* __restrict__ Ah,
                                                  const _Float16* __restrict__ Al,
                                                  const _Float16* __restrict__ Bh,
                                                  const _Float16* __restrict__ Bl,
                                                  float* __restrict__ C, int N, int K) {
    __shared__ _Float16 Ahs[2][128 * 32];
    __shared__ _Float16 Als[2][128 * 32];
    __shared__ _Float16 Bhs[2][128 * 32];
    __shared__ _Float16 Bls[2][128 * 32];
    const int tid = threadIdx.x;
    const int lane = tid & 63;
    const int wid = tid >> 6;
    const int wr = wid >> 1, wc = wid & 1;
    const int wg = xcd_swz(blockIdx.x, gridDim.x);
    const int col0 = (wg >> 6) * 128;
    const int row0 = ((wg & 63) >> 2) * 128;
    const int ks4 = wg & 3;
    const int kbeg = ks4 * (K >> 2), kend = kbeg + (K >> 2);
    floatx4 acc1[4][4], acc2[4][4];
    for (int m = 0; m < 4; ++m)
        for (int n = 0; n < 4; ++n) { acc1[m][n] = (floatx4)0.f; acc2[m][n] = (floatx4)0.f; }
    const int rL = tid >> 2, koff = (tid & 3) * 8;
    const size_t o0 = (size_t)(row0 + rL) * K + koff;
    const size_t o1 = (size_t)(row0 + 64 + rL) * K + koff;
    const size_t p0 = (size_t)(col0 + rL) * K + koff;
    const size_t p1 = (size_t)(col0 + 64 + rL) * K + koff;
#define DSTAGE(buf, kk) do { \
        gload16(Ah + o0 + (kk), Ahs[buf] + tid * 8); gload16(Ah + o1 + (kk), Ahs[buf] + 2048 + tid * 8); \
        gload16(Al + o0 + (kk), Als[buf] + tid * 8); gload16(Al + o1 + (kk), Als[buf] + 2048 + tid * 8); \
        gload16(Bh + p0 + (kk), Bhs[buf] + tid * 8); gload16(Bh + p1 + (kk), Bhs[buf] + 2048 + tid * 8); \
        gload16(Bl + p0 + (kk), Bls[buf] + tid * 8); gload16(Bl + p1 + (kk), Bls[buf] + 2048 + tid * 8); \
    } while (0)
    DSTAGE(0, kbeg);
    int cur = 0;
    for (int k0 = kbeg; k0 < kend; k0 += 32) {
        if (k0 + 32 < kend) {
            DSTAGE(cur ^ 1, k0 + 32);
            asm volatile("s_waitcnt vmcnt(8)" ::: "memory");
        } else {
            asm volatile("s_waitcnt vmcnt(0)" ::: "memory");
        }
        __builtin_amdgcn_s_barrier();
        __builtin_amdgcn_sched_barrier(0);
        const int lk = (lane >> 4) * 8;
        half8 ah[4], al[4], bh[4], bl[4];
#pragma unroll
        for (int m = 0; m < 4; ++m) {
            int ro = (wr * 64 + m * 16 + (lane & 15)) * 32 + lk;
            ah[m] = *(const half8*)&Ahs[cur][ro];
            al[m] = *(const half8*)&Als[cur][ro];
        }
#pragma unroll
        for (int n = 0; n < 4; ++n) {
            int ro = (wc * 64 + n * 16 + (lane & 15)) * 32 + lk;
            bh[n] = *(const half8*)&Bhs[cur][ro];
            bl[n] = *(const half8*)&Bls[cur][ro];
        }
#pragma unroll
        for (int m = 0; m < 4; ++m)
#pragma unroll
            for (int n = 0; n < 4; ++n) {
                acc1[m][n] = MF16(ah[m], bh[n], acc1[m][n]);
                acc2[m][n] = MF16(ah[m], bl[n], acc2[m][n]);
                acc2[m][n] = MF16(al[m], bh[n], acc2[m][n]);
            }
        __builtin_amdgcn_sched_barrier(0);
        __builtin_amdgcn_s_barrier();
        cur ^= 1;
    }
#undef DSTAGE
#pragma unroll
    for (int mf = 0; mf < 4; ++mf)
#pragma unroll
        for (int i = 0; i < 4; ++i) {
            int r = row0 + wr * 64 + mf * 16 + ((lane >> 4) << 2) + i;
#pragma unroll
            for (int nf = 0; nf < 4; ++nf) {
                int c = col0 + wc * 64 + nf * 16 + (lane & 15);
                atomicAdd(&C[(size_t)r * N + c], acc1[mf][nf][i] + acc2[mf][nf][i] * INV_SPLIT_);
            }
        }
}

// ====== MoE 256x256 8-wave 8-phase core (BK=64, chunk-XOR LDS, counted vmcnt) ======
// Wave tile 128x64 (2x4 waves). Per K-tile 4 phases; staging order S1..S4 matched
// to read order so vmcnt(6) provably covers every ds_read (3-phase pipeline gap).
#define MOE8_PROLOG() \
    __shared__ _Float16 As[2][16384]; \
    __shared__ _Float16 Bs[2][16384]; \
    const int tid = threadIdx.x; \
    const int lane = tid & 63; \
    const int wid = tid >> 6; \
    const int wr = wid >> 2, wc = wid & 3; \
    const int l15 = lane & 15, g = lane >> 4; \
    const int rr = tid >> 3, cc8 = tid & 7; \
    const int ksw = (cc8 ^ (rr & 7)) * 8; \
    const int brow = (rr & 31) + 64 * (rr >> 5); \
    floatx4 acc[8][4]; \
    _Pragma("unroll") for (int m = 0; m < 8; ++m) \
        _Pragma("unroll") for (int n = 0; n < 4; ++n) acc[m][n] = (floatx4)0.f;

// staging: 2 gloads each. A rows {rr,rr+128}(S1) {rr+64,rr+192}(S4);
// B rows {brow,brow+128}(S2) {brow+32,brow+160}(S3)
#define ST1(bf, kk) { gload16(asrc[0] + (kk), As[bf] + rr * 64 + cc8 * 8); \
                      gload16(asrc[2] + (kk), As[bf] + 8192 + rr * 64 + cc8 * 8); }
#define ST2(bf, kk) { gload16(bsrc[0] + (kk), Bs[bf] + brow * 64 + cc8 * 8); \
                      gload16(bsrc[1] + (kk), Bs[bf] + 8192 + brow * 64 + cc8 * 8); }
#define ST3(bf, kk) { gload16(bsrc[2] + (kk), Bs[bf] + 2048 + brow * 64 + cc8 * 8); \
                      gload16(bsrc[3] + (kk), Bs[bf] + 10240 + brow * 64 + cc8 * 8); }
#define ST4(bf, kk) { gload16(asrc[1] + (kk), As[bf] + 4096 + rr * 64 + cc8 * 8); \
                      gload16(asrc[3] + (kk), As[bf] + 12288 + rr * 64 + cc8 * 8); }

#define RD_A(dst, mf, ks) { int ra = wr * 128 + (mf) * 16 + l15; \
    dst = *(const half8*)&As[cur][ra * 64 + ((g + 4 * (ks)) ^ (ra & 7)) * 8]; }
#define RD_B(dst, nf, ks) { int rb = wc * 64 + (nf) * 16 + l15; \
    dst = *(const half8*)&Bs[cur][rb * 64 + ((g + 4 * (ks)) ^ (rb & 7)) * 8]; }

#define PH_SYNC() __builtin_amdgcn_s_barrier(); __builtin_amdgcn_sched_barrier(0);
#define PRIO_MFMA_BEG() __builtin_amdgcn_s_setprio(1);
#define PRIO_MFMA_END() __builtin_amdgcn_s_setprio(0); __builtin_amdgcn_sched_barrier(0);

#define MOE8_KLOOP(KD) \
    ST1(0, 0); ST2(0, 0); ST3(0, 0); ST4(0, 0); \
    asm volatile("s_waitcnt vmcnt(0)" ::: "memory"); \
    __builtin_amdgcn_s_barrier(); \
    const int nt = (KD) / 64; \
    for (int t = 0; t < nt; ++t) { \
        const int cur = t & 1, nxt = cur ^ 1; \
        const int kn = (t + 1) * 64; \
        const bool more = (t + 1 < nt); \
        half8 a[4][2], b0[2][2], b1[2][2]; \
        /* phase 1: reads a0(S1) b0(S2) */ \
        if (more) { ST1(nxt, kn); asm volatile("s_waitcnt vmcnt(6)" ::: "memory"); } \
        else      { asm volatile("s_waitcnt vmcnt(4)" ::: "memory"); } \
        PH_SYNC(); \
        _Pragma("unroll") for (int m = 0; m < 4; ++m) \
            _Pragma("unroll") for (int k = 0; k < 2; ++k) RD_A(a[m][k], m, k); \
        _Pragma("unroll") for (int n = 0; n < 2; ++n) \
            _Pragma("unroll") for (int k = 0; k < 2; ++k) RD_B(b0[n][k], n, k); \
        PRIO_MFMA_BEG(); \
        _Pragma("unroll") for (int m = 0; m < 4; ++m) \
            _Pragma("unroll") for (int n = 0; n < 2; ++n) \
                _Pragma("unroll") for (int k = 0; k < 2; ++k) \
                    acc[m][n] = MF16(a[m][k], b0[n][k], acc[m][n]); \
        PRIO_MFMA_END(); \
        /* phase 2: reads b1(S3) */ \
        if (more) { ST2(nxt, kn); asm volatile("s_waitcnt vmcnt(6)" ::: "memory"); } \
        else      { asm volatile("s_waitcnt vmcnt(2)" ::: "memory"); } \
        PH_SYNC(); \
        _Pragma("unroll") for (int n = 0; n < 2; ++n) \
            _Pragma("unroll") for (int k = 0; k < 2; ++k) RD_B(b1[n][k], 2 + n, k); \
        PRIO_MFMA_BEG(); \
        _Pragma("unroll") for (int m = 0; m < 4; ++m) \
            _Pragma("unroll") for (int n = 0; n < 2; ++n) \
                _Pragma("unroll") for (int k = 0; k < 2; ++k) \
                    acc[m][2 + n] = MF16(a[m][k], b1[n][k], acc[m][2 + n]); \
        PRIO_MFMA_END(); \
        /* phase 3: reads a1(S4), overwrite a regs */ \
        if (more) { ST3(nxt, kn); asm volatile("s_waitcnt vmcnt(6)" ::: "memory"); } \
        else      { asm volatile("s_waitcnt vmcnt(0)" ::: "memory"); } \
        PH_SYNC(); \
        _Pragma("unroll") for (int m = 0; m < 4; ++m) \
            _Pragma("unroll") for (int k = 0; k < 2; ++k) RD_A(a[m][k], 4 + m, k); \
        PRIO_MFMA_BEG(); \
        _Pragma("unroll") for (int m = 0; m < 4; ++m) \
            _Pragma("unroll") for (int n = 0; n < 2; ++n) \
                _Pragma("unroll") for (int k = 0; k < 2; ++k) \
                    acc[4 + m][2 + n] = MF16(a[m][k], b1[n][k], acc[4 + m][2 + n]); \
        PRIO_MFMA_END(); \
        /* phase 4: no reads */ \
        if (more) { ST4(nxt, kn); asm volatile("s_waitcnt vmcnt(6)" ::: "memory"); } \
        PH_SYNC(); \
        PRIO_MFMA_BEG(); \
        _Pragma("unroll") for (int m = 0; m < 4; ++m) \
            _Pragma("unroll") for (int n = 0; n < 2; ++n) \
                _Pragma("unroll") for (int k = 0; k < 2; ++k) \
                    acc[4 + m][n] = MF16(a[m][k], b0[n][k], acc[4 + m][n]); \
        PRIO_MFMA_END(); \
        __builtin_amdgcn_s_barrier(); \
    }

// MoE GEMM1: 256-row tile table; gathered A rows; fused GLU -> gated f16
__global__ __launch_bounds__(512, 2) void k_moe1(const _Float16* __restrict__ X,
                                                 const _Float16* __restrict__ W,
                                                 const float* __restrict__ bias,
                                                 const int* __restrict__ perm,
                                                 const int* __restrict__ counts,
                                                 const int* __restrict__ offs,
                                                 const int* __restrict__ te,
                                                 const int* __restrict__ tm,
                                                 const int* __restrict__ ntt,
                                                 _Float16* __restrict__ gated) {
    const int wg = xcd_swz(blockIdx.x, MAXT_ * 8);
    const int tt = wg >> 3;
    if (tt >= ntt[0]) return;
    const int e = te[tt];
    const int m0 = tm[tt];
    const int ne = counts[e];
    const int base = offs[e];
    const int col0 = (wg & 7) * 256;
    MOE8_PROLOG();
    const _Float16* asrc[4];
    const _Float16* bsrc[4];
#pragma unroll
    for (int i = 0; i < 4; ++i) {
        int tok = perm[base + min(m0 + rr + 64 * i, ne - 1)];
        asrc[i] = X + (size_t)tok * H_ + ksw;
    }
    {
        const int boff[4] = {0, 128, 32, 160};
#pragma unroll
        for (int i = 0; i < 4; ++i)
            bsrc[i] = W + ((size_t)e * 2048 + col0 + brow + boff[i]) * H_ + ksw;
    }
    MOE8_KLOOP(H_);
#pragma unroll
    for (int mf = 0; mf < 8; ++mf)
#pragma unroll
        for (int i = 0; i < 4; ++i) {
            int r = m0 + wr * 128 + mf * 16 + g * 4 + i;
            bool ok = r < ne;
            int slot = base + r;
#pragma unroll
            for (int nf = 0; nf < 4; ++nf) {
                int c = col0 + wc * 64 + nf * 16 + l15;
                float v = acc[mf][nf][i] + bias[e * 2048 + c];
                float o = __shfl_xor(v, 1);
                if (ok && !(lane & 1)) {
                    float gt = fminf(v, LIMIT_);
                    float up = fminf(fmaxf(o, -LIMIT_), LIMIT_);
                    float sg = 1.f / (1.f + __expf(-ALPHA_ * gt));
                    gated[(size_t)slot * ED_ + (c >> 1)] = (_Float16)((up + 1.f) * (gt * sg));
                }
            }
        }
}

__global__ __launch_bounds__(512, 2) void k_moe2(const _Float16* __restrict__ G,
                                                 const _Float16* __restrict__ W,
                                                 const float* __restrict__ bias,
                                                 const int* __restrict__ perm,
                                                 const float* __restrict__ pw,
                                                 const int* __restrict__ counts,
                                                 const int* __restrict__ offs,
                                                 const int* __restrict__ te,
                                                 const int* __restrict__ tm,
                                                 const int* __restrict__ ntt,
                                                 float* __restrict__ out) {
    const int wg = xcd_swz(blockIdx.x, MAXT_ * 8);
    const int tt = wg >> 3;
    if (tt >= ntt[0]) return;
    const int e = te[tt];
    const int m0 = tm[tt];
    const int ne = counts[e];
    const int base = offs[e];
    const int col0 = (wg & 7) * 256;
    MOE8_PROLOG();
    const _Float16* asrc[4];
    const _Float16* bsrc[4];
#pragma unroll
    for (int i = 0; i < 4; ++i) {
        int s = base + min(m0 + rr + 64 * i, ne - 1);
        asrc[i] = G + (size_t)s * ED_ + ksw;
    }
    {
        const int boff[4] = {0, 128, 32, 160};
#pragma unroll
        for (int i = 0; i < 4; ++i)
            bsrc[i] = W + ((size_t)e * H_ + col0 + brow + boff[i]) * ED_ + ksw;
    }
    MOE8_KLOOP(ED_);
#pragma unroll
    for (int mf = 0; mf < 8; ++mf)
#pragma unroll
        for (int i = 0; i < 4; ++i) {
            int r = m0 + wr * 128 + mf * 16 + g * 4 + i;
            if (r >= ne) continue;
            int slot = base + r;
            int tok = perm[slot];
            float wgt = pw[slot];
#pragma unroll
            for (int nf = 0; nf < 4; ++nf) {
                int c = col0 + wc * 64 + nf * 16 + l15;
                atomicAdd(&out[(size_t)tok * H_ + c], wgt * (acc[mf][nf][i] + bias[e * H_ + c]));
            }
        }
}

// ================= conversions =================
__global__ __launch_bounds__(256) void k_cvts(const float* __restrict__ s,
                                              _Float16* __restrict__ dh,
                                              _Float16* __restrict__ dl, int n8) {
    int i = blockIdx.x * 256 + threadIdx.x;
    if (i >= n8) return;
    float4 x = ((const float4*)s)[i * 2], y = ((const float4*)s)[i * 2 + 1];
    float xs[8] = {x.x, x.y, x.z, x.w, y.x, y.y, y.z, y.w};
    half8 h, l;
#pragma unroll
    for (int j = 0; j < 8; ++j) {
        _Float16 hv = (_Float16)xs[j];
        h[j] = hv;
        l[j] = (_Float16)((xs[j] - (float)hv) * SPLIT_);
    }
    ((half8*)dh)[i] = h;
    ((half8*)dl)[i] = l;
}

__global__ __launch_bounds__(256) void k_cvt_t(const float* __restrict__ src,
                                               _Float16* __restrict__ dst, int K, int N) {
    const int e = blockIdx.z;
    const int k0 = blockIdx.x * 32, n0 = blockIdx.y * 32;
    __shared__ float t[32][33];
    const int tid = threadIdx.x;
    {
        int kr = tid >> 3, nc = (tid & 7) * 4;
        float4 v = *(const float4*)(src + ((size_t)e * K + k0 + kr) * N + n0 + nc);
        t[kr][nc] = v.x; t[kr][nc + 1] = v.y; t[kr][nc + 2] = v.z; t[kr][nc + 3] = v.w;
    }
    __syncthreads();
    {
        int nr = tid >> 3, kc = (tid & 7) * 4;
        half4v o;
        o[0] = (_Float16)t[kc + 0][nr];
        o[1] = (_Float16)t[kc + 1][nr];
        o[2] = (_Float16)t[kc + 2][nr];
        o[3] = (_Float16)t[kc + 3][nr];
        *(half4v*)(dst + ((size_t)e * N + n0 + nr) * K + k0 + kc) = o;
    }
}

// v transpose-split: vbuf fp32 [b][s][kvh][64] -> vth/vtl [b][kvh][64 d][1024 s]
__global__ __launch_bounds__(256) void k_cvt_vt(const float* __restrict__ vbuf,
                                                _Float16* __restrict__ vth,
                                                _Float16* __restrict__ vtl) {
    const int s0 = blockIdx.x * 32, d0 = blockIdx.y * 32;
    const int bk = blockIdx.z;
    const int b = bk >> 3, kvh = bk & 7;
    __shared__ float tl[32][33];
    const int tid = threadIdx.x;
    {
        int sr = tid >> 3, dc = (tid & 7) * 4;
        float4 v = *(const float4*)(vbuf + (size_t)(b * 1024 + s0 + sr) * 512 + kvh * 64 + d0 + dc);
        tl[sr][dc] = v.x; tl[sr][dc + 1] = v.y; tl[sr][dc + 2] = v.z; tl[sr][dc + 3] = v.w;
    }
    __syncthreads();
    {
        int dr = tid >> 3, sc = (tid & 7) * 4;
        half4v h4, l4;
#pragma unroll
        for (int j = 0; j < 4; ++j) {
            float x = tl[sc + j][dr];
            _Float16 hv = (_Float16)x;
            h4[j] = hv;
            l4[j] = (_Float16)((x - (float)hv) * SPLIT_);
        }
        size_t dst = (size_t)(bk * 64 + d0 + dr) * 1024 + s0 + sc;
        *(half4v*)(vth + dst) = h4;
        *(half4v*)(vtl + dst) = l4;
    }
}

// ================= RMSNorm (fp32 + split f16 outputs) =================
__global__ __launch_bounds__(256) void k_rmsnorm(const float* __restrict__ x,
                                                 const float* __restrict__ w,
                                                 float* __restrict__ y,
                                                 _Float16* __restrict__ yh,
                                                 _Float16* __restrict__ yl) {
    int t = blockIdx.x;
    const float* row = x + (size_t)t * H_;
    float ss = 0.f;
    for (int i = threadIdx.x; i < H_ / 4; i += 256) {
        float4 v = ((const float4*)row)[i];
        ss += v.x * v.x + v.y * v.y + v.z * v.z + v.w * v.w;
    }
    for (int o = 32; o >= 1; o >>= 1) ss += __shfl_xor(ss, o);
    __shared__ float wsum[4];
    if ((threadIdx.x & 63) == 0) wsum[threadIdx.x >> 6] = ss;
    __syncthreads();
    float tot = wsum[0] + wsum[1] + wsum[2] + wsum[3];
    float r = rsqrtf(tot / (float)H_ + EPS_);
    float* yrow = y + (size_t)t * H_;
    _Float16* hrow = yh + (size_t)t * H_;
    _Float16* lrow = yl + (size_t)t * H_;
    for (int i = threadIdx.x; i < H_ / 4; i += 256) {
        float4 v = ((const float4*)row)[i];
        float4 g = ((const float4*)w)[i];
        float o4[4];
        o4[0] = v.x * r * g.x; o4[1] = v.y * r * g.y;
        o4[2] = v.z * r * g.z; o4[3] = v.w * r * g.w;
        ((float4*)yrow)[i] = *(float4*)o4;
        half4v h4, l4;
#pragma unroll
        for (int j = 0; j < 4; ++j) {
            _Float16 hv = (_Float16)o4[j];
            h4[j] = hv;
            l4[j] = (_Float16)((o4[j] - (float)hv) * SPLIT_);
        }
        ((half4v*)hrow)[i] = h4;
        ((half4v*)lrow)[i] = l4;
    }
}

// ================= RoPE -> head-major split q/k =================
__global__ __launch_bounds__(256) void k_rope_sp(const float* __restrict__ qbuf,
                                                 const float* __restrict__ kbuf,
                                                 const float* __restrict__ cs,
                                                 const float* __restrict__ sn,
                                                 _Float16* __restrict__ qh, _Float16* __restrict__ ql,
                                                 _Float16* __restrict__ kh, _Float16* __restrict__ kl) {
    int t = blockIdx.x;
    int b = t >> 10, s = t & 1023;
    size_t cb = (size_t)t * 64;
    for (int p = threadIdx.x; p < 40 * 32; p += 256) {
        int head = p >> 5, d = p & 31;
        float c1 = cs[cb + d],      s1v = sn[cb + d];
        float c2 = cs[cb + d + 32], s2v = sn[cb + d + 32];
        float x1, x2; size_t dst;
        _Float16 *oh, *ol;
        if (head < 32) {
            const float* src = qbuf + (size_t)t * 2048 + head * 64;
            x1 = src[d]; x2 = src[d + 32];
            dst = (((size_t)b * 32 + head) * 1024 + s) * 64 + d;
            oh = qh; ol = ql;
        } else {
            int hk = head - 32;
            const float* src = kbuf + (size_t)t * 512 + hk * 64;
            x1 = src[d]; x2 = src[d + 32];
            dst = (((size_t)b * 8 + hk) * 1024 + s) * 64 + d;
            oh = kh; ol = kl;
        }
        float r1 = x1 * c1 - x2 * s1v;
        float r2 = x2 * c2 + x1 * s2v;
        _Float16 h1 = (_Float16)r1;
        oh[dst] = h1; ol[dst] = (_Float16)((r1 - (float)h1) * SPLIT_);
        _Float16 h2 = (_Float16)r2;
        oh[dst + 32] = h2; ol[dst + 32] = (_Float16)((r2 - (float)h2) * SPLIT_);
    }
}

// ================= MFMA flash attention (split-fp16, fp32-accurate) ===========
#define PPITCH 68
union U8h { unsigned w[4]; half8 v; };

__global__ __launch_bounds__(256, 1) void k_attn_m(
        const _Float16* __restrict__ qhg, const _Float16* __restrict__ qlg,
        const _Float16* __restrict__ khg, const _Float16* __restrict__ klg,
        const _Float16* __restrict__ vthg, const _Float16* __restrict__ vtlg,
        const float* __restrict__ sinks,
        _Float16* __restrict__ ath, _Float16* __restrict__ atl) {
    __shared__ _Float16 Khs[4096], Kls[4096], Vhs[4096], Vls[4096];
    __shared__ unsigned Pp[4][64 * PPITCH];
    const int bx = blockIdx.x;
    const int b = bx >> 7, kvh = (bx >> 4) & 7, tile = bx & 15;
    const int i0 = tile * 64;
    const int tid = threadIdx.x, lane = tid & 63, wid = tid >> 6;
    const int l15 = lane & 15, g = lane >> 4;
    const int h = kvh * 4 + wid;
    const size_t kvbase = (size_t)(b * 8 + kvh) * 1024 * 64;
    const size_t vbase  = (size_t)(b * 8 + kvh) * 64 * 1024;
    half8 aqh[4][2], aql[4][2];
    {
        const size_t qb0 = ((size_t)(b * 32 + h) * 1024 + i0) * 64;
#pragma unroll
        for (int mf = 0; mf < 4; ++mf)
#pragma unroll
            for (int ks = 0; ks < 2; ++ks) {
                size_t a = qb0 + (size_t)(16 * mf + l15) * 64 + ks * 32 + g * 8;
                aqh[mf][ks] = *(const half8*)(qhg + a);
                aql[mf][ks] = *(const half8*)(qlg + a);
            }
    }
    floatx4 o1[4][4], o2[4][4];
    float m_run[4][4], l_run[4][4];
#pragma unroll
    for (int mf = 0; mf < 4; ++mf)
#pragma unroll
        for (int x = 0; x < 4; ++x) {
            o1[mf][x] = (floatx4)0.f; o2[mf][x] = (floatx4)0.f;
            m_run[mf][x] = -1e20f; l_run[mf][x] = 0.f;
        }
    const int nch = tile >= 2 ? 3 : tile + 1;
    const int jr = tid >> 3, cc = tid & 7;
    unsigned* pw = &Pp[wid][0];
    for (int ci = 0; ci < nch; ++ci) {
        const int jb = i0 - 64 * (nch - 1 - ci);
        __syncthreads();
        {
            const int sw0 = (cc ^ (jr & 7)) * 8;
            const size_t k0 = kvbase + (size_t)(jb + jr) * 64 + sw0;
            const size_t k1 = kvbase + (size_t)(jb + jr + 32) * 64 + sw0;
            gload16(khg + k0, Khs + tid * 8);
            gload16(khg + k1, Khs + 2048 + tid * 8);
            gload16(klg + k0, Kls + tid * 8);
            gload16(klg + k1, Kls + 2048 + tid * 8);
            const size_t v0 = vbase + (size_t)jr * 1024 + jb + sw0;
            const size_t v1 = vbase + (size_t)(jr + 32) * 1024 + jb + sw0;
            gload16(vthg + v0, Vhs + tid * 8);
            gload16(vthg + v1, Vhs + 2048 + tid * 8);
            gload16(vtlg + v0, Vls + tid * 8);
            gload16(vtlg + v1, Vls + 2048 + tid * 8);
        }
        __syncthreads();
        floatx4 s1[4][4], s2[4][4];
#pragma unroll
        for (int mf = 0; mf < 4; ++mf)
#pragma unroll
            for (int nf = 0; nf < 4; ++nf) { s1[mf][nf] = (floatx4)0.f; s2[mf][nf] = (floatx4)0.f; }
#pragma unroll
        for (int ks = 0; ks < 2; ++ks) {
            half8 kbh[4], kbl[4];
#pragma unroll
            for (int nf = 0; nf < 4; ++nf) {
                int j = l15 + 16 * nf;
                int c = (g + 4 * ks) ^ (j & 7);
                kbh[nf] = *(const half8*)&Khs[j * 64 + c * 8];
                kbl[nf] = *(const half8*)&Kls[j * 64 + c * 8];
            }
#pragma unroll
            for (int mf = 0; mf < 4; ++mf)
#pragma unroll
                for (int nf = 0; nf < 4; ++nf) {
                    s1[mf][nf] = MF16(aqh[mf][ks], kbh[nf], s1[mf][nf]);
                    s2[mf][nf] = MF16(aqh[mf][ks], kbl[nf], s2[mf][nf]);
                    s2[mf][nf] = MF16(aql[mf][ks], kbh[nf], s2[mf][nf]);
                }
        }
#pragma unroll
        for (int mf = 0; mf < 4; ++mf)
#pragma unroll
            for (int reg = 0; reg < 4; ++reg) {
                int i = i0 + 16 * mf + g * 4 + reg;
                float best = -1e30f;
#pragma unroll
                for (int nf = 0; nf < 4; ++nf) {
                    int j = jb + 16 * nf + l15;
                    float sv = (s1[mf][nf][reg] + s2[mf][nf][reg] * INV_SPLIT_) * SCALE_;
                    bool ok = (j <= i) && (i - j < WIN_);
                    sv = ok ? sv : -1e30f;
                    s1[mf][nf][reg] = sv;
                    best = fmaxf(best, sv);
                }
                for (int off = 1; off < 16; off <<= 1) best = fmaxf(best, __shfl_xor(best, off));
                float nm = fmaxf(m_run[mf][reg], best);
                float sc = __expf(m_run[mf][reg] - nm);
                m_run[mf][reg] = nm;
                l_run[mf][reg] *= sc;
#pragma unroll
                for (int nf = 0; nf < 4; ++nf) { o1[mf][nf][reg] *= sc; o2[mf][nf][reg] *= sc; }
            }
#pragma unroll
        for (int mf = 0; mf < 4; ++mf)
#pragma unroll
            for (int nf = 0; nf < 4; ++nf)
#pragma unroll
                for (int reg = 0; reg < 4; ++reg) {
                    float pv = __expf(s1[mf][nf][reg] - m_run[mf][reg]);
                    l_run[mf][reg] += pv;
                    _Float16 hv = (_Float16)pv;
                    _Float16 lv = (_Float16)((pv - (float)hv) * SPLIT_);
                    union { _Float16 h; unsigned short u; } ch, cl;
                    ch.h = hv; cl.h = lv;
                    int t = 16 * mf + g * 4 + reg, jj = l15 + 16 * nf;
                    pw[t * PPITCH + jj] = (unsigned)ch.u | ((unsigned)cl.u << 16);
                }
#pragma unroll
        for (int ks = 0; ks < 2; ++ks) {
            half8 bvh[4], bvl[4];
#pragma unroll
            for (int nf = 0; nf < 4; ++nf) {
                int d = l15 + 16 * nf;
                int c = (g + 4 * ks) ^ (d & 7);
                bvh[nf] = *(const half8*)&Vhs[d * 64 + c * 8];
                bvl[nf] = *(const half8*)&Vls[d * 64 + c * 8];
            }
#pragma unroll
            for (int mf = 0; mf < 4; ++mf) {
                const unsigned* pr = &pw[(16 * mf + l15) * PPITCH + 32 * ks + g * 8];
                int4 va = *(const int4*)pr;
                int4 vb = *(const int4*)(pr + 4);
                U8h ph, pl;
                ph.w[0] = ((unsigned)va.x & 0xffffu) | ((unsigned)va.y << 16);
                ph.w[1] = ((unsigned)va.z & 0xffffu) | ((unsigned)va.w << 16);
                ph.w[2] = ((unsigned)vb.x & 0xffffu) | ((unsigned)vb.y << 16);
                ph.w[3] = ((unsigned)vb.z & 0xffffu) | ((unsigned)vb.w << 16);
                pl.w[0] = ((unsigned)va.x >> 16) | ((unsigned)va.y & 0xffff0000u);
                pl.w[1] = ((unsigned)va.z >> 16) | ((unsigned)va.w & 0xffff0000u);
                pl.w[2] = ((unsigned)vb.x >> 16) | ((unsigned)vb.y & 0xffff0000u);
                pl.w[3] = ((unsigned)vb.z >> 16) | ((unsigned)vb.w & 0xffff0000u);
#pragma unroll
                for (int nf = 0; nf < 4; ++nf) {
                    o1[mf][nf] = MF16(ph.v, bvh[nf], o1[mf][nf]);
                    o2[mf][nf] = MF16(ph.v, bvl[nf], o2[mf][nf]);
                    o2[mf][nf] = MF16(pl.v, bvh[nf], o2[mf][nf]);
                }
            }
        }
    }
    const float sinkv = sinks[h];
    float inv[4][4];
#pragma unroll
    for (int mf = 0; mf < 4; ++mf)
#pragma unroll
        for (int reg = 0; reg < 4; ++reg) {
            float l = l_run[mf][reg];
            for (int off = 1; off < 16; off <<= 1) l += __shfl_xor(l, off);
            inv[mf][reg] = 1.f / (l + __expf(sinkv - m_run[mf][reg]));
        }
#pragma unroll
    for (int mf = 0; mf < 4; ++mf)
#pragma unroll
        for (int nf = 0; nf < 4; ++nf)
#pragma unroll
            for (int reg = 0; reg < 4; ++reg) {
                int t = i0 + 16 * mf + g * 4 + reg;
                int d = l15 + 16 * nf;
                float ov = (o1[mf][nf][reg] + o2[mf][nf][reg] * INV_SPLIT_) * inv[mf][reg];
                size_t idx = ((size_t)(b * 1024 + t) * 32 + h) * 64 + d;
                _Float16 hv = (_Float16)ov;
                ath[idx] = hv;
                atl[idx] = (_Float16)((ov - (float)hv) * SPLIT_);
            }
}

// ================= Router =================
__global__ __launch_bounds__(256) void k_router(const float* __restrict__ x,
                                                const float* __restrict__ rw,
                                                const float* __restrict__ rb,
                                                int* __restrict__ topi,
                                                float* __restrict__ topw) {
    int t = blockIdx.x;
    int e = threadIdx.x >> 4, g = threadIdx.x & 15;
    const float* row = x + (size_t)t * H_;
    const float* wr = rw + (size_t)e * H_;
    float acc = 0.f;
    int kbeg = g * (H_ / 16);
    for (int kk = 0; kk < H_ / 16; kk += 4) {
        float4 xv = *(const float4*)(row + kbeg + kk);
        float4 wv = *(const float4*)(wr + kbeg + kk);
        acc += xv.x * wv.x + xv.y * wv.y + xv.z * wv.z + xv.w * wv.w;
    }
    __shared__ float part[16][17];
    part[e][g] = acc;
    __syncthreads();
    __shared__ float logits[16];
    if (threadIdx.x < 16) {
        float s2 = rb[threadIdx.x];
        for (int g2 = 0; g2 < 16; g2++) s2 += part[threadIdx.x][g2];
        logits[threadIdx.x] = s2;
    }
    __syncthreads();
    if (threadIdx.x == 0) {
        float tv[4]; int ti4[4];
        unsigned used = 0;
        for (int s3 = 0; s3 < 4; s3++) {
            float best = -3.0e38f; int bi = 0;
            for (int e2 = 0; e2 < 16; e2++)
                if (!((used >> e2) & 1) && logits[e2] > best) { best = logits[e2]; bi = e2; }
            used |= 1u << bi; tv[s3] = best; ti4[s3] = bi;
        }
        float mx = tv[0], pe[4], sum = 0.f;
        for (int s3 = 0; s3 < 4; s3++) { pe[s3] = __expf(tv[s3] - mx); sum += pe[s3]; }
        for (int s3 = 0; s3 < 4; s3++) {
            topw[t * 4 + s3] = pe[s3] / sum;
            topi[t * 4 + s3] = ti4[s3];
        }
    }
}

// ================= MoE prep =================
__global__ void k_zero(int* counts) { if (threadIdx.x < E_) counts[threadIdx.x] = 0; }

__global__ void k_hist(const int* __restrict__ topi, int* counts) {
    int g = blockIdx.x * 256 + threadIdx.x;
    if (g < T_ * TOPK_) atomicAdd(&counts[topi[g]], 1);
}

// scan + build compact MoE tile table (<=48 row-tiles of 256)
__global__ void k_scan(const int* __restrict__ counts, int* offs, int* cursor,
                       int* te, int* tm, int* ntt) {
    if (threadIdx.x == 0 && blockIdx.x == 0) {
        int run = 0, t = 0;
        for (int e = 0; e < E_; e++) {
            offs[e] = run; cursor[e] = run;
            for (int m0 = 0; m0 < counts[e]; m0 += 256) { te[t] = e; tm[t] = m0; t++; }
            run += counts[e];
        }
        ntt[0] = t;
    }
}

__global__ void k_scatter(const int* __restrict__ topi, const float* __restrict__ topw,
                          int* cursor, int* __restrict__ perm, float* __restrict__ pw) {
    int g = blockIdx.x * 256 + threadIdx.x;
    if (g >= T_ * TOPK_) return;
    int e = topi[g];
    int pos = atomicAdd(&cursor[e], 1);
    perm[pos] = g >> 2;
    pw[pos] = topw[g];
}

// ================= launch =================
extern "C" void kernel_launch(void* const* d_in, const int* in_sizes, int n_in,
                              void* d_out, int out_size, void* d_ws, size_t ws_size,
                              hipStream_t stream) {
    const float* hidden = (const float*)d_in[0];
    const float* cosp  = (const float*)d_in[1];
    const float* sinp  = (const float*)d_in[2];
    const float* ln1   = (const float*)d_in[3];
    const float* ln2   = (const float*)d_in[4];
    const float* qw    = (const float*)d_in[5];
    const float* qb    = (const float*)d_in[6];
    const float* kw    = (const float*)d_in[7];
    const float* kbia  = (const float*)d_in[8];
    const float* vw    = (const float*)d_in[9];
    const float* vbia  = (const float*)d_in[10];
    const float* ow    = (const float*)d_in[11];
    const float* ob    = (const float*)d_in[12];
    const float* sinks = (const float*)d_in[13];
    const float* rw    = (const float*)d_in[14];
    const float* rb    = (const float*)d_in[15];
    const float* gup   = (const float*)d_in[16];
    const float* gub   = (const float*)d_in[17];
    const float* dwp   = (const float*)d_in[18];
    const float* dwb   = (const float*)d_in[19];
    float* out = (float*)d_out;

    char* p = (char*)d_ws;
    auto alloc = [&](size_t bytes) { char* r = p; p += (bytes + 255) & ~(size_t)255; return r; };
    float*     xnorm  = (float*)alloc((size_t)T_ * H_ * 4);
    _Float16*  xh     = (_Float16*)alloc((size_t)T_ * H_ * 2);
    _Float16*  xl     = (_Float16*)alloc((size_t)T_ * H_ * 2);
    float*     qbuf   = (float*)alloc((size_t)T_ * NH_ * HD_ * 4);
    float*     kbuf   = (float*)alloc((size_t)T_ * NKV_ * HD_ * 4);
    float*     vbuf   = (float*)alloc((size_t)T_ * NKV_ * HD_ * 4);
    _Float16*  ath    = (_Float16*)alloc((size_t)T_ * NH_ * HD_ * 2);
    _Float16*  atl    = (_Float16*)alloc((size_t)T_ * NH_ * HD_ * 2);
    _Float16*  gatedh = (_Float16*)alloc((size_t)T_ * TOPK_ * ED_ * 2);
    _Float16*  qwh    = (_Float16*)alloc((size_t)2048 * H_ * 2);
    _Float16*  qwl    = (_Float16*)alloc((size_t)2048 * H_ * 2);
    _Float16*  kwh    = (_Float16*)alloc((size_t)512 * H_ * 2);
    _Float16*  kwl    = (_Float16*)alloc((size_t)512 * H_ * 2);
    _Float16*  vwh    = (_Float16*)alloc((size_t)512 * H_ * 2);
    _Float16*  vwl    = (_Float16*)alloc((size_t)512 * H_ * 2);
    _Float16*  owh    = (_Float16*)alloc((size_t)H_ * 2048 * 2);
    _Float16*  owl    = (_Float16*)alloc((size_t)H_ * 2048 * 2);
    _Float16*  gupt   = (_Float16*)alloc((size_t)E_ * 2048 * H_ * 2);
    _Float16*  dwnt   = (_Float16*)alloc((size_t)E_ * H_ * ED_ * 2);
    _Float16*  qhb    = (_Float16*)alloc((size_t)T_ * NH_ * HD_ * 2);
    _Float16*  qlb    = (_Float16*)alloc((size_t)T_ * NH_ * HD_ * 2);
    _Float16*  khb    = (_Float16*)alloc((size_t)T_ * NKV_ * HD_ * 2);
    _Float16*  klb    = (_Float16*)alloc((size_t)T_ * NKV_ * HD_ * 2);
    _Float16*  vthb   = (_Float16*)alloc((size_t)T_ * NKV_ * HD_ * 2);
    _Float16*  vtlb   = (_Float16*)alloc((size_t)T_ * NKV_ * HD_ * 2);
    float*     topw   = (float*)alloc(T_ * TOPK_ * 4);
    float*     pwb    = (float*)alloc(T_ * TOPK_ * 4);
    int*       topi   = (int*)alloc(T_ * TOPK_ * 4);
    int*       perm   = (int*)alloc(T_ * TOPK_ * 4);
    int*       counts = (int*)alloc(E_ * 4);
    int*       offs   = (int*)alloc(E_ * 4);
    int*       cursor = (int*)alloc(E_ * 4);
    int*       te     = (int*)alloc(MAXT_ * 4);
    int*       tm     = (int*)alloc(MAXT_ * 4);
    int*       ntt    = (int*)alloc(4);

    // weight conversions
    k_cvts<<<2048, 256, 0, stream>>>(qw, qwh, qwl, 2048 * H_ / 8);
    k_cvts<<<512, 256, 0, stream>>>(kw, kwh, kwl, 512 * H_ / 8);
    k_cvts<<<512, 256, 0, stream>>>(vw, vwh, vwl, 512 * H_ / 8);
    k_cvts<<<2048, 256, 0, stream>>>(ow, owh, owl, H_ * 2048 / 8);
    k_cvt_t<<<dim3(H_ / 32, 2048 / 32, E_), 256, 0, stream>>>(gup, gupt, H_, 2048);
    k_cvt_t<<<dim3(ED_ / 32, H_ / 32, E_), 256, 0, stream>>>(dwp, dwnt, ED_, H_);

    k_rmsnorm<<<T_, 256, 0, stream>>>(hidden, ln1, xnorm, xh, xl);
    // QKV: init C with bias, split-K=4 GEMMs atomically accumulate
    k_initc<<<4096, 256, 0, stream>>>(qb, nullptr, qbuf, 2048, T_ * 2048 / 4);
    k_initc<<<1024, 256, 0, stream>>>(kbia, nullptr, kbuf, 512, T_ * 512 / 4);
    k_initc<<<1024, 256, 0, stream>>>(vbia, nullptr, vbuf, 512, T_ * 512 / 4);
    k_gemm_spk<<<1024, 256, 0, stream>>>(xh, xl, qwh, qwl, qbuf, 2048, H_);
    k_gemm_spk<<<256, 256, 0, stream>>>(xh, xl, kwh, kwl, kbuf, 512, H_);
    k_gemm_spk<<<256, 256, 0, stream>>>(xh, xl, vwh, vwl, vbuf, 512, H_);
    k_rope_sp<<<T_, 256, 0, stream>>>(qbuf, kbuf, cosp, sinp, qhb, qlb, khb, klb);
    k_cvt_vt<<<dim3(32, 2, 16), 256, 0, stream>>>(vbuf, vthb, vtlb);
    k_attn_m<<<256, 256, 0, stream>>>(qhb, qlb, khb, klb, vthb, vtlb, sinks, ath, atl);
    // O-proj: out = hidden + ob + attn @ ow^T (init + split-K atomic)
    k_initc<<<4096, 256, 0, stream>>>(ob, hidden, out, 2048, T_ * 2048 / 4);
    k_gemm_spk<<<1024, 256, 0, stream>>>(ath, atl, owh, owl, out, 2048, H_);
    k_rmsnorm<<<T_, 256, 0, stream>>>(out, ln2, xnorm, xh, xl);
    k_router<<<T_, 256, 0, stream>>>(xnorm, rw, rb, topi, topw);
    k_zero<<<1, 64, 0, stream>>>(counts);
    k_hist<<<(T_ * TOPK_ + 255) / 256, 256, 0, stream>>>(topi, counts);
    k_scan<<<1, 1, 0, stream>>>(counts, offs, cursor, te, tm, ntt);
    k_scatter<<<(T_ * TOPK_ + 255) / 256, 256, 0, stream>>>(topi, topw, cursor, perm, pwb);
    k_moe1<<<MAXT_ * 8, 512, 0, stream>>>(xh, gupt, gub, perm, counts, offs, te, tm, ntt, gatedh);
    k_moe2<<<MAXT_ * 8, 512, 0, stream>>>(gatedh, dwnt, dwb, perm, pwb, counts, offs, te, tm, ntt, out);
}

// Round 11
// 937.197 us; speedup vs baseline: 1.0970x; 1.0970x over previous
//
#include <hip/hip_runtime.h>
#include <hip/hip_bf16.h>
#include <cstdint>

#define B_    2
#define S_    1024
#define H_    2048
#define NH_   32
#define NKV_  8
#define HD_   64
#define T_    (B_*S_)
#define E_    16
#define ED_   1024
#define TOPK_ 4
#define WIN_  128
#define LIMIT_ 7.0f
#define ALPHA_ 1.702f
#define EPS_   1e-6f
#define SCALE_ 0.125f  /* HD^-0.5 */
#define SPLIT_ 2048.0f
#define INV_SPLIT_ 4.8828125e-4f
#define MAXT_ 80      /* max MoE row-tiles of 128: 64 + 16 */

typedef _Float16 half8 __attribute__((ext_vector_type(8)));
typedef _Float16 half4v __attribute__((ext_vector_type(4)));
typedef float floatx4 __attribute__((ext_vector_type(4)));

#define MF16(a,b,c) __builtin_amdgcn_mfma_f32_16x16x32_f16(a,b,c,0,0,0)

__device__ __forceinline__ void gload16(const void* g, void* l) {
    __builtin_amdgcn_global_load_lds((const __attribute__((address_space(1))) void*)g,
                                     (__attribute__((address_space(3))) void*)l, 16, 0, 0);
}

// bijective chunked XCD swizzle (nwg % 8 == 0)
__device__ __forceinline__ int xcd_swz(int bid, int nwg) {
    int cpx = nwg >> 3;
    return (bid & 7) * cpx + (bid >> 3);
}

// ================= C init: C = bias (+res) =================
__global__ __launch_bounds__(256) void k_initc(const float* __restrict__ bias,
                                               const float* __restrict__ res,
                                               float* __restrict__ C, int N, int n4) {
    int i = blockIdx.x * 256 + threadIdx.x;
    if (i >= n4) return;
    int c4 = (i % (N >> 2)) << 2;
    float4 v = *(const float4*)(bias + c4);
    if (res) {
        float4 r = ((const float4*)res)[i];
        v.x += r.x; v.y += r.y; v.z += r.z; v.w += r.w;
    }
    ((float4*)C)[i] = v;
}

// ===== split-fp16 GEMM, split-K=4, double-buffered LDS + counted vmcnt =====
__global__ __launch_bounds__(256) void k_gemm_spk(const _Float16* __restrict__ Ah,
                                                  const _Float16* __restrict__ Al,
                                                  const _Float16* __restrict__ Bh,
                                                  const _Float16* __restrict__ Bl,
                                                  float* __restrict__ C, int N, int K) {
    __shared__ _Float16 Ahs[2][128 * 32];
    __shared__ _Float16 Als[2][128 * 32];
    __shared__ _Float16 Bhs[2][128 * 32];
    __shared__ _Float16 Bls[2][128 * 32];
    const int tid = threadIdx.x;
    const int lane = tid & 63;
    const int wid = tid >> 6;
    const int wr = wid >> 1, wc = wid & 1;
    const int wg = xcd_swz(blockIdx.x, gridDim.x);
    const int col0 = (wg >> 6) * 128;
    const int row0 = ((wg & 63) >> 2) * 128;
    const int ks4 = wg & 3;
    const int kbeg = ks4 * (K >> 2), kend = kbeg + (K >> 2);
    floatx4 acc1[4][4], acc2[4][4];
    for (int m = 0; m < 4; ++m)
        for (int n = 0; n < 4; ++n) { acc1[m][n] = (floatx4)0.f; acc2[m][n] = (floatx4)0.f; }
    const int rL = tid >> 2, koff = (tid & 3) * 8;
    const size_t o0 = (size_t)(row0 + rL) * K + koff;
    const size_t o1 = (size_t)(row0 + 64 + rL) * K + koff;
    const size_t p0 = (size_t)(col0 + rL) * K + koff;
    const size_t p1 = (size_t)(col0 + 64 + rL) * K + koff;
#define DSTAGE(buf, kk) do { \
        gload16(Ah + o0 + (kk), Ahs[buf] + tid * 8); gload16(Ah + o1 + (kk), Ahs[buf] + 2048 + tid * 8); \
        gload16(Al + o0 + (kk), Als[buf] + tid * 8); gload16(Al + o1 + (kk), Als[buf] + 2048 + tid * 8); \
        gload16(Bh + p0 + (kk), Bhs[buf] + tid * 8); gload16(Bh + p1 + (kk), Bhs[buf] + 2048 + tid * 8); \
        gload16(Bl + p0 + (kk), Bls[buf] + tid * 8); gload16(Bl + p1 + (kk), Bls[buf] + 2048 + tid * 8); \
    } while (0)
    DSTAGE(0, kbeg);
    int cur = 0;
    for (int k0 = kbeg; k0 < kend; k0 += 32) {
        if (k0 + 32 < kend) {
            DSTAGE(cur ^ 1, k0 + 32);
            asm volatile("s_waitcnt vmcnt(8)" ::: "memory");
        } else {
            asm volatile("s_waitcnt vmcnt(0)" ::: "memory");
        }
        __builtin_amdgcn_s_barrier();
        __builtin_amdgcn_sched_barrier(0);
        const int lk = (lane >> 4) * 8;
        half8 ah[4], al[4], bh[4], bl[4];
#pragma unroll
        for (int m = 0; m < 4; ++m) {
            int ro = (wr * 64 + m * 16 + (lane & 15)) * 32 + lk;
            ah[m] = *(const half8*)&Ahs[cur][ro];
            al[m] = *(const half8*)&Als[cur][ro];
        }
#pragma unroll
        for (int n = 0; n < 4; ++n) {
            int ro = (wc * 64 + n * 16 + (lane & 15)) * 32 + lk;
            bh[n] = *(const half8*)&Bhs[cur][ro];
            bl[n] = *(const half8*)&Bls[cur][ro];
        }
#pragma unroll
        for (int m = 0; m < 4; ++m)
#pragma unroll
            for (int n = 0; n < 4; ++n) {
                acc1[m][n] = MF16(ah[m], bh[n], acc1[m][n]);
                acc2[m][n] = MF16(ah[m], bl[n], acc2[m][n]);
                acc2[m][n] = MF16(al[m], bh[n], acc2[m][n]);
            }
        __builtin_amdgcn_sched_barrier(0);
        __builtin_amdgcn_s_barrier();
        cur ^= 1;
    }
#undef DSTAGE
#pragma unroll
    for (int mf = 0; mf < 4; ++mf)
#pragma unroll
        for (int i = 0; i < 4; ++i) {
            int r = row0 + wr * 64 + mf * 16 + ((lane >> 4) << 2) + i;
#pragma unroll
            for (int nf = 0; nf < 4; ++nf) {
                int c = col0 + wc * 64 + nf * 16 + (lane & 15);
                atomicAdd(&C[(size_t)r * N + c], acc1[mf][nf][i] + acc2[mf][nf][i] * INV_SPLIT_);
            }
        }
}

// ===== MoE MFMA core: BK=64, XOR-swizzled LDS, dbuf + COUNTED vmcnt (R9) =====
#define MOE_PROLOG() \
    __shared__ _Float16 As[2][128 * 64]; \
    __shared__ _Float16 Bs[2][128 * 64]; \
    const int tid = threadIdx.x; \
    const int lane = tid & 63; \
    const int wid = tid >> 6; \
    const int wr = wid >> 1, wc = wid & 1; \
    const int rloc = tid >> 3; \
    const int ksw = ((tid & 7) ^ (rloc & 7)) * 8; \
    floatx4 acc[4][4]; \
    for (int m = 0; m < 4; ++m) for (int n = 0; n < 4; ++n) acc[m][n] = (floatx4)0.f;

#define MOE_STAGE(buf, kk) do { \
        _Pragma("unroll") for (int c = 0; c < 4; ++c) { \
            gload16(asrc[c] + (kk), As[buf] + c * 2048 + tid * 8); \
            gload16(bsrc[c] + (kk), Bs[buf] + c * 2048 + tid * 8); \
        } \
    } while (0)

#define MOE_KLOOP(KD) \
    MOE_STAGE(0, 0); \
    { int cur = 0; \
    for (int k0 = 0; k0 < (KD); k0 += 64) { \
        if (k0 + 64 < (KD)) { \
            MOE_STAGE(cur ^ 1, k0 + 64); \
            asm volatile("s_waitcnt vmcnt(8)" ::: "memory"); \
        } else { \
            asm volatile("s_waitcnt vmcnt(0)" ::: "memory"); \
        } \
        __builtin_amdgcn_s_barrier(); \
        __builtin_amdgcn_sched_barrier(0); \
        _Pragma("unroll") for (int s = 0; s < 2; ++s) { \
            const int gc = ((s * 4 + (lane >> 4)) ^ (lane & 7)) * 8; \
            half8 a[4], b[4]; \
            _Pragma("unroll") for (int m = 0; m < 4; ++m) \
                a[m] = *(const half8*)&As[cur][(wr * 64 + m * 16 + (lane & 15)) * 64 + gc]; \
            _Pragma("unroll") for (int n = 0; n < 4; ++n) \
                b[n] = *(const half8*)&Bs[cur][(wc * 64 + n * 16 + (lane & 15)) * 64 + gc]; \
            _Pragma("unroll") for (int m = 0; m < 4; ++m) \
                _Pragma("unroll") for (int n = 0; n < 4; ++n) \
                    acc[m][n] = MF16(a[m], b[n], acc[m][n]); \
        } \
        __builtin_amdgcn_sched_barrier(0); \
        __builtin_amdgcn_s_barrier(); \
        cur ^= 1; \
    } }

// MoE GEMM1: tile-table grid (80x16). gathered A rows; fused GLU -> gated f16
__global__ __launch_bounds__(256) void k_moe1(const _Float16* __restrict__ X,
                                              const _Float16* __restrict__ W,
                                              const float* __restrict__ bias,
                                              const int* __restrict__ perm,
                                              const int* __restrict__ counts,
                                              const int* __restrict__ offs,
                                              const int* __restrict__ te,
                                              const int* __restrict__ tm,
                                              const int* __restrict__ ntt,
                                              _Float16* __restrict__ gated) {
    const int wg = xcd_swz(blockIdx.x, MAXT_ * 16);
    const int tt = wg >> 4;
    if (tt >= ntt[0]) return;
    const int e = te[tt];
    const int m0 = tm[tt];
    const int ne = counts[e];
    const int base = offs[e];
    const int col0 = (wg & 15) * 128;
    MOE_PROLOG();
    const _Float16* asrc[4];
    const _Float16* bsrc[4];
#pragma unroll
    for (int c = 0; c < 4; ++c) {
        int t = perm[base + min(m0 + c * 32 + rloc, ne - 1)];
        asrc[c] = X + (size_t)t * H_ + ksw;
        bsrc[c] = W + ((size_t)e * 2048 + col0 + c * 32 + rloc) * H_ + ksw;
    }
    MOE_KLOOP(H_);
#pragma unroll
    for (int mf = 0; mf < 4; ++mf)
#pragma unroll
        for (int i = 0; i < 4; ++i) {
            int r = m0 + wr * 64 + mf * 16 + ((lane >> 4) << 2) + i;
            bool ok = r < ne;
            int slot = base + r;
#pragma unroll
            for (int nf = 0; nf < 4; ++nf) {
                int c = col0 + wc * 64 + nf * 16 + (lane & 15);
                float v = acc[mf][nf][i] + bias[e * 2048 + c];
                float o = __shfl_xor(v, 1);
                if (ok && !(lane & 1)) {
                    float gt = fminf(v, LIMIT_);
                    float up = fminf(fmaxf(o, -LIMIT_), LIMIT_);
                    float sg = 1.f / (1.f + __expf(-ALPHA_ * gt));
                    gated[(size_t)slot * ED_ + (c >> 1)] = (_Float16)((up + 1.f) * (gt * sg));
                }
            }
        }
}

__global__ __launch_bounds__(256) void k_moe2(const _Float16* __restrict__ G,
                                              const _Float16* __restrict__ W,
                                              const float* __restrict__ bias,
                                              const int* __restrict__ perm,
                                              const float* __restrict__ pw,
                                              const int* __restrict__ counts,
                                              const int* __restrict__ offs,
                                              const int* __restrict__ te,
                                              const int* __restrict__ tm,
                                              const int* __restrict__ ntt,
                                              float* __restrict__ out) {
    const int wg = xcd_swz(blockIdx.x, MAXT_ * 16);
    const int tt = wg >> 4;
    if (tt >= ntt[0]) return;
    const int e = te[tt];
    const int m0 = tm[tt];
    const int ne = counts[e];
    const int base = offs[e];
    const int col0 = (wg & 15) * 128;
    MOE_PROLOG();
    const _Float16* asrc[4];
    const _Float16* bsrc[4];
#pragma unroll
    for (int c = 0; c < 4; ++c) {
        int s = base + min(m0 + c * 32 + rloc, ne - 1);
        asrc[c] = G + (size_t)s * ED_ + ksw;
        bsrc[c] = W + ((size_t)e * H_ + col0 + c * 32 + rloc) * ED_ + ksw;
    }
    MOE_KLOOP(ED_);
#pragma unroll
    for (int mf = 0; mf < 4; ++mf)
#pragma unroll
        for (int i = 0; i < 4; ++i) {
            int r = m0 + wr * 64 + mf * 16 + ((lane >> 4) << 2) + i;
            if (r >= ne) continue;
            int slot = base + r;
            int tok = perm[slot];
            float wgt = pw[slot];
#pragma unroll
            for (int nf = 0; nf < 4; ++nf) {
                int c = col0 + wc * 64 + nf * 16 + (lane & 15);
                atomicAdd(&out[(size_t)tok * H_ + c], wgt * (acc[mf][nf][i] + bias[e * H_ + c]));
            }
        }
}

// ================= conversions =================
__global__ __launch_bounds__(256) void k_cvts(const float* __restrict__ s,
                                              _Float16* __restrict__ dh,
                                              _Float16* __restrict__ dl, int n8) {
    int i = blockIdx.x * 256 + threadIdx.x;
    if (i >= n8) return;
    float4 x = ((const float4*)s)[i * 2], y = ((const float4*)s)[i * 2 + 1];
    float xs[8] = {x.x, x.y, x.z, x.w, y.x, y.y, y.z, y.w};
    half8 h, l;
#pragma unroll
    for (int j = 0; j < 8; ++j) {
        _Float16 hv = (_Float16)xs[j];
        h[j] = hv;
        l[j] = (_Float16)((xs[j] - (float)hv) * SPLIT_);
    }
    ((half8*)dh)[i] = h;
    ((half8*)dl)[i] = l;
}

// transpose-convert: src [e][K][N] fp32 -> dst [e][N][K] f16.
// 64x64 tile; fp32 loads float4-coalesced; f16 writes half8 (128B/8 lanes contiguous).
__global__ __launch_bounds__(256) void k_cvt_t(const float* __restrict__ src,
                                               _Float16* __restrict__ dst, int K, int N) {
    const int e = blockIdx.z;
    const int k0 = blockIdx.x * 64, n0 = blockIdx.y * 64;
    __shared__ float t[64][65];
    const int tid = threadIdx.x;
    {
        int kr = tid >> 4, nc = (tid & 15) * 4;
#pragma unroll
        for (int j = 0; j < 4; ++j) {
            float4 v = *(const float4*)(src + ((size_t)e * K + k0 + kr + j * 16) * N + n0 + nc);
            t[kr + j * 16][nc] = v.x; t[kr + j * 16][nc + 1] = v.y;
            t[kr + j * 16][nc + 2] = v.z; t[kr + j * 16][nc + 3] = v.w;
        }
    }
    __syncthreads();
    {
        int nr = tid >> 3, kc = (tid & 7) * 8;
#pragma unroll
        for (int j = 0; j < 2; ++j) {
            int n = nr + j * 32;
            half8 o;
#pragma unroll
            for (int i = 0; i < 8; ++i) o[i] = (_Float16)t[kc + i][n];
            *(half8*)(dst + ((size_t)e * N + n0 + n) * K + k0 + kc) = o;
        }
    }
}

// v transpose-split: vbuf fp32 [b][s][kvh][64] -> vth/vtl [b][kvh][64 d][1024 s]
__global__ __launch_bounds__(256) void k_cvt_vt(const float* __restrict__ vbuf,
                                                _Float16* __restrict__ vth,
                                                _Float16* __restrict__ vtl) {
    const int s0 = blockIdx.x * 32, d0 = blockIdx.y * 32;
    const int bk = blockIdx.z;
    const int b = bk >> 3, kvh = bk & 7;
    __shared__ float tl[32][33];
    const int tid = threadIdx.x;
    {
        int sr = tid >> 3, dc = (tid & 7) * 4;
        float4 v = *(const float4*)(vbuf + (size_t)(b * 1024 + s0 + sr) * 512 + kvh * 64 + d0 + dc);
        tl[sr][dc] = v.x; tl[sr][dc + 1] = v.y; tl[sr][dc + 2] = v.z; tl[sr][dc + 3] = v.w;
    }
    __syncthreads();
    {
        int dr = tid >> 3, sc = (tid & 7) * 4;
        half4v h4, l4;
#pragma unroll
        for (int j = 0; j < 4; ++j) {
            float x = tl[sc + j][dr];
            _Float16 hv = (_Float16)x;
            h4[j] = hv;
            l4[j] = (_Float16)((x - (float)hv) * SPLIT_);
        }
        size_t dst = (size_t)(bk * 64 + d0 + dr) * 1024 + s0 + sc;
        *(half4v*)(vth + dst) = h4;
        *(half4v*)(vtl + dst) = l4;
    }
}

// ================= RMSNorm (fp32 + split f16 outputs) =================
__global__ __launch_bounds__(256) void k_rmsnorm(const float* __restrict__ x,
                                                 const float* __restrict__ w,
                                                 float* __restrict__ y,
                                                 _Float16* __restrict__ yh,
                                                 _Float16* __restrict__ yl) {
    int t = blockIdx.x;
    const float* row = x + (size_t)t * H_;
    float ss = 0.f;
    for (int i = threadIdx.x; i < H_ / 4; i += 256) {
        float4 v = ((const float4*)row)[i];
        ss += v.x * v.x + v.y * v.y + v.z * v.z + v.w * v.w;
    }
    for (int o = 32; o >= 1; o >>= 1) ss += __shfl_xor(ss, o);
    __shared__ float wsum[4];
    if ((threadIdx.x & 63) == 0) wsum[threadIdx.x >> 6] = ss;
    __syncthreads();
    float tot = wsum[0] + wsum[1] + wsum[2] + wsum[3];
    float r = rsqrtf(tot / (float)H_ + EPS_);
    float* yrow = y + (size_t)t * H_;
    _Float16* hrow = yh + (size_t)t * H_;
    _Float16* lrow = yl + (size_t)t * H_;
    for (int i = threadIdx.x; i < H_ / 4; i += 256) {
        float4 v = ((const float4*)row)[i];
        float4 g = ((const float4*)w)[i];
        float o4[4];
        o4[0] = v.x * r * g.x; o4[1] = v.y * r * g.y;
        o4[2] = v.z * r * g.z; o4[3] = v.w * r * g.w;
        ((float4*)yrow)[i] = *(float4*)o4;
        half4v h4, l4;
#pragma unroll
        for (int j = 0; j < 4; ++j) {
            _Float16 hv = (_Float16)o4[j];
            h4[j] = hv;
            l4[j] = (_Float16)((o4[j] - (float)hv) * SPLIT_);
        }
        ((half4v*)hrow)[i] = h4;
        ((half4v*)lrow)[i] = l4;
    }
}

// ================= RoPE -> head-major split q/k =================
__global__ __launch_bounds__(256) void k_rope_sp(const float* __restrict__ qbuf,
                                                 const float* __restrict__ kbuf,
                                                 const float* __restrict__ cs,
                                                 const float* __restrict__ sn,
                                                 _Float16* __restrict__ qh, _Float16* __restrict__ ql,
                                                 _Float16* __restrict__ kh, _Float16* __restrict__ kl) {
    int t = blockIdx.x;
    int b = t >> 10, s = t & 1023;
    size_t cb = (size_t)t * 64;
    for (int p = threadIdx.x; p < 40 * 32; p += 256) {
        int head = p >> 5, d = p & 31;
        float c1 = cs[cb + d],      s1v = sn[cb + d];
        float c2 = cs[cb + d + 32], s2v = sn[cb + d + 32];
        float x1, x2; size_t dst;
        _Float16 *oh, *ol;
        if (head < 32) {
            const float* src = qbuf + (size_t)t * 2048 + head * 64;
            x1 = src[d]; x2 = src[d + 32];
            dst = (((size_t)b * 32 + head) * 1024 + s) * 64 + d;
            oh = qh; ol = ql;
        } else {
            int hk = head - 32;
            const float* src = kbuf + (size_t)t * 512 + hk * 64;
            x1 = src[d]; x2 = src[d + 32];
            dst = (((size_t)b * 8 + hk) * 1024 + s) * 64 + d;
            oh = kh; ol = kl;
        }
        float r1 = x1 * c1 - x2 * s1v;
        float r2 = x2 * c2 + x1 * s2v;
        _Float16 h1 = (_Float16)r1;
        oh[dst] = h1; ol[dst] = (_Float16)((r1 - (float)h1) * SPLIT_);
        _Float16 h2 = (_Float16)r2;
        oh[dst + 32] = h2; ol[dst + 32] = (_Float16)((r2 - (float)h2) * SPLIT_);
    }
}

// ================= MFMA flash attention (split-fp16, fp32-accurate) ===========
#define PPITCH 68
union U8h { unsigned w[4]; half8 v; };

__global__ __launch_bounds__(256, 1) void k_attn_m(
        const _Float16* __restrict__ qhg, const _Float16* __restrict__ qlg,
        const _Float16* __restrict__ khg, const _Float16* __restrict__ klg,
        const _Float16* __restrict__ vthg, const _Float16* __restrict__ vtlg,
        const float* __restrict__ sinks,
        _Float16* __restrict__ ath, _Float16* __restrict__ atl) {
    __shared__ _Float16 Khs[4096], Kls[4096], Vhs[4096], Vls[4096];
    __shared__ unsigned Pp[4][64 * PPITCH];
    const int bx = blockIdx.x;
    const int b = bx >> 7, kvh = (bx >> 4) & 7, tile = bx & 15;
    const int i0 = tile * 64;
    const int tid = threadIdx.x, lane = tid & 63, wid = tid >> 6;
    const int l15 = lane & 15, g = lane >> 4;
    const int h = kvh * 4 + wid;
    const size_t kvbase = (size_t)(b * 8 + kvh) * 1024 * 64;
    const size_t vbase  = (size_t)(b * 8 + kvh) * 64 * 1024;
    half8 aqh[4][2], aql[4][2];
    {
        const size_t qb0 = ((size_t)(b * 32 + h) * 1024 + i0) * 64;
#pragma unroll
        for (int mf = 0; mf < 4; ++mf)
#pragma unroll
            for (int ks = 0; ks < 2; ++ks) {
                size_t a = qb0 + (size_t)(16 * mf + l15) * 64 + ks * 32 + g * 8;
                aqh[mf][ks] = *(const half8*)(qhg + a);
                aql[mf][ks] = *(const half8*)(qlg + a);
            }
    }
    floatx4 o1[4][4], o2[4][4];
    float m_run[4][4], l_run[4][4];
#pragma unroll
    for (int mf = 0; mf < 4; ++mf)
#pragma unroll
        for (int x = 0; x < 4; ++x) {
            o1[mf][x] = (floatx4)0.f; o2[mf][x] = (floatx4)0.f;
            m_run[mf][x] = -1e20f; l_run[mf][x] = 0.f;
        }
    const int nch = tile >= 2 ? 3 : tile + 1;
    const int jr = tid >> 3, cc = tid & 7;
    unsigned* pw = &Pp[wid][0];
    for (int ci = 0; ci < nch; ++ci) {
        const int jb = i0 - 64 * (nch - 1 - ci);
        __syncthreads();
        {
            const int sw0 = (cc ^ (jr & 7)) * 8;
            const size_t k0 = kvbase + (size_t)(jb + jr) * 64 + sw0;
            const size_t k1 = kvbase + (size_t)(jb + jr + 32) * 64 + sw0;
            gload16(khg + k0, Khs + tid * 8);
            gload16(khg + k1, Khs + 2048 + tid * 8);
            gload16(klg + k0, Kls + tid * 8);
            gload16(klg + k1, Kls + 2048 + tid * 8);
            const size_t v0 = vbase + (size_t)jr * 1024 + jb + sw0;
            const size_t v1 = vbase + (size_t)(jr + 32) * 1024 + jb + sw0;
            gload16(vthg + v0, Vhs + tid * 8);
            gload16(vthg + v1, Vhs + 2048 + tid * 8);
            gload16(vtlg + v0, Vls + tid * 8);
            gload16(vtlg + v1, Vls + 2048 + tid * 8);
        }
        __syncthreads();
        floatx4 s1[4][4], s2[4][4];
#pragma unroll
        for (int mf = 0; mf < 4; ++mf)
#pragma unroll
            for (int nf = 0; nf < 4; ++nf) { s1[mf][nf] = (floatx4)0.f; s2[mf][nf] = (floatx4)0.f; }
#pragma unroll
        for (int ks = 0; ks < 2; ++ks) {
            half8 kbh[4], kbl[4];
#pragma unroll
            for (int nf = 0; nf < 4; ++nf) {
                int j = l15 + 16 * nf;
                int c = (g + 4 * ks) ^ (j & 7);
                kbh[nf] = *(const half8*)&Khs[j * 64 + c * 8];
                kbl[nf] = *(const half8*)&Kls[j * 64 + c * 8];
            }
#pragma unroll
            for (int mf = 0; mf < 4; ++mf)
#pragma unroll
                for (int nf = 0; nf < 4; ++nf) {
                    s1[mf][nf] = MF16(aqh[mf][ks], kbh[nf], s1[mf][nf]);
                    s2[mf][nf] = MF16(aqh[mf][ks], kbl[nf], s2[mf][nf]);
                    s2[mf][nf] = MF16(aql[mf][ks], kbh[nf], s2[mf][nf]);
                }
        }
#pragma unroll
        for (int mf = 0; mf < 4; ++mf)
#pragma unroll
            for (int reg = 0; reg < 4; ++reg) {
                int i = i0 + 16 * mf + g * 4 + reg;
                float best = -1e30f;
#pragma unroll
                for (int nf = 0; nf < 4; ++nf) {
                    int j = jb + 16 * nf + l15;
                    float sv = (s1[mf][nf][reg] + s2[mf][nf][reg] * INV_SPLIT_) * SCALE_;
                    bool ok = (j <= i) && (i - j < WIN_);
                    sv = ok ? sv : -1e30f;
                    s1[mf][nf][reg] = sv;
                    best = fmaxf(best, sv);
                }
                for (int off = 1; off < 16; off <<= 1) best = fmaxf(best, __shfl_xor(best, off));
                float nm = fmaxf(m_run[mf][reg], best);
                float sc = __expf(m_run[mf][reg] - nm);
                m_run[mf][reg] = nm;
                l_run[mf][reg] *= sc;
#pragma unroll
                for (int nf = 0; nf < 4; ++nf) { o1[mf][nf][reg] *= sc; o2[mf][nf][reg] *= sc; }
            }
#pragma unroll
        for (int mf = 0; mf < 4; ++mf)
#pragma unroll
            for (int nf = 0; nf < 4; ++nf)
#pragma unroll
                for (int reg = 0; reg < 4; ++reg) {
                    float pv = __expf(s1[mf][nf][reg] - m_run[mf][reg]);
                    l_run[mf][reg] += pv;
                    _Float16 hv = (_Float16)pv;
                    _Float16 lv = (_Float16)((pv - (float)hv) * SPLIT_);
                    union { _Float16 h; unsigned short u; } ch, cl;
                    ch.h = hv; cl.h = lv;
                    int t = 16 * mf + g * 4 + reg, jj = l15 + 16 * nf;
                    pw[t * PPITCH + jj] = (unsigned)ch.u | ((unsigned)cl.u << 16);
                }
#pragma unroll
        for (int ks = 0; ks < 2; ++ks) {
            half8 bvh[4], bvl[4];
#pragma unroll
            for (int nf = 0; nf < 4; ++nf) {
                int d = l15 + 16 * nf;
                int c = (g + 4 * ks) ^ (d & 7);
                bvh[nf] = *(const half8*)&Vhs[d * 64 + c * 8];
                bvl[nf] = *(const half8*)&Vls[d * 64 + c * 8];
            }
#pragma unroll
            for (int mf = 0; mf < 4; ++mf) {
                const unsigned* pr = &pw[(16 * mf + l15) * PPITCH + 32 * ks + g * 8];
                int4 va = *(const int4*)pr;
                int4 vb = *(const int4*)(pr + 4);
                U8h ph, pl;
                ph.w[0] = ((unsigned)va.x & 0xffffu) | ((unsigned)va.y << 16);
                ph.w[1] = ((unsigned)va.z & 0xffffu) | ((unsigned)va.w << 16);
                ph.w[2] = ((unsigned)vb.x & 0xffffu) | ((unsigned)vb.y << 16);
                ph.w[3] = ((unsigned)vb.z & 0xffffu) | ((unsigned)vb.w << 16);
                pl.w[0] = ((unsigned)va.x >> 16) | ((unsigned)va.y & 0xffff0000u);
                pl.w[1] = ((unsigned)va.z >> 16) | ((unsigned)va.w & 0xffff0000u);
                pl.w[2] = ((unsigned)vb.x >> 16) | ((unsigned)vb.y & 0xffff0000u);
                pl.w[3] = ((unsigned)vb.z >> 16) | ((unsigned)vb.w & 0xffff0000u);
#pragma unroll
                for (int nf = 0; nf < 4; ++nf) {
                    o1[mf][nf] = MF16(ph.v, bvh[nf], o1[mf][nf]);
                    o2[mf][nf] = MF16(ph.v, bvl[nf], o2[mf][nf]);
                    o2[mf][nf] = MF16(pl.v, bvh[nf], o2[mf][nf]);
                }
            }
        }
    }
    const float sinkv = sinks[h];
    float inv[4][4];
#pragma unroll
    for (int mf = 0; mf < 4; ++mf)
#pragma unroll
        for (int reg = 0; reg < 4; ++reg) {
            float l = l_run[mf][reg];
            for (int off = 1; off < 16; off <<= 1) l += __shfl_xor(l, off);
            inv[mf][reg] = 1.f / (l + __expf(sinkv - m_run[mf][reg]));
        }
#pragma unroll
    for (int mf = 0; mf < 4; ++mf)
#pragma unroll
        for (int nf = 0; nf < 4; ++nf)
#pragma unroll
            for (int reg = 0; reg < 4; ++reg) {
                int t = i0 + 16 * mf + g * 4 + reg;
                int d = l15 + 16 * nf;
                float ov = (o1[mf][nf][reg] + o2[mf][nf][reg] * INV_SPLIT_) * inv[mf][reg];
                size_t idx = ((size_t)(b * 1024 + t) * 32 + h) * 64 + d;
                _Float16 hv = (_Float16)ov;
                ath[idx] = hv;
                atl[idx] = (_Float16)((ov - (float)hv) * SPLIT_);
            }
}

// ================= Router =================
__global__ __launch_bounds__(256) void k_router(const float* __restrict__ x,
                                                const float* __restrict__ rw,
                                                const float* __restrict__ rb,
                                                int* __restrict__ topi,
                                                float* __restrict__ topw) {
    int t = blockIdx.x;
    int e = threadIdx.x >> 4, g = threadIdx.x & 15;
    const float* row = x + (size_t)t * H_;
    const float* wr = rw + (size_t)e * H_;
    float acc = 0.f;
    int kbeg = g * (H_ / 16);
    for (int kk = 0; kk < H_ / 16; kk += 4) {
        float4 xv = *(const float4*)(row + kbeg + kk);
        float4 wv = *(const float4*)(wr + kbeg + kk);
        acc += xv.x * wv.x + xv.y * wv.y + xv.z * wv.z + xv.w * wv.w;
    }
    __shared__ float part[16][17];
    part[e][g] = acc;
    __syncthreads();
    __shared__ float logits[16];
    if (threadIdx.x < 16) {
        float s2 = rb[threadIdx.x];
        for (int g2 = 0; g2 < 16; g2++) s2 += part[threadIdx.x][g2];
        logits[threadIdx.x] = s2;
    }
    __syncthreads();
    if (threadIdx.x == 0) {
        float tv[4]; int ti4[4];
        unsigned used = 0;
        for (int s3 = 0; s3 < 4; s3++) {
            float best = -3.0e38f; int bi = 0;
            for (int e2 = 0; e2 < 16; e2++)
                if (!((used >> e2) & 1) && logits[e2] > best) { best = logits[e2]; bi = e2; }
            used |= 1u << bi; tv[s3] = best; ti4[s3] = bi;
        }
        float mx = tv[0], pe[4], sum = 0.f;
        for (int s3 = 0; s3 < 4; s3++) { pe[s3] = __expf(tv[s3] - mx); sum += pe[s3]; }
        for (int s3 = 0; s3 < 4; s3++) {
            topw[t * 4 + s3] = pe[s3] / sum;
            topi[t * 4 + s3] = ti4[s3];
        }
    }
}

// ================= MoE prep =================
__global__ void k_zero(int* counts) { if (threadIdx.x < E_) counts[threadIdx.x] = 0; }

__global__ void k_hist(const int* __restrict__ topi, int* counts) {
    int g = blockIdx.x * 256 + threadIdx.x;
    if (g < T_ * TOPK_) atomicAdd(&counts[topi[g]], 1);
}

// scan + build compact MoE tile table (<=80 row-tiles of 128)
__global__ void k_scan(const int* __restrict__ counts, int* offs, int* cursor,
                       int* te, int* tm, int* ntt) {
    if (threadIdx.x == 0 && blockIdx.x == 0) {
        int run = 0, t = 0;
        for (int e = 0; e < E_; e++) {
            offs[e] = run; cursor[e] = run;
            for (int m0 = 0; m0 < counts[e]; m0 += 128) { te[t] = e; tm[t] = m0; t++; }
            run += counts[e];
        }
        ntt[0] = t;
    }
}

__global__ void k_scatter(const int* __restrict__ topi, const float* __restrict__ topw,
                          int* cursor, int* __restrict__ perm, float* __restrict__ pw) {
    int g = blockIdx.x * 256 + threadIdx.x;
    if (g >= T_ * TOPK_) return;
    int e = topi[g];
    int pos = atomicAdd(&cursor[e], 1);
    perm[pos] = g >> 2;
    pw[pos] = topw[g];
}

// ================= launch =================
extern "C" void kernel_launch(void* const* d_in, const int* in_sizes, int n_in,
                              void* d_out, int out_size, void* d_ws, size_t ws_size,
                              hipStream_t stream) {
    const float* hidden = (const float*)d_in[0];
    const float* cosp  = (const float*)d_in[1];
    const float* sinp  = (const float*)d_in[2];
    const float* ln1   = (const float*)d_in[3];
    const float* ln2   = (const float*)d_in[4];
    const float* qw    = (const float*)d_in[5];
    const float* qb    = (const float*)d_in[6];
    const float* kw    = (const float*)d_in[7];
    const float* kbia  = (const float*)d_in[8];
    const float* vw    = (const float*)d_in[9];
    const float* vbia  = (const float*)d_in[10];
    const float* ow    = (const float*)d_in[11];
    const float* ob    = (const float*)d_in[12];
    const float* sinks = (const float*)d_in[13];
    const float* rw    = (const float*)d_in[14];
    const float* rb    = (const float*)d_in[15];
    const float* gup   = (const float*)d_in[16];
    const float* gub   = (const float*)d_in[17];
    const float* dwp   = (const float*)d_in[18];
    const float* dwb   = (const float*)d_in[19];
    float* out = (float*)d_out;

    char* p = (char*)d_ws;
    auto alloc = [&](size_t bytes) { char* r = p; p += (bytes + 255) & ~(size_t)255; return r; };
    float*     xnorm  = (float*)alloc((size_t)T_ * H_ * 4);
    _Float16*  xh     = (_Float16*)alloc((size_t)T_ * H_ * 2);
    _Float16*  xl     = (_Float16*)alloc((size_t)T_ * H_ * 2);
    float*     qbuf   = (float*)alloc((size_t)T_ * NH_ * HD_ * 4);
    float*     kbuf   = (float*)alloc((size_t)T_ * NKV_ * HD_ * 4);
    float*     vbuf   = (float*)alloc((size_t)T_ * NKV_ * HD_ * 4);
    _Float16*  ath    = (_Float16*)alloc((size_t)T_ * NH_ * HD_ * 2);
    _Float16*  atl    = (_Float16*)alloc((size_t)T_ * NH_ * HD_ * 2);
    _Float16*  gatedh = (_Float16*)alloc((size_t)T_ * TOPK_ * ED_ * 2);
    _Float16*  qwh    = (_Float16*)alloc((size_t)2048 * H_ * 2);
    _Float16*  qwl    = (_Float16*)alloc((size_t)2048 * H_ * 2);
    _Float16*  kwh    = (_Float16*)alloc((size_t)512 * H_ * 2);
    _Float16*  kwl    = (_Float16*)alloc((size_t)512 * H_ * 2);
    _Float16*  vwh    = (_Float16*)alloc((size_t)512 * H_ * 2);
    _Float16*  vwl    = (_Float16*)alloc((size_t)512 * H_ * 2);
    _Float16*  owh    = (_Float16*)alloc((size_t)H_ * 2048 * 2);
    _Float16*  owl    = (_Float16*)alloc((size_t)H_ * 2048 * 2);
    _Float16*  gupt   = (_Float16*)alloc((size_t)E_ * 2048 * H_ * 2);
    _Float16*  dwnt   = (_Float16*)alloc((size_t)E_ * H_ * ED_ * 2);
    _Float16*  qhb    = (_Float16*)alloc((size_t)T_ * NH_ * HD_ * 2);
    _Float16*  qlb    = (_Float16*)alloc((size_t)T_ * NH_ * HD_ * 2);
    _Float16*  khb    = (_Float16*)alloc((size_t)T_ * NKV_ * HD_ * 2);
    _Float16*  klb    = (_Float16*)alloc((size_t)T_ * NKV_ * HD_ * 2);
    _Float16*  vthb   = (_Float16*)alloc((size_t)T_ * NKV_ * HD_ * 2);
    _Float16*  vtlb   = (_Float16*)alloc((size_t)T_ * NKV_ * HD_ * 2);
    float*     topw   = (float*)alloc(T_ * TOPK_ * 4);
    float*     pwb    = (float*)alloc(T_ * TOPK_ * 4);
    int*       topi   = (int*)alloc(T_ * TOPK_ * 4);
    int*       perm   = (int*)alloc(T_ * TOPK_ * 4);
    int*       counts = (int*)alloc(E_ * 4);
    int*       offs   = (int*)alloc(E_ * 4);
    int*       cursor = (int*)alloc(E_ * 4);
    int*       te     = (int*)alloc(MAXT_ * 4);
    int*       tm     = (int*)alloc(MAXT_ * 4);
    int*       ntt    = (int*)alloc(4);

    // weight conversions
    k_cvts<<<2048, 256, 0, stream>>>(qw, qwh, qwl, 2048 * H_ / 8);
    k_cvts<<<512, 256, 0, stream>>>(kw, kwh, kwl, 512 * H_ / 8);
    k_cvts<<<512, 256, 0, stream>>>(vw, vwh, vwl, 512 * H_ / 8);
    k_cvts<<<2048, 256, 0, stream>>>(ow, owh, owl, H_ * 2048 / 8);
    k_cvt_t<<<dim3(H_ / 64, 2048 / 64, E_), 256, 0, stream>>>(gup, gupt, H_, 2048);
    k_cvt_t<<<dim3(ED_ / 64, H_ / 64, E_), 256, 0, stream>>>(dwp, dwnt, ED_, H_);

    k_rmsnorm<<<T_, 256, 0, stream>>>(hidden, ln1, xnorm, xh, xl);
    // QKV: init C with bias, split-K=4 GEMMs atomically accumulate
    k_initc<<<4096, 256, 0, stream>>>(qb, nullptr, qbuf, 2048, T_ * 2048 / 4);
    k_initc<<<1024, 256, 0, stream>>>(kbia, nullptr, kbuf, 512, T_ * 512 / 4);
    k_initc<<<1024, 256, 0, stream>>>(vbia, nullptr, vbuf, 512, T_ * 512 / 4);
    k_gemm_spk<<<1024, 256, 0, stream>>>(xh, xl, qwh, qwl, qbuf, 2048, H_);
    k_gemm_spk<<<256, 256, 0, stream>>>(xh, xl, kwh, kwl, kbuf, 512, H_);
    k_gemm_spk<<<256, 256, 0, stream>>>(xh, xl, vwh, vwl, vbuf, 512, H_);
    k_rope_sp<<<T_, 256, 0, stream>>>(qbuf, kbuf, cosp, sinp, qhb, qlb, khb, klb);
    k_cvt_vt<<<dim3(32, 2, 16), 256, 0, stream>>>(vbuf, vthb, vtlb);
    k_attn_m<<<256, 256, 0, stream>>>(qhb, qlb, khb, klb, vthb, vtlb, sinks, ath, atl);
    // O-proj: out = hidden + ob + attn @ ow^T (init + split-K atomic)
    k_initc<<<4096, 256, 0, stream>>>(ob, hidden, out, 2048, T_ * 2048 / 4);
    k_gemm_spk<<<1024, 256, 0, stream>>>(ath, atl, owh, owl, out, 2048, H_);
    k_rmsnorm<<<T_, 256, 0, stream>>>(out, ln2, xnorm, xh, xl);
    k_router<<<T_, 256, 0, stream>>>(xnorm, rw, rb, topi, topw);
    k_zero<<<1, 64, 0, stream>>>(counts);
    k_hist<<<(T_ * TOPK_ + 255) / 256, 256, 0, stream>>>(topi, counts);
    k_scan<<<1, 1, 0, stream>>>(counts, offs, cursor, te, tm, ntt);
    k_scatter<<<(T_ * TOPK_ + 255) / 256, 256, 0, stream>>>(topi, topw, cursor, perm, pwb);
    k_moe1<<<MAXT_ * 16, 256, 0, stream>>>(xh, gupt, gub, perm, counts, offs, te, tm, ntt, gatedh);
    k_moe2<<<MAXT_ * 16, 256, 0, stream>>>(gatedh, dwnt, dwb, perm, pwb, counts, offs, te, tm, ntt, out);
}

// Round 12
// 829.890 us; speedup vs baseline: 1.2388x; 1.1293x over previous
//
#include <hip/hip_runtime.h>
#include <hip/hip_bf16.h>
#include <cstdint>

#define B_    2
#define S_    1024
#define H_    2048
#define NH_   32
#define NKV_  8
#define HD_   64
#define T_    (B_*S_)
#define E_    16
#define ED_   1024
#define TOPK_ 4
#define WIN_  128
#define LIMIT_ 7.0f
#define ALPHA_ 1.702f
#define EPS_   1e-6f
#define SCALE_ 0.125f  /* HD^-0.5 */
#define SPLIT_ 2048.0f
#define INV_SPLIT_ 4.8828125e-4f
#define MAXT_ 80      /* max MoE row-tiles of 128: 64 + 16 */
#define NQKV_ 3072    /* fused q(2048)+k(512)+v(512) */

typedef _Float16 half8 __attribute__((ext_vector_type(8)));
typedef _Float16 half4v __attribute__((ext_vector_type(4)));
typedef float floatx4 __attribute__((ext_vector_type(4)));

#define MF16(a,b,c) __builtin_amdgcn_mfma_f32_16x16x32_f16(a,b,c,0,0,0)

__device__ __forceinline__ void gload16(const void* g, void* l) {
    __builtin_amdgcn_global_load_lds((const __attribute__((address_space(1))) void*)g,
                                     (__attribute__((address_space(3))) void*)l, 16, 0, 0);
}

// bijective chunked XCD swizzle (nwg % 8 == 0)
__device__ __forceinline__ int xcd_swz(int bid, int nwg) {
    int cpx = nwg >> 3;
    return (bid & 7) * cpx + (bid >> 3);
}

// ================= C init: C = bias (+res) =================
__global__ __launch_bounds__(256) void k_initc(const float* __restrict__ bias,
                                               const float* __restrict__ res,
                                               float* __restrict__ C, int N, int n4) {
    int i = blockIdx.x * 256 + threadIdx.x;
    if (i >= n4) return;
    int c4 = (i % (N >> 2)) << 2;
    float4 v = *(const float4*)(bias + c4);
    if (res) {
        float4 r = ((const float4*)res)[i];
        v.x += r.x; v.y += r.y; v.z += r.z; v.w += r.w;
    }
    ((float4*)C)[i] = v;
}

// ===== split-fp16 GEMM, split-K=4, double-buffered LDS + counted vmcnt =====
// grid = (N/128) * 16 * 4 (1D). wg: n = wg>>6, m = (wg&63)>>2, ks = wg&3.
__global__ __launch_bounds__(256) void k_gemm_spk(const _Float16* __restrict__ Ah,
                                                  const _Float16* __restrict__ Al,
                                                  const _Float16* __restrict__ Bh,
                                                  const _Float16* __restrict__ Bl,
                                                  float* __restrict__ C, int N, int K) {
    __shared__ _Float16 Ahs[2][128 * 32];
    __shared__ _Float16 Als[2][128 * 32];
    __shared__ _Float16 Bhs[2][128 * 32];
    __shared__ _Float16 Bls[2][128 * 32];
    const int tid = threadIdx.x;
    const int lane = tid & 63;
    const int wid = tid >> 6;
    const int wr = wid >> 1, wc = wid & 1;
    const int wg = xcd_swz(blockIdx.x, gridDim.x);
    const int col0 = (wg >> 6) * 128;
    const int row0 = ((wg & 63) >> 2) * 128;
    const int ks4 = wg & 3;
    const int kbeg = ks4 * (K >> 2), kend = kbeg + (K >> 2);
    floatx4 acc1[4][4], acc2[4][4];
    for (int m = 0; m < 4; ++m)
        for (int n = 0; n < 4; ++n) { acc1[m][n] = (floatx4)0.f; acc2[m][n] = (floatx4)0.f; }
    const int rL = tid >> 2, koff = (tid & 3) * 8;
    const size_t o0 = (size_t)(row0 + rL) * K + koff;
    const size_t o1 = (size_t)(row0 + 64 + rL) * K + koff;
    const size_t p0 = (size_t)(col0 + rL) * K + koff;
    const size_t p1 = (size_t)(col0 + 64 + rL) * K + koff;
#define DSTAGE(buf, kk) do { \
        gload16(Ah + o0 + (kk), Ahs[buf] + tid * 8); gload16(Ah + o1 + (kk), Ahs[buf] + 2048 + tid * 8); \
        gload16(Al + o0 + (kk), Als[buf] + tid * 8); gload16(Al + o1 + (kk), Als[buf] + 2048 + tid * 8); \
        gload16(Bh + p0 + (kk), Bhs[buf] + tid * 8); gload16(Bh + p1 + (kk), Bhs[buf] + 2048 + tid * 8); \
        gload16(Bl + p0 + (kk), Bls[buf] + tid * 8); gload16(Bl + p1 + (kk), Bls[buf] + 2048 + tid * 8); \
    } while (0)
    DSTAGE(0, kbeg);
    int cur = 0;
    for (int k0 = kbeg; k0 < kend; k0 += 32) {
        if (k0 + 32 < kend) {
            DSTAGE(cur ^ 1, k0 + 32);
            asm volatile("s_waitcnt vmcnt(8)" ::: "memory");
        } else {
            asm volatile("s_waitcnt vmcnt(0)" ::: "memory");
        }
        __builtin_amdgcn_s_barrier();
        __builtin_amdgcn_sched_barrier(0);
        const int lk = (lane >> 4) * 8;
        half8 ah[4], al[4], bh[4], bl[4];
#pragma unroll
        for (int m = 0; m < 4; ++m) {
            int ro = (wr * 64 + m * 16 + (lane & 15)) * 32 + lk;
            ah[m] = *(const half8*)&Ahs[cur][ro];
            al[m] = *(const half8*)&Als[cur][ro];
        }
#pragma unroll
        for (int n = 0; n < 4; ++n) {
            int ro = (wc * 64 + n * 16 + (lane & 15)) * 32 + lk;
            bh[n] = *(const half8*)&Bhs[cur][ro];
            bl[n] = *(const half8*)&Bls[cur][ro];
        }
#pragma unroll
        for (int m = 0; m < 4; ++m)
#pragma unroll
            for (int n = 0; n < 4; ++n) {
                acc1[m][n] = MF16(ah[m], bh[n], acc1[m][n]);
                acc2[m][n] = MF16(ah[m], bl[n], acc2[m][n]);
                acc2[m][n] = MF16(al[m], bh[n], acc2[m][n]);
            }
        __builtin_amdgcn_sched_barrier(0);
        __builtin_amdgcn_s_barrier();
        cur ^= 1;
    }
#undef DSTAGE
#pragma unroll
    for (int mf = 0; mf < 4; ++mf)
#pragma unroll
        for (int i = 0; i < 4; ++i) {
            int r = row0 + wr * 64 + mf * 16 + ((lane >> 4) << 2) + i;
#pragma unroll
            for (int nf = 0; nf < 4; ++nf) {
                int c = col0 + wc * 64 + nf * 16 + (lane & 15);
                atomicAdd(&C[(size_t)r * N + c], acc1[mf][nf][i] + acc2[mf][nf][i] * INV_SPLIT_);
            }
        }
}

// ===== MoE MFMA core: BK=64, XOR-swizzled LDS, dbuf + COUNTED vmcnt =====
#define MOE_PROLOG() \
    __shared__ _Float16 As[2][128 * 64]; \
    __shared__ _Float16 Bs[2][128 * 64]; \
    const int tid = threadIdx.x; \
    const int lane = tid & 63; \
    const int wid = tid >> 6; \
    const int wr = wid >> 1, wc = wid & 1; \
    const int rloc = tid >> 3; \
    const int ksw = ((tid & 7) ^ (rloc & 7)) * 8; \
    floatx4 acc[4][4]; \
    for (int m = 0; m < 4; ++m) for (int n = 0; n < 4; ++n) acc[m][n] = (floatx4)0.f;

#define MOE_STAGE(buf, kk) do { \
        _Pragma("unroll") for (int c = 0; c < 4; ++c) { \
            gload16(asrc[c] + (kk), As[buf] + c * 2048 + tid * 8); \
            gload16(bsrc[c] + (kk), Bs[buf] + c * 2048 + tid * 8); \
        } \
    } while (0)

#define MOE_KLOOP(KD) \
    MOE_STAGE(0, 0); \
    { int cur = 0; \
    for (int k0 = 0; k0 < (KD); k0 += 64) { \
        if (k0 + 64 < (KD)) { \
            MOE_STAGE(cur ^ 1, k0 + 64); \
            asm volatile("s_waitcnt vmcnt(8)" ::: "memory"); \
        } else { \
            asm volatile("s_waitcnt vmcnt(0)" ::: "memory"); \
        } \
        __builtin_amdgcn_s_barrier(); \
        __builtin_amdgcn_sched_barrier(0); \
        _Pragma("unroll") for (int s = 0; s < 2; ++s) { \
            const int gc = ((s * 4 + (lane >> 4)) ^ (lane & 7)) * 8; \
            half8 a[4], b[4]; \
            _Pragma("unroll") for (int m = 0; m < 4; ++m) \
                a[m] = *(const half8*)&As[cur][(wr * 64 + m * 16 + (lane & 15)) * 64 + gc]; \
            _Pragma("unroll") for (int n = 0; n < 4; ++n) \
                b[n] = *(const half8*)&Bs[cur][(wc * 64 + n * 16 + (lane & 15)) * 64 + gc]; \
            _Pragma("unroll") for (int m = 0; m < 4; ++m) \
                _Pragma("unroll") for (int n = 0; n < 4; ++n) \
                    acc[m][n] = MF16(a[m], b[n], acc[m][n]); \
        } \
        __builtin_amdgcn_sched_barrier(0); \
        __builtin_amdgcn_s_barrier(); \
        cur ^= 1; \
    } }

// MoE GEMM1: tile-table grid (80x16). gathered A rows; fused GLU -> gated f16
__global__ __launch_bounds__(256) void k_moe1(const _Float16* __restrict__ X,
                                              const _Float16* __restrict__ W,
                                              const float* __restrict__ bias,
                                              const int* __restrict__ perm,
                                              const int* __restrict__ counts,
                                              const int* __restrict__ offs,
                                              const int* __restrict__ te,
                                              const int* __restrict__ tm,
                                              const int* __restrict__ ntt,
                                              _Float16* __restrict__ gated) {
    const int wg = xcd_swz(blockIdx.x, MAXT_ * 16);
    const int tt = wg >> 4;
    if (tt >= ntt[0]) return;
    const int e = te[tt];
    const int m0 = tm[tt];
    const int ne = counts[e];
    const int base = offs[e];
    const int col0 = (wg & 15) * 128;
    MOE_PROLOG();
    const _Float16* asrc[4];
    const _Float16* bsrc[4];
#pragma unroll
    for (int c = 0; c < 4; ++c) {
        int t = perm[base + min(m0 + c * 32 + rloc, ne - 1)];
        asrc[c] = X + (size_t)t * H_ + ksw;
        bsrc[c] = W + ((size_t)e * 2048 + col0 + c * 32 + rloc) * H_ + ksw;
    }
    MOE_KLOOP(H_);
#pragma unroll
    for (int mf = 0; mf < 4; ++mf)
#pragma unroll
        for (int i = 0; i < 4; ++i) {
            int r = m0 + wr * 64 + mf * 16 + ((lane >> 4) << 2) + i;
            bool ok = r < ne;
            int slot = base + r;
#pragma unroll
            for (int nf = 0; nf < 4; ++nf) {
                int c = col0 + wc * 64 + nf * 16 + (lane & 15);
                float v = acc[mf][nf][i] + bias[e * 2048 + c];
                float o = __shfl_xor(v, 1);
                if (ok && !(lane & 1)) {
                    float gt = fminf(v, LIMIT_);
                    float up = fminf(fmaxf(o, -LIMIT_), LIMIT_);
                    float sg = 1.f / (1.f + __expf(-ALPHA_ * gt));
                    gated[(size_t)slot * ED_ + (c >> 1)] = (_Float16)((up + 1.f) * (gt * sg));
                }
            }
        }
}

__global__ __launch_bounds__(256) void k_moe2(const _Float16* __restrict__ G,
                                              const _Float16* __restrict__ W,
                                              const float* __restrict__ bias,
                                              const int* __restrict__ perm,
                                              const float* __restrict__ pw,
                                              const int* __restrict__ counts,
                                              const int* __restrict__ offs,
                                              const int* __restrict__ te,
                                              const int* __restrict__ tm,
                                              const int* __restrict__ ntt,
                                              float* __restrict__ out) {
    const int wg = xcd_swz(blockIdx.x, MAXT_ * 16);
    const int tt = wg >> 4;
    if (tt >= ntt[0]) return;
    const int e = te[tt];
    const int m0 = tm[tt];
    const int ne = counts[e];
    const int base = offs[e];
    const int col0 = (wg & 15) * 128;
    MOE_PROLOG();
    const _Float16* asrc[4];
    const _Float16* bsrc[4];
#pragma unroll
    for (int c = 0; c < 4; ++c) {
        int s = base + min(m0 + c * 32 + rloc, ne - 1);
        asrc[c] = G + (size_t)s * ED_ + ksw;
        bsrc[c] = W + ((size_t)e * H_ + col0 + c * 32 + rloc) * ED_ + ksw;
    }
    MOE_KLOOP(ED_);
#pragma unroll
    for (int mf = 0; mf < 4; ++mf)
#pragma unroll
        for (int i = 0; i < 4; ++i) {
            int r = m0 + wr * 64 + mf * 16 + ((lane >> 4) << 2) + i;
            if (r >= ne) continue;
            int slot = base + r;
            int tok = perm[slot];
            float wgt = pw[slot];
#pragma unroll
            for (int nf = 0; nf < 4; ++nf) {
                int c = col0 + wc * 64 + nf * 16 + (lane & 15);
                atomicAdd(&out[(size_t)tok * H_ + c], wgt * (acc[mf][nf][i] + bias[e * H_ + c]));
            }
        }
}

// ================= conversions =================
// stacked qkv weight conversion + bias stacking: rows 0..2047=qw, 2048..2559=kw, 2560..3071=vw
__global__ __launch_bounds__(256) void k_cvts_qkv(const float* __restrict__ qw,
                                                  const float* __restrict__ kw,
                                                  const float* __restrict__ vw,
                                                  const float* __restrict__ qb,
                                                  const float* __restrict__ kb,
                                                  const float* __restrict__ vb,
                                                  _Float16* __restrict__ dh,
                                                  _Float16* __restrict__ dl,
                                                  float* __restrict__ biasout) {
    const int r = blockIdx.x;
    const int tid = threadIdx.x;
    const float* src = (r < 2048) ? qw + (size_t)r * H_
                     : (r < 2560) ? kw + (size_t)(r - 2048) * H_
                                  : vw + (size_t)(r - 2560) * H_;
    float4 x = ((const float4*)src)[tid * 2], y = ((const float4*)src)[tid * 2 + 1];
    float xs[8] = {x.x, x.y, x.z, x.w, y.x, y.y, y.z, y.w};
    half8 h, l;
#pragma unroll
    for (int j = 0; j < 8; ++j) {
        _Float16 hv = (_Float16)xs[j];
        h[j] = hv;
        l[j] = (_Float16)((xs[j] - (float)hv) * SPLIT_);
    }
    ((half8*)(dh + (size_t)r * H_))[tid] = h;
    ((half8*)(dl + (size_t)r * H_))[tid] = l;
    if (r < 12) {
        int g = r * 256 + tid;
        if (g < NQKV_) {
            float bv = (g < 2048) ? qb[g] : (g < 2560) ? kb[g - 2048] : vb[g - 2560];
            biasout[g] = bv;
        }
    }
}

__global__ __launch_bounds__(256) void k_cvts(const float* __restrict__ s,
                                              _Float16* __restrict__ dh,
                                              _Float16* __restrict__ dl, int n8) {
    int i = blockIdx.x * 256 + threadIdx.x;
    if (i >= n8) return;
    float4 x = ((const float4*)s)[i * 2], y = ((const float4*)s)[i * 2 + 1];
    float xs[8] = {x.x, x.y, x.z, x.w, y.x, y.y, y.z, y.w};
    half8 h, l;
#pragma unroll
    for (int j = 0; j < 8; ++j) {
        _Float16 hv = (_Float16)xs[j];
        h[j] = hv;
        l[j] = (_Float16)((xs[j] - (float)hv) * SPLIT_);
    }
    ((half8*)dh)[i] = h;
    ((half8*)dl)[i] = l;
}

// transpose-convert: src [e][K][N] fp32 -> dst [e][N][K] f16. 64x64 tiles.
__global__ __launch_bounds__(256) void k_cvt_t(const float* __restrict__ src,
                                               _Float16* __restrict__ dst, int K, int N) {
    const int e = blockIdx.z;
    const int k0 = blockIdx.x * 64, n0 = blockIdx.y * 64;
    __shared__ float t[64][65];
    const int tid = threadIdx.x;
    {
        int kr = tid >> 4, nc = (tid & 15) * 4;
#pragma unroll
        for (int j = 0; j < 4; ++j) {
            float4 v = *(const float4*)(src + ((size_t)e * K + k0 + kr + j * 16) * N + n0 + nc);
            t[kr + j * 16][nc] = v.x; t[kr + j * 16][nc + 1] = v.y;
            t[kr + j * 16][nc + 2] = v.z; t[kr + j * 16][nc + 3] = v.w;
        }
    }
    __syncthreads();
    {
        int nr = tid >> 3, kc = (tid & 7) * 8;
#pragma unroll
        for (int j = 0; j < 2; ++j) {
            int n = nr + j * 32;
            half8 o;
#pragma unroll
            for (int i = 0; i < 8; ++i) o[i] = (_Float16)t[kc + i][n];
            *(half8*)(dst + ((size_t)e * N + n0 + n) * K + k0 + kc) = o;
        }
    }
}

// ================= RMSNorm (optional fp32 + split f16 outputs) =================
__global__ __launch_bounds__(256) void k_rmsnorm(const float* __restrict__ x,
                                                 const float* __restrict__ w,
                                                 float* __restrict__ y,
                                                 _Float16* __restrict__ yh,
                                                 _Float16* __restrict__ yl) {
    int t = blockIdx.x;
    const float* row = x + (size_t)t * H_;
    float ss = 0.f;
    for (int i = threadIdx.x; i < H_ / 4; i += 256) {
        float4 v = ((const float4*)row)[i];
        ss += v.x * v.x + v.y * v.y + v.z * v.z + v.w * v.w;
    }
    for (int o = 32; o >= 1; o >>= 1) ss += __shfl_xor(ss, o);
    __shared__ float wsum[4];
    if ((threadIdx.x & 63) == 0) wsum[threadIdx.x >> 6] = ss;
    __syncthreads();
    float tot = wsum[0] + wsum[1] + wsum[2] + wsum[3];
    float r = rsqrtf(tot / (float)H_ + EPS_);
    _Float16* hrow = yh + (size_t)t * H_;
    _Float16* lrow = yl + (size_t)t * H_;
    for (int i = threadIdx.x; i < H_ / 4; i += 256) {
        float4 v = ((const float4*)row)[i];
        float4 g = ((const float4*)w)[i];
        float o4[4];
        o4[0] = v.x * r * g.x; o4[1] = v.y * r * g.y;
        o4[2] = v.z * r * g.z; o4[3] = v.w * r * g.w;
        if (y) ((float4*)(y + (size_t)t * H_))[i] = *(float4*)o4;
        half4v h4, l4;
#pragma unroll
        for (int j = 0; j < 4; ++j) {
            _Float16 hv = (_Float16)o4[j];
            h4[j] = hv;
            l4[j] = (_Float16)((o4[j] - (float)hv) * SPLIT_);
        }
        ((half4v*)hrow)[i] = h4;
        ((half4v*)lrow)[i] = l4;
    }
}

// ======= fused RMSNorm2 + router (fp32-accurate logits, split f16 x out) =======
__global__ __launch_bounds__(256) void k_rms2_router(const float* __restrict__ x,
                                                     const float* __restrict__ w,
                                                     _Float16* __restrict__ yh,
                                                     _Float16* __restrict__ yl,
                                                     const float* __restrict__ rw,
                                                     const float* __restrict__ rb,
                                                     int* __restrict__ topi,
                                                     float* __restrict__ topw) {
    const int t = blockIdx.x;
    const int tid = threadIdx.x;
    const float* row = x + (size_t)t * H_;
    float4 v0 = ((const float4*)row)[tid];
    float4 v1 = ((const float4*)row)[tid + 256];
    float ss = v0.x*v0.x + v0.y*v0.y + v0.z*v0.z + v0.w*v0.w
             + v1.x*v1.x + v1.y*v1.y + v1.z*v1.z + v1.w*v1.w;
    for (int o = 32; o >= 1; o >>= 1) ss += __shfl_xor(ss, o);
    __shared__ float wsum[4];
    if ((tid & 63) == 0) wsum[tid >> 6] = ss;
    __syncthreads();
    float tot = wsum[0] + wsum[1] + wsum[2] + wsum[3];
    float r = rsqrtf(tot / (float)H_ + EPS_);
    float4 g0 = ((const float4*)w)[tid];
    float4 g1 = ((const float4*)w)[tid + 256];
    float o8[8] = {v0.x*r*g0.x, v0.y*r*g0.y, v0.z*r*g0.z, v0.w*r*g0.w,
                   v1.x*r*g1.x, v1.y*r*g1.y, v1.z*r*g1.z, v1.w*r*g1.w};
    _Float16* hrow = yh + (size_t)t * H_;
    _Float16* lrow = yl + (size_t)t * H_;
    {
        half4v h4, l4;
#pragma unroll
        for (int j = 0; j < 4; ++j) {
            _Float16 hv = (_Float16)o8[j];
            h4[j] = hv; l4[j] = (_Float16)((o8[j] - (float)hv) * SPLIT_);
        }
        ((half4v*)hrow)[tid] = h4; ((half4v*)lrow)[tid] = l4;
#pragma unroll
        for (int j = 0; j < 4; ++j) {
            _Float16 hv = (_Float16)o8[4 + j];
            h4[j] = hv; l4[j] = (_Float16)((o8[4 + j] - (float)hv) * SPLIT_);
        }
        ((half4v*)hrow)[tid + 256] = h4; ((half4v*)lrow)[tid + 256] = l4;
    }
    float pe[E_];
#pragma unroll
    for (int e = 0; e < E_; ++e) {
        const float* wr = rw + (size_t)e * H_;
        float4 a = ((const float4*)wr)[tid];
        float4 b = ((const float4*)wr)[tid + 256];
        pe[e] = o8[0]*a.x + o8[1]*a.y + o8[2]*a.z + o8[3]*a.w
              + o8[4]*b.x + o8[5]*b.y + o8[6]*b.z + o8[7]*b.w;
    }
#pragma unroll
    for (int e = 0; e < E_; ++e)
        for (int o = 32; o >= 1; o >>= 1) pe[e] += __shfl_xor(pe[e], o);
    __shared__ float part[4][E_];
    if ((tid & 63) == 0)
#pragma unroll
        for (int e = 0; e < E_; ++e) part[tid >> 6][e] = pe[e];
    __syncthreads();
    __shared__ float logits[E_];
    if (tid < E_) logits[tid] = rb[tid] + part[0][tid] + part[1][tid] + part[2][tid] + part[3][tid];
    __syncthreads();
    if (tid == 0) {
        float tv[4]; int ti4[4];
        unsigned used = 0;
        for (int s3 = 0; s3 < 4; s3++) {
            float best = -3.0e38f; int bi = 0;
            for (int e2 = 0; e2 < E_; e2++)
                if (!((used >> e2) & 1) && logits[e2] > best) { best = logits[e2]; bi = e2; }
            used |= 1u << bi; tv[s3] = best; ti4[s3] = bi;
        }
        float mx = tv[0], pex[4], sum = 0.f;
        for (int s3 = 0; s3 < 4; s3++) { pex[s3] = __expf(tv[s3] - mx); sum += pex[s3]; }
        for (int s3 = 0; s3 < 4; s3++) {
            topw[t * 4 + s3] = pex[s3] / sum;
            topi[t * 4 + s3] = ti4[s3];
        }
    }
}

// ======= fused RoPE (blocks 0..2047) + V transpose-split (blocks 2048..3071) ====
__global__ __launch_bounds__(256) void k_rope_vt(const float* __restrict__ qkv,
                                                 const float* __restrict__ cs,
                                                 const float* __restrict__ sn,
                                                 _Float16* __restrict__ qh, _Float16* __restrict__ ql,
                                                 _Float16* __restrict__ kh, _Float16* __restrict__ kl,
                                                 _Float16* __restrict__ vth, _Float16* __restrict__ vtl) {
    const int bid = blockIdx.x;
    const int tid = threadIdx.x;
    if (bid < T_) {
        int t = bid;
        int b = t >> 10, s = t & 1023;
        size_t cb = (size_t)t * 64;
        const float* rowsrc = qkv + (size_t)t * NQKV_;
        for (int p = tid; p < 40 * 32; p += 256) {
            int head = p >> 5, d = p & 31;
            float c1 = cs[cb + d],      s1v = sn[cb + d];
            float c2 = cs[cb + d + 32], s2v = sn[cb + d + 32];
            float x1, x2; size_t dst;
            _Float16 *oh, *ol;
            if (head < 32) {
                const float* src = rowsrc + head * 64;
                x1 = src[d]; x2 = src[d + 32];
                dst = (((size_t)b * 32 + head) * 1024 + s) * 64 + d;
                oh = qh; ol = ql;
            } else {
                int hk = head - 32;
                const float* src = rowsrc + 2048 + hk * 64;
                x1 = src[d]; x2 = src[d + 32];
                dst = (((size_t)b * 8 + hk) * 1024 + s) * 64 + d;
                oh = kh; ol = kl;
            }
            float r1 = x1 * c1 - x2 * s1v;
            float r2 = x2 * c2 + x1 * s2v;
            _Float16 h1 = (_Float16)r1;
            oh[dst] = h1; ol[dst] = (_Float16)((r1 - (float)h1) * SPLIT_);
            _Float16 h2 = (_Float16)r2;
            oh[dst + 32] = h2; ol[dst + 32] = (_Float16)((r2 - (float)h2) * SPLIT_);
        }
    } else {
        int vb = bid - T_;
        int s0 = (vb & 31) * 32;
        int rest = vb >> 5;
        int d0 = (rest & 1) * 32;
        int bk = rest >> 1;          // b*8 + kvh
        int b = bk >> 3, kvh = bk & 7;
        __shared__ float tl[32][33];
        {
            int sr = tid >> 3, dc = (tid & 7) * 4;
            float4 v = *(const float4*)(qkv + (size_t)(b * 1024 + s0 + sr) * NQKV_ + 2560 + kvh * 64 + d0 + dc);
            tl[sr][dc] = v.x; tl[sr][dc + 1] = v.y; tl[sr][dc + 2] = v.z; tl[sr][dc + 3] = v.w;
        }
        __syncthreads();
        {
            int dr = tid >> 3, sc = (tid & 7) * 4;
            half4v h4, l4;
#pragma unroll
            for (int j = 0; j < 4; ++j) {
                float x = tl[sc + j][dr];
                _Float16 hv = (_Float16)x;
                h4[j] = hv;
                l4[j] = (_Float16)((x - (float)hv) * SPLIT_);
            }
            size_t dst = (size_t)(bk * 64 + d0 + dr) * 1024 + s0 + sc;
            *(half4v*)(vth + dst) = h4;
            *(half4v*)(vtl + dst) = l4;
        }
    }
}

// ================= MFMA flash attention (split-fp16, fp32-accurate) ===========
#define PPITCH 68
union U8h { unsigned w[4]; half8 v; };

__global__ __launch_bounds__(256, 1) void k_attn_m(
        const _Float16* __restrict__ qhg, const _Float16* __restrict__ qlg,
        const _Float16* __restrict__ khg, const _Float16* __restrict__ klg,
        const _Float16* __restrict__ vthg, const _Float16* __restrict__ vtlg,
        const float* __restrict__ sinks,
        _Float16* __restrict__ ath, _Float16* __restrict__ atl) {
    __shared__ _Float16 Khs[4096], Kls[4096], Vhs[4096], Vls[4096];
    __shared__ unsigned Pp[4][64 * PPITCH];
    const int bx = blockIdx.x;
    const int b = bx >> 7, kvh = (bx >> 4) & 7, tile = bx & 15;
    const int i0 = tile * 64;
    const int tid = threadIdx.x, lane = tid & 63, wid = tid >> 6;
    const int l15 = lane & 15, g = lane >> 4;
    const int h = kvh * 4 + wid;
    const size_t kvbase = (size_t)(b * 8 + kvh) * 1024 * 64;
    const size_t vbase  = (size_t)(b * 8 + kvh) * 64 * 1024;
    half8 aqh[4][2], aql[4][2];
    {
        const size_t qb0 = ((size_t)(b * 32 + h) * 1024 + i0) * 64;
#pragma unroll
        for (int mf = 0; mf < 4; ++mf)
#pragma unroll
            for (int ks = 0; ks < 2; ++ks) {
                size_t a = qb0 + (size_t)(16 * mf + l15) * 64 + ks * 32 + g * 8;
                aqh[mf][ks] = *(const half8*)(qhg + a);
                aql[mf][ks] = *(const half8*)(qlg + a);
            }
    }
    floatx4 o1[4][4], o2[4][4];
    float m_run[4][4], l_run[4][4];
#pragma unroll
    for (int mf = 0; mf < 4; ++mf)
#pragma unroll
        for (int x = 0; x < 4; ++x) {
            o1[mf][x] = (floatx4)0.f; o2[mf][x] = (floatx4)0.f;
            m_run[mf][x] = -1e20f; l_run[mf][x] = 0.f;
        }
    const int nch = tile >= 2 ? 3 : tile + 1;
    const int jr = tid >> 3, cc = tid & 7;
    unsigned* pw = &Pp[wid][0];
    for (int ci = 0; ci < nch; ++ci) {
        const int jb = i0 - 64 * (nch - 1 - ci);
        __syncthreads();
        {
            const int sw0 = (cc ^ (jr & 7)) * 8;
            const size_t k0 = kvbase + (size_t)(jb + jr) * 64 + sw0;
            const size_t k1 = kvbase + (size_t)(jb + jr + 32) * 64 + sw0;
            gload16(khg + k0, Khs + tid * 8);
            gload16(khg + k1, Khs + 2048 + tid * 8);
            gload16(klg + k0, Kls + tid * 8);
            gload16(klg + k1, Kls + 2048 + tid * 8);
            const size_t v0 = vbase + (size_t)jr * 1024 + jb + sw0;
            const size_t v1 = vbase + (size_t)(jr + 32) * 1024 + jb + sw0;
            gload16(vthg + v0, Vhs + tid * 8);
            gload16(vthg + v1, Vhs + 2048 + tid * 8);
            gload16(vtlg + v0, Vls + tid * 8);
            gload16(vtlg + v1, Vls + 2048 + tid * 8);
        }
        __syncthreads();
        floatx4 s1[4][4], s2[4][4];
#pragma unroll
        for (int mf = 0; mf < 4; ++mf)
#pragma unroll
            for (int nf = 0; nf < 4; ++nf) { s1[mf][nf] = (floatx4)0.f; s2[mf][nf] = (floatx4)0.f; }
#pragma unroll
        for (int ks = 0; ks < 2; ++ks) {
            half8 kbh[4], kbl[4];
#pragma unroll
            for (int nf = 0; nf < 4; ++nf) {
                int j = l15 + 16 * nf;
                int c = (g + 4 * ks) ^ (j & 7);
                kbh[nf] = *(const half8*)&Khs[j * 64 + c * 8];
                kbl[nf] = *(const half8*)&Kls[j * 64 + c * 8];
            }
#pragma unroll
            for (int mf = 0; mf < 4; ++mf)
#pragma unroll
                for (int nf = 0; nf < 4; ++nf) {
                    s1[mf][nf] = MF16(aqh[mf][ks], kbh[nf], s1[mf][nf]);
                    s2[mf][nf] = MF16(aqh[mf][ks], kbl[nf], s2[mf][nf]);
                    s2[mf][nf] = MF16(aql[mf][ks], kbh[nf], s2[mf][nf]);
                }
        }
#pragma unroll
        for (int mf = 0; mf < 4; ++mf)
#pragma unroll
            for (int reg = 0; reg < 4; ++reg) {
                int i = i0 + 16 * mf + g * 4 + reg;
                float best = -1e30f;
#pragma unroll
                for (int nf = 0; nf < 4; ++nf) {
                    int j = jb + 16 * nf + l15;
                    float sv = (s1[mf][nf][reg] + s2[mf][nf][reg] * INV_SPLIT_) * SCALE_;
                    bool ok = (j <= i) && (i - j < WIN_);
                    sv = ok ? sv : -1e30f;
                    s1[mf][nf][reg] = sv;
                    best = fmaxf(best, sv);
                }
                for (int off = 1; off < 16; off <<= 1) best = fmaxf(best, __shfl_xor(best, off));
                float nm = fmaxf(m_run[mf][reg], best);
                float sc = __expf(m_run[mf][reg] - nm);
                m_run[mf][reg] = nm;
                l_run[mf][reg] *= sc;
#pragma unroll
                for (int nf = 0; nf < 4; ++nf) { o1[mf][nf][reg] *= sc; o2[mf][nf][reg] *= sc; }
            }
#pragma unroll
        for (int mf = 0; mf < 4; ++mf)
#pragma unroll
            for (int nf = 0; nf < 4; ++nf)
#pragma unroll
                for (int reg = 0; reg < 4; ++reg) {
                    float pv = __expf(s1[mf][nf][reg] - m_run[mf][reg]);
                    l_run[mf][reg] += pv;
                    _Float16 hv = (_Float16)pv;
                    _Float16 lv = (_Float16)((pv - (float)hv) * SPLIT_);
                    union { _Float16 h; unsigned short u; } ch, cl;
                    ch.h = hv; cl.h = lv;
                    int t = 16 * mf + g * 4 + reg, jj = l15 + 16 * nf;
                    pw[t * PPITCH + jj] = (unsigned)ch.u | ((unsigned)cl.u << 16);
                }
#pragma unroll
        for (int ks = 0; ks < 2; ++ks) {
            half8 bvh[4], bvl[4];
#pragma unroll
            for (int nf = 0; nf < 4; ++nf) {
                int d = l15 + 16 * nf;
                int c = (g + 4 * ks) ^ (d & 7);
                bvh[nf] = *(const half8*)&Vhs[d * 64 + c * 8];
                bvl[nf] = *(const half8*)&Vls[d * 64 + c * 8];
            }
#pragma unroll
            for (int mf = 0; mf < 4; ++mf) {
                const unsigned* pr = &pw[(16 * mf + l15) * PPITCH + 32 * ks + g * 8];
                int4 va = *(const int4*)pr;
                int4 vb = *(const int4*)(pr + 4);
                U8h ph, pl;
                ph.w[0] = ((unsigned)va.x & 0xffffu) | ((unsigned)va.y << 16);
                ph.w[1] = ((unsigned)va.z & 0xffffu) | ((unsigned)va.w << 16);
                ph.w[2] = ((unsigned)vb.x & 0xffffu) | ((unsigned)vb.y << 16);
                ph.w[3] = ((unsigned)vb.z & 0xffffu) | ((unsigned)vb.w << 16);
                pl.w[0] = ((unsigned)va.x >> 16) | ((unsigned)va.y & 0xffff0000u);
                pl.w[1] = ((unsigned)va.z >> 16) | ((unsigned)va.w & 0xffff0000u);
                pl.w[2] = ((unsigned)vb.x >> 16) | ((unsigned)vb.y & 0xffff0000u);
                pl.w[3] = ((unsigned)vb.z >> 16) | ((unsigned)vb.w & 0xffff0000u);
#pragma unroll
                for (int nf = 0; nf < 4; ++nf) {
                    o1[mf][nf] = MF16(ph.v, bvh[nf], o1[mf][nf]);
                    o2[mf][nf] = MF16(ph.v, bvl[nf], o2[mf][nf]);
                    o2[mf][nf] = MF16(pl.v, bvh[nf], o2[mf][nf]);
                }
            }
        }
    }
    const float sinkv = sinks[h];
    float inv[4][4];
#pragma unroll
    for (int mf = 0; mf < 4; ++mf)
#pragma unroll
        for (int reg = 0; reg < 4; ++reg) {
            float l = l_run[mf][reg];
            for (int off = 1; off < 16; off <<= 1) l += __shfl_xor(l, off);
            inv[mf][reg] = 1.f / (l + __expf(sinkv - m_run[mf][reg]));
        }
#pragma unroll
    for (int mf = 0; mf < 4; ++mf)
#pragma unroll
        for (int nf = 0; nf < 4; ++nf)
#pragma unroll
            for (int reg = 0; reg < 4; ++reg) {
                int t = i0 + 16 * mf + g * 4 + reg;
                int d = l15 + 16 * nf;
                float ov = (o1[mf][nf][reg] + o2[mf][nf][reg] * INV_SPLIT_) * inv[mf][reg];
                size_t idx = ((size_t)(b * 1024 + t) * 32 + h) * 64 + d;
                _Float16 hv = (_Float16)ov;
                ath[idx] = hv;
                atl[idx] = (_Float16)((ov - (float)hv) * SPLIT_);
            }
}

// ======= fused MoE prep: hist + scan + tile table + scatter (one block) =======
__global__ __launch_bounds__(1024) void k_route_build(const int* __restrict__ topi,
                                                      const float* __restrict__ topw,
                                                      int* __restrict__ counts,
                                                      int* __restrict__ offs,
                                                      int* __restrict__ perm,
                                                      float* __restrict__ pw,
                                                      int* __restrict__ te,
                                                      int* __restrict__ tm,
                                                      int* __restrict__ ntt) {
    __shared__ int cnt[E_], cur[E_];
    const int tid = threadIdx.x;
    if (tid < E_) cnt[tid] = 0;
    __syncthreads();
    for (int g = tid; g < T_ * TOPK_; g += 1024) atomicAdd(&cnt[topi[g]], 1);
    __syncthreads();
    if (tid == 0) {
        int run = 0, t = 0;
        for (int e = 0; e < E_; e++) {
            offs[e] = run; cur[e] = run; counts[e] = cnt[e];
            for (int m0 = 0; m0 < cnt[e]; m0 += 128) { te[t] = e; tm[t] = m0; t++; }
            run += cnt[e];
        }
        ntt[0] = t;
    }
    __syncthreads();
    for (int g = tid; g < T_ * TOPK_; g += 1024) {
        int pos = atomicAdd(&cur[topi[g]], 1);
        perm[pos] = g >> 2;
        pw[pos] = topw[g];
    }
}

// ================= launch =================
extern "C" void kernel_launch(void* const* d_in, const int* in_sizes, int n_in,
                              void* d_out, int out_size, void* d_ws, size_t ws_size,
                              hipStream_t stream) {
    const float* hidden = (const float*)d_in[0];
    const float* cosp  = (const float*)d_in[1];
    const float* sinp  = (const float*)d_in[2];
    const float* ln1   = (const float*)d_in[3];
    const float* ln2   = (const float*)d_in[4];
    const float* qw    = (const float*)d_in[5];
    const float* qb    = (const float*)d_in[6];
    const float* kw    = (const float*)d_in[7];
    const float* kbia  = (const float*)d_in[8];
    const float* vw    = (const float*)d_in[9];
    const float* vbia  = (const float*)d_in[10];
    const float* ow    = (const float*)d_in[11];
    const float* ob    = (const float*)d_in[12];
    const float* sinks = (const float*)d_in[13];
    const float* rw    = (const float*)d_in[14];
    const float* rb    = (const float*)d_in[15];
    const float* gup   = (const float*)d_in[16];
    const float* gub   = (const float*)d_in[17];
    const float* dwp   = (const float*)d_in[18];
    const float* dwb   = (const float*)d_in[19];
    float* out = (float*)d_out;

    char* p = (char*)d_ws;
    auto alloc = [&](size_t bytes) { char* r = p; p += (bytes + 255) & ~(size_t)255; return r; };
    _Float16*  xh     = (_Float16*)alloc((size_t)T_ * H_ * 2);
    _Float16*  xl     = (_Float16*)alloc((size_t)T_ * H_ * 2);
    float*     qkvbuf = (float*)alloc((size_t)T_ * NQKV_ * 4);
    _Float16*  ath    = (_Float16*)alloc((size_t)T_ * NH_ * HD_ * 2);
    _Float16*  atl    = (_Float16*)alloc((size_t)T_ * NH_ * HD_ * 2);
    _Float16*  gatedh = (_Float16*)alloc((size_t)T_ * TOPK_ * ED_ * 2);
    _Float16*  qkvwh  = (_Float16*)alloc((size_t)NQKV_ * H_ * 2);
    _Float16*  qkvwl  = (_Float16*)alloc((size_t)NQKV_ * H_ * 2);
    float*     qkvbias= (float*)alloc(NQKV_ * 4);
    _Float16*  owh    = (_Float16*)alloc((size_t)H_ * 2048 * 2);
    _Float16*  owl    = (_Float16*)alloc((size_t)H_ * 2048 * 2);
    _Float16*  gupt   = (_Float16*)alloc((size_t)E_ * 2048 * H_ * 2);
    _Float16*  dwnt   = (_Float16*)alloc((size_t)E_ * H_ * ED_ * 2);
    _Float16*  qhb    = (_Float16*)alloc((size_t)T_ * NH_ * HD_ * 2);
    _Float16*  qlb    = (_Float16*)alloc((size_t)T_ * NH_ * HD_ * 2);
    _Float16*  khb    = (_Float16*)alloc((size_t)T_ * NKV_ * HD_ * 2);
    _Float16*  klb    = (_Float16*)alloc((size_t)T_ * NKV_ * HD_ * 2);
    _Float16*  vthb   = (_Float16*)alloc((size_t)T_ * NKV_ * HD_ * 2);
    _Float16*  vtlb   = (_Float16*)alloc((size_t)T_ * NKV_ * HD_ * 2);
    float*     topw   = (float*)alloc(T_ * TOPK_ * 4);
    float*     pwb    = (float*)alloc(T_ * TOPK_ * 4);
    int*       topi   = (int*)alloc(T_ * TOPK_ * 4);
    int*       perm   = (int*)alloc(T_ * TOPK_ * 4);
    int*       counts = (int*)alloc(E_ * 4);
    int*       offs   = (int*)alloc(E_ * 4);
    int*       te     = (int*)alloc(MAXT_ * 4);
    int*       tm     = (int*)alloc(MAXT_ * 4);
    int*       ntt    = (int*)alloc(4);

    // weight conversions (stacked QKV + O + expert transposes)
    k_cvts_qkv<<<NQKV_, 256, 0, stream>>>(qw, kw, vw, qb, kbia, vbia, qkvwh, qkvwl, qkvbias);
    k_cvts<<<2048, 256, 0, stream>>>(ow, owh, owl, H_ * 2048 / 8);
    k_cvt_t<<<dim3(H_ / 64, 2048 / 64, E_), 256, 0, stream>>>(gup, gupt, H_, 2048);
    k_cvt_t<<<dim3(ED_ / 64, H_ / 64, E_), 256, 0, stream>>>(dwp, dwnt, ED_, H_);

    k_rmsnorm<<<T_, 256, 0, stream>>>(hidden, ln1, nullptr, xh, xl);
    // fused QKV: init with stacked bias, split-K=4 GEMM into [T][3072]
    k_initc<<<(T_ * NQKV_ / 4 + 255) / 256, 256, 0, stream>>>(qkvbias, nullptr, qkvbuf, NQKV_, T_ * NQKV_ / 4);
    k_gemm_spk<<<(NQKV_ / 128) * 64, 256, 0, stream>>>(xh, xl, qkvwh, qkvwl, qkvbuf, NQKV_, H_);
    k_rope_vt<<<T_ + 1024, 256, 0, stream>>>(qkvbuf, cosp, sinp, qhb, qlb, khb, klb, vthb, vtlb);
    k_attn_m<<<256, 256, 0, stream>>>(qhb, qlb, khb, klb, vthb, vtlb, sinks, ath, atl);
    // O-proj: out = hidden + ob + attn @ ow^T (init + split-K atomic)
    k_initc<<<4096, 256, 0, stream>>>(ob, hidden, out, 2048, T_ * 2048 / 4);
    k_gemm_spk<<<1024, 256, 0, stream>>>(ath, atl, owh, owl, out, 2048, H_);
    // fused RMSNorm2 + router
    k_rms2_router<<<T_, 256, 0, stream>>>(out, ln2, xh, xl, rw, rb, topi, topw);
    k_route_build<<<1, 1024, 0, stream>>>(topi, topw, counts, offs, perm, pwb, te, tm, ntt);
    k_moe1<<<MAXT_ * 16, 256, 0, stream>>>(xh, gupt, gub, perm, counts, offs, te, tm, ntt, gatedh);
    k_moe2<<<MAXT_ * 16, 256, 0, stream>>>(gatedh, dwnt, dwb, perm, pwb, counts, offs, te, tm, ntt, out);
}

// Round 13
// 805.432 us; speedup vs baseline: 1.2764x; 1.0304x over previous
//
#include <hip/hip_runtime.h>
#include <hip/hip_bf16.h>
#include <cstdint>

#define B_    2
#define S_    1024
#define H_    2048
#define NH_   32
#define NKV_  8
#define HD_   64
#define T_    (B_*S_)
#define E_    16
#define ED_   1024
#define TOPK_ 4
#define WIN_  128
#define LIMIT_ 7.0f
#define ALPHA_ 1.702f
#define EPS_   1e-6f
#define SCALE_ 0.125f  /* HD^-0.5 */
#define SPLIT_ 2048.0f
#define INV_SPLIT_ 4.8828125e-4f
#define MAXT_ 80      /* max MoE row-tiles of 128: 64 + 16 */
#define NQKV_ 3072    /* fused q(2048)+k(512)+v(512) */

typedef _Float16 half8 __attribute__((ext_vector_type(8)));
typedef _Float16 half4v __attribute__((ext_vector_type(4)));
typedef float floatx4 __attribute__((ext_vector_type(4)));

#define MF16(a,b,c) __builtin_amdgcn_mfma_f32_16x16x32_f16(a,b,c,0,0,0)

__device__ __forceinline__ void gload16(const void* g, void* l) {
    __builtin_amdgcn_global_load_lds((const __attribute__((address_space(1))) void*)g,
                                     (__attribute__((address_space(3))) void*)l, 16, 0, 0);
}

// bijective chunked XCD swizzle (nwg % 8 == 0)
__device__ __forceinline__ int xcd_swz(int bid, int nwg) {
    int cpx = nwg >> 3;
    return (bid & 7) * cpx + (bid >> 3);
}

// ================= C init: C = bias (+res) =================
__global__ __launch_bounds__(256) void k_initc(const float* __restrict__ bias,
                                               const float* __restrict__ res,
                                               float* __restrict__ C, int N, int n4) {
    int i = blockIdx.x * 256 + threadIdx.x;
    if (i >= n4) return;
    int c4 = (i % (N >> 2)) << 2;
    float4 v = *(const float4*)(bias + c4);
    if (res) {
        float4 r = ((const float4*)res)[i];
        v.x += r.x; v.y += r.y; v.z += r.z; v.w += r.w;
    }
    ((float4*)C)[i] = v;
}

// ===== shared dense-GEMM body: BK=32 dbuf + counted vmcnt + chunk-XOR(row&3) ====
// staging: thread tid stages 16B chunk (tid&3) of row (tid>>2); source chunk
// pre-swizzled by ^(row&3); reads XOR the same way (both-sides rule).
#define DG_PROLog() \
    __shared__ _Float16 Ahs[2][128 * 32]; \
    __shared__ _Float16 Als[2][128 * 32]; \
    __shared__ _Float16 Bhs[2][128 * 32]; \
    __shared__ _Float16 Bls[2][128 * 32]; \
    const int tid = threadIdx.x; \
    const int lane = tid & 63; \
    const int wid = tid >> 6; \
    const int wr = wid >> 1, wc = wid & 1; \
    const int l15 = lane & 15, g4 = lane >> 4; \
    floatx4 acc1[4][4], acc2[4][4]; \
    for (int m = 0; m < 4; ++m) \
        for (int n = 0; n < 4; ++n) { acc1[m][n] = (floatx4)0.f; acc2[m][n] = (floatx4)0.f; } \
    const int rL = tid >> 2; \
    const int koff = (((tid & 3) ^ (rL & 3))) * 8;

#define DG_STAGE(buf, kk) do { \
        gload16(Ah + o0 + (kk), Ahs[buf] + tid * 8); gload16(Ah + o1 + (kk), Ahs[buf] + 2048 + tid * 8); \
        gload16(Al + o0 + (kk), Als[buf] + tid * 8); gload16(Al + o1 + (kk), Als[buf] + 2048 + tid * 8); \
        gload16(Bh + p0 + (kk), Bhs[buf] + tid * 8); gload16(Bh + p1 + (kk), Bhs[buf] + 2048 + tid * 8); \
        gload16(Bl + p0 + (kk), Bls[buf] + tid * 8); gload16(Bl + p1 + (kk), Bls[buf] + 2048 + tid * 8); \
    } while (0)

#define DG_KLOOP(KB, KE) \
    DG_STAGE(0, KB); \
    { int cur = 0; \
    for (int k0 = (KB); k0 < (KE); k0 += 32) { \
        if (k0 + 32 < (KE)) { \
            DG_STAGE(cur ^ 1, k0 + 32); \
            asm volatile("s_waitcnt vmcnt(8)" ::: "memory"); \
        } else { \
            asm volatile("s_waitcnt vmcnt(0)" ::: "memory"); \
        } \
        __builtin_amdgcn_s_barrier(); \
        __builtin_amdgcn_sched_barrier(0); \
        half8 ah[4], al[4], bh[4], bl[4]; \
        _Pragma("unroll") for (int m = 0; m < 4; ++m) { \
            int ra = wr * 64 + m * 16 + l15; \
            int ro = ra * 32 + ((g4 ^ (ra & 3)) * 8); \
            ah[m] = *(const half8*)&Ahs[cur][ro]; \
            al[m] = *(const half8*)&Als[cur][ro]; \
        } \
        _Pragma("unroll") for (int n = 0; n < 4; ++n) { \
            int rb = wc * 64 + n * 16 + l15; \
            int ro = rb * 32 + ((g4 ^ (rb & 3)) * 8); \
            bh[n] = *(const half8*)&Bhs[cur][ro]; \
            bl[n] = *(const half8*)&Bls[cur][ro]; \
        } \
        _Pragma("unroll") for (int m = 0; m < 4; ++m) \
            _Pragma("unroll") for (int n = 0; n < 4; ++n) { \
                acc1[m][n] = MF16(ah[m], bh[n], acc1[m][n]); \
                acc2[m][n] = MF16(ah[m], bl[n], acc2[m][n]); \
                acc2[m][n] = MF16(al[m], bh[n], acc2[m][n]); \
            } \
        __builtin_amdgcn_sched_barrier(0); \
        __builtin_amdgcn_s_barrier(); \
        cur ^= 1; \
    } }

// QKV GEMM: no split-K (384 natural blocks), bias epilogue, plain stores
__global__ __launch_bounds__(256) void k_gemm_qkv(const _Float16* __restrict__ Ah,
                                                  const _Float16* __restrict__ Al,
                                                  const _Float16* __restrict__ Bh,
                                                  const _Float16* __restrict__ Bl,
                                                  const float* __restrict__ bias,
                                                  float* __restrict__ C, int N, int K) {
    const int wg = xcd_swz(blockIdx.x, gridDim.x);
    const int col0 = (wg >> 4) * 128;
    const int row0 = (wg & 15) * 128;
    DG_PROLog();
    const size_t o0 = (size_t)(row0 + rL) * K + koff;
    const size_t o1 = (size_t)(row0 + 64 + rL) * K + koff;
    const size_t p0 = (size_t)(col0 + rL) * K + koff;
    const size_t p1 = (size_t)(col0 + 64 + rL) * K + koff;
    DG_KLOOP(0, K);
#pragma unroll
    for (int mf = 0; mf < 4; ++mf)
#pragma unroll
        for (int i = 0; i < 4; ++i) {
            int r = row0 + wr * 64 + mf * 16 + g4 * 4 + i;
#pragma unroll
            for (int nf = 0; nf < 4; ++nf) {
                int c = col0 + wc * 64 + nf * 16 + l15;
                C[(size_t)r * N + c] = acc1[mf][nf][i] + acc2[mf][nf][i] * INV_SPLIT_ + bias[c];
            }
        }
}

// O-proj GEMM: split-K=2 (512 blocks), atomicAdd into pre-initialized C
__global__ __launch_bounds__(256) void k_gemm_spk2(const _Float16* __restrict__ Ah,
                                                   const _Float16* __restrict__ Al,
                                                   const _Float16* __restrict__ Bh,
                                                   const _Float16* __restrict__ Bl,
                                                   float* __restrict__ C, int N, int K) {
    const int wg = xcd_swz(blockIdx.x, gridDim.x);
    const int col0 = (wg >> 5) * 128;
    const int row0 = ((wg >> 1) & 15) * 128;
    const int ks2 = wg & 1;
    const int kbeg = ks2 * (K >> 1), kend = kbeg + (K >> 1);
    DG_PROLog();
    const size_t o0 = (size_t)(row0 + rL) * K + koff;
    const size_t o1 = (size_t)(row0 + 64 + rL) * K + koff;
    const size_t p0 = (size_t)(col0 + rL) * K + koff;
    const size_t p1 = (size_t)(col0 + 64 + rL) * K + koff;
    DG_KLOOP(kbeg, kend);
#pragma unroll
    for (int mf = 0; mf < 4; ++mf)
#pragma unroll
        for (int i = 0; i < 4; ++i) {
            int r = row0 + wr * 64 + mf * 16 + g4 * 4 + i;
#pragma unroll
            for (int nf = 0; nf < 4; ++nf) {
                int c = col0 + wc * 64 + nf * 16 + l15;
                atomicAdd(&C[(size_t)r * N + c], acc1[mf][nf][i] + acc2[mf][nf][i] * INV_SPLIT_);
            }
        }
}

// ===== MoE MFMA core: BK=64, XOR-swizzled LDS, dbuf + COUNTED vmcnt =====
#define MOE_PROLOG() \
    __shared__ _Float16 As[2][128 * 64]; \
    __shared__ _Float16 Bs[2][128 * 64]; \
    const int tid = threadIdx.x; \
    const int lane = tid & 63; \
    const int wid = tid >> 6; \
    const int wr = wid >> 1, wc = wid & 1; \
    const int rloc = tid >> 3; \
    const int ksw = ((tid & 7) ^ (rloc & 7)) * 8; \
    floatx4 acc[4][4]; \
    for (int m = 0; m < 4; ++m) for (int n = 0; n < 4; ++n) acc[m][n] = (floatx4)0.f;

#define MOE_STAGE(buf, kk) do { \
        _Pragma("unroll") for (int c = 0; c < 4; ++c) { \
            gload16(asrc[c] + (kk), As[buf] + c * 2048 + tid * 8); \
            gload16(bsrc[c] + (kk), Bs[buf] + c * 2048 + tid * 8); \
        } \
    } while (0)

#define MOE_KLOOP(KD) \
    MOE_STAGE(0, 0); \
    { int cur = 0; \
    for (int k0 = 0; k0 < (KD); k0 += 64) { \
        if (k0 + 64 < (KD)) { \
            MOE_STAGE(cur ^ 1, k0 + 64); \
            asm volatile("s_waitcnt vmcnt(8)" ::: "memory"); \
        } else { \
            asm volatile("s_waitcnt vmcnt(0)" ::: "memory"); \
        } \
        __builtin_amdgcn_s_barrier(); \
        __builtin_amdgcn_sched_barrier(0); \
        _Pragma("unroll") for (int s = 0; s < 2; ++s) { \
            const int gc = ((s * 4 + (lane >> 4)) ^ (lane & 7)) * 8; \
            half8 a[4], b[4]; \
            _Pragma("unroll") for (int m = 0; m < 4; ++m) \
                a[m] = *(const half8*)&As[cur][(wr * 64 + m * 16 + (lane & 15)) * 64 + gc]; \
            _Pragma("unroll") for (int n = 0; n < 4; ++n) \
                b[n] = *(const half8*)&Bs[cur][(wc * 64 + n * 16 + (lane & 15)) * 64 + gc]; \
            _Pragma("unroll") for (int m = 0; m < 4; ++m) \
                _Pragma("unroll") for (int n = 0; n < 4; ++n) \
                    acc[m][n] = MF16(a[m], b[n], acc[m][n]); \
        } \
        __builtin_amdgcn_sched_barrier(0); \
        __builtin_amdgcn_s_barrier(); \
        cur ^= 1; \
    } }

// MoE GEMM1: tile-table grid (80x16). gathered A rows; fused GLU -> gated f16
__global__ __launch_bounds__(256) void k_moe1(const _Float16* __restrict__ X,
                                              const _Float16* __restrict__ W,
                                              const float* __restrict__ bias,
                                              const int* __restrict__ perm,
                                              const int* __restrict__ counts,
                                              const int* __restrict__ offs,
                                              const int* __restrict__ te,
                                              const int* __restrict__ tm,
                                              const int* __restrict__ ntt,
                                              _Float16* __restrict__ gated) {
    const int wg = xcd_swz(blockIdx.x, MAXT_ * 16);
    const int tt = wg >> 4;
    if (tt >= ntt[0]) return;
    const int e = te[tt];
    const int m0 = tm[tt];
    const int ne = counts[e];
    const int base = offs[e];
    const int col0 = (wg & 15) * 128;
    MOE_PROLOG();
    const _Float16* asrc[4];
    const _Float16* bsrc[4];
#pragma unroll
    for (int c = 0; c < 4; ++c) {
        int t = perm[base + min(m0 + c * 32 + rloc, ne - 1)];
        asrc[c] = X + (size_t)t * H_ + ksw;
        bsrc[c] = W + ((size_t)e * 2048 + col0 + c * 32 + rloc) * H_ + ksw;
    }
    MOE_KLOOP(H_);
#pragma unroll
    for (int mf = 0; mf < 4; ++mf)
#pragma unroll
        for (int i = 0; i < 4; ++i) {
            int r = m0 + wr * 64 + mf * 16 + ((lane >> 4) << 2) + i;
            bool ok = r < ne;
            int slot = base + r;
#pragma unroll
            for (int nf = 0; nf < 4; ++nf) {
                int c = col0 + wc * 64 + nf * 16 + (lane & 15);
                float v = acc[mf][nf][i] + bias[e * 2048 + c];
                float o = __shfl_xor(v, 1);
                if (ok && !(lane & 1)) {
                    float gt = fminf(v, LIMIT_);
                    float up = fminf(fmaxf(o, -LIMIT_), LIMIT_);
                    float sg = 1.f / (1.f + __expf(-ALPHA_ * gt));
                    gated[(size_t)slot * ED_ + (c >> 1)] = (_Float16)((up + 1.f) * (gt * sg));
                }
            }
        }
}

__global__ __launch_bounds__(256) void k_moe2(const _Float16* __restrict__ G,
                                              const _Float16* __restrict__ W,
                                              const float* __restrict__ bias,
                                              const int* __restrict__ perm,
                                              const float* __restrict__ pw,
                                              const int* __restrict__ counts,
                                              const int* __restrict__ offs,
                                              const int* __restrict__ te,
                                              const int* __restrict__ tm,
                                              const int* __restrict__ ntt,
                                              float* __restrict__ out) {
    const int wg = xcd_swz(blockIdx.x, MAXT_ * 16);
    const int tt = wg >> 4;
    if (tt >= ntt[0]) return;
    const int e = te[tt];
    const int m0 = tm[tt];
    const int ne = counts[e];
    const int base = offs[e];
    const int col0 = (wg & 15) * 128;
    MOE_PROLOG();
    const _Float16* asrc[4];
    const _Float16* bsrc[4];
#pragma unroll
    for (int c = 0; c < 4; ++c) {
        int s = base + min(m0 + c * 32 + rloc, ne - 1);
        asrc[c] = G + (size_t)s * ED_ + ksw;
        bsrc[c] = W + ((size_t)e * H_ + col0 + c * 32 + rloc) * ED_ + ksw;
    }
    MOE_KLOOP(ED_);
#pragma unroll
    for (int mf = 0; mf < 4; ++mf)
#pragma unroll
        for (int i = 0; i < 4; ++i) {
            int r = m0 + wr * 64 + mf * 16 + ((lane >> 4) << 2) + i;
            if (r >= ne) continue;
            int slot = base + r;
            int tok = perm[slot];
            float wgt = pw[slot];
#pragma unroll
            for (int nf = 0; nf < 4; ++nf) {
                int c = col0 + wc * 64 + nf * 16 + (lane & 15);
                atomicAdd(&out[(size_t)tok * H_ + c], wgt * (acc[mf][nf][i] + bias[e * H_ + c]));
            }
        }
}

// ================= conversions =================
__global__ __launch_bounds__(256) void k_cvts_qkv(const float* __restrict__ qw,
                                                  const float* __restrict__ kw,
                                                  const float* __restrict__ vw,
                                                  const float* __restrict__ qb,
                                                  const float* __restrict__ kb,
                                                  const float* __restrict__ vb,
                                                  _Float16* __restrict__ dh,
                                                  _Float16* __restrict__ dl,
                                                  float* __restrict__ biasout) {
    const int r = blockIdx.x;
    const int tid = threadIdx.x;
    const float* src = (r < 2048) ? qw + (size_t)r * H_
                     : (r < 2560) ? kw + (size_t)(r - 2048) * H_
                                  : vw + (size_t)(r - 2560) * H_;
    float4 x = ((const float4*)src)[tid * 2], y = ((const float4*)src)[tid * 2 + 1];
    float xs[8] = {x.x, x.y, x.z, x.w, y.x, y.y, y.z, y.w};
    half8 h, l;
#pragma unroll
    for (int j = 0; j < 8; ++j) {
        _Float16 hv = (_Float16)xs[j];
        h[j] = hv;
        l[j] = (_Float16)((xs[j] - (float)hv) * SPLIT_);
    }
    ((half8*)(dh + (size_t)r * H_))[tid] = h;
    ((half8*)(dl + (size_t)r * H_))[tid] = l;
    if (r < 12) {
        int g = r * 256 + tid;
        if (g < NQKV_) {
            float bv = (g < 2048) ? qb[g] : (g < 2560) ? kb[g - 2048] : vb[g - 2560];
            biasout[g] = bv;
        }
    }
}

__global__ __launch_bounds__(256) void k_cvts(const float* __restrict__ s,
                                              _Float16* __restrict__ dh,
                                              _Float16* __restrict__ dl, int n8) {
    int i = blockIdx.x * 256 + threadIdx.x;
    if (i >= n8) return;
    float4 x = ((const float4*)s)[i * 2], y = ((const float4*)s)[i * 2 + 1];
    float xs[8] = {x.x, x.y, x.z, x.w, y.x, y.y, y.z, y.w};
    half8 h, l;
#pragma unroll
    for (int j = 0; j < 8; ++j) {
        _Float16 hv = (_Float16)xs[j];
        h[j] = hv;
        l[j] = (_Float16)((xs[j] - (float)hv) * SPLIT_);
    }
    ((half8*)dh)[i] = h;
    ((half8*)dl)[i] = l;
}

// transpose-convert: src [e][K][N] fp32 -> dst [e][N][K] f16. 64x64 tiles.
__global__ __launch_bounds__(256) void k_cvt_t(const float* __restrict__ src,
                                               _Float16* __restrict__ dst, int K, int N) {
    const int e = blockIdx.z;
    const int k0 = blockIdx.x * 64, n0 = blockIdx.y * 64;
    __shared__ float t[64][65];
    const int tid = threadIdx.x;
    {
        int kr = tid >> 4, nc = (tid & 15) * 4;
#pragma unroll
        for (int j = 0; j < 4; ++j) {
            float4 v = *(const float4*)(src + ((size_t)e * K + k0 + kr + j * 16) * N + n0 + nc);
            t[kr + j * 16][nc] = v.x; t[kr + j * 16][nc + 1] = v.y;
            t[kr + j * 16][nc + 2] = v.z; t[kr + j * 16][nc + 3] = v.w;
        }
    }
    __syncthreads();
    {
        int nr = tid >> 3, kc = (tid & 7) * 8;
#pragma unroll
        for (int j = 0; j < 2; ++j) {
            int n = nr + j * 32;
            half8 o;
#pragma unroll
            for (int i = 0; i < 8; ++i) o[i] = (_Float16)t[kc + i][n];
            *(half8*)(dst + ((size_t)e * N + n0 + n) * K + k0 + kc) = o;
        }
    }
}

// ================= RMSNorm (split f16 outputs) =================
__global__ __launch_bounds__(256) void k_rmsnorm(const float* __restrict__ x,
                                                 const float* __restrict__ w,
                                                 float* __restrict__ y,
                                                 _Float16* __restrict__ yh,
                                                 _Float16* __restrict__ yl) {
    int t = blockIdx.x;
    const float* row = x + (size_t)t * H_;
    float ss = 0.f;
    for (int i = threadIdx.x; i < H_ / 4; i += 256) {
        float4 v = ((const float4*)row)[i];
        ss += v.x * v.x + v.y * v.y + v.z * v.z + v.w * v.w;
    }
    for (int o = 32; o >= 1; o >>= 1) ss += __shfl_xor(ss, o);
    __shared__ float wsum[4];
    if ((threadIdx.x & 63) == 0) wsum[threadIdx.x >> 6] = ss;
    __syncthreads();
    float tot = wsum[0] + wsum[1] + wsum[2] + wsum[3];
    float r = rsqrtf(tot / (float)H_ + EPS_);
    _Float16* hrow = yh + (size_t)t * H_;
    _Float16* lrow = yl + (size_t)t * H_;
    for (int i = threadIdx.x; i < H_ / 4; i += 256) {
        float4 v = ((const float4*)row)[i];
        float4 g = ((const float4*)w)[i];
        float o4[4];
        o4[0] = v.x * r * g.x; o4[1] = v.y * r * g.y;
        o4[2] = v.z * r * g.z; o4[3] = v.w * r * g.w;
        if (y) ((float4*)(y + (size_t)t * H_))[i] = *(float4*)o4;
        half4v h4, l4;
#pragma unroll
        for (int j = 0; j < 4; ++j) {
            _Float16 hv = (_Float16)o4[j];
            h4[j] = hv;
            l4[j] = (_Float16)((o4[j] - (float)hv) * SPLIT_);
        }
        ((half4v*)hrow)[i] = h4;
        ((half4v*)lrow)[i] = l4;
    }
}

// ======= fused RMSNorm2 + router (fp32-accurate logits, split f16 x out) =======
__global__ __launch_bounds__(256) void k_rms2_router(const float* __restrict__ x,
                                                     const float* __restrict__ w,
                                                     _Float16* __restrict__ yh,
                                                     _Float16* __restrict__ yl,
                                                     const float* __restrict__ rw,
                                                     const float* __restrict__ rb,
                                                     int* __restrict__ topi,
                                                     float* __restrict__ topw) {
    const int t = blockIdx.x;
    const int tid = threadIdx.x;
    const float* row = x + (size_t)t * H_;
    float4 v0 = ((const float4*)row)[tid];
    float4 v1 = ((const float4*)row)[tid + 256];
    float ss = v0.x*v0.x + v0.y*v0.y + v0.z*v0.z + v0.w*v0.w
             + v1.x*v1.x + v1.y*v1.y + v1.z*v1.z + v1.w*v1.w;
    for (int o = 32; o >= 1; o >>= 1) ss += __shfl_xor(ss, o);
    __shared__ float wsum[4];
    if ((tid & 63) == 0) wsum[tid >> 6] = ss;
    __syncthreads();
    float tot = wsum[0] + wsum[1] + wsum[2] + wsum[3];
    float r = rsqrtf(tot / (float)H_ + EPS_);
    float4 g0 = ((const float4*)w)[tid];
    float4 g1 = ((const float4*)w)[tid + 256];
    float o8[8] = {v0.x*r*g0.x, v0.y*r*g0.y, v0.z*r*g0.z, v0.w*r*g0.w,
                   v1.x*r*g1.x, v1.y*r*g1.y, v1.z*r*g1.z, v1.w*r*g1.w};
    _Float16* hrow = yh + (size_t)t * H_;
    _Float16* lrow = yl + (size_t)t * H_;
    {
        half4v h4, l4;
#pragma unroll
        for (int j = 0; j < 4; ++j) {
            _Float16 hv = (_Float16)o8[j];
            h4[j] = hv; l4[j] = (_Float16)((o8[j] - (float)hv) * SPLIT_);
        }
        ((half4v*)hrow)[tid] = h4; ((half4v*)lrow)[tid] = l4;
#pragma unroll
        for (int j = 0; j < 4; ++j) {
            _Float16 hv = (_Float16)o8[4 + j];
            h4[j] = hv; l4[j] = (_Float16)((o8[4 + j] - (float)hv) * SPLIT_);
        }
        ((half4v*)hrow)[tid + 256] = h4; ((half4v*)lrow)[tid + 256] = l4;
    }
    float pe[E_];
#pragma unroll
    for (int e = 0; e < E_; ++e) {
        const float* wr = rw + (size_t)e * H_;
        float4 a = ((const float4*)wr)[tid];
        float4 b = ((const float4*)wr)[tid + 256];
        pe[e] = o8[0]*a.x + o8[1]*a.y + o8[2]*a.z + o8[3]*a.w
              + o8[4]*b.x + o8[5]*b.y + o8[6]*b.z + o8[7]*b.w;
    }
#pragma unroll
    for (int e = 0; e < E_; ++e)
        for (int o = 32; o >= 1; o >>= 1) pe[e] += __shfl_xor(pe[e], o);
    __shared__ float part[4][E_];
    if ((tid & 63) == 0)
#pragma unroll
        for (int e = 0; e < E_; ++e) part[tid >> 6][e] = pe[e];
    __syncthreads();
    __shared__ float logits[E_];
    if (tid < E_) logits[tid] = rb[tid] + part[0][tid] + part[1][tid] + part[2][tid] + part[3][tid];
    __syncthreads();
    if (tid == 0) {
        float tv[4]; int ti4[4];
        unsigned used = 0;
        for (int s3 = 0; s3 < 4; s3++) {
            float best = -3.0e38f; int bi = 0;
            for (int e2 = 0; e2 < E_; e2++)
                if (!((used >> e2) & 1) && logits[e2] > best) { best = logits[e2]; bi = e2; }
            used |= 1u << bi; tv[s3] = best; ti4[s3] = bi;
        }
        float mx = tv[0], pex[4], sum = 0.f;
        for (int s3 = 0; s3 < 4; s3++) { pex[s3] = __expf(tv[s3] - mx); sum += pex[s3]; }
        for (int s3 = 0; s3 < 4; s3++) {
            topw[t * 4 + s3] = pex[s3] / sum;
            topi[t * 4 + s3] = ti4[s3];
        }
    }
}

// ======= fused RoPE (blocks 0..2047) + V transpose-split (blocks 2048..3071) ====
__global__ __launch_bounds__(256) void k_rope_vt(const float* __restrict__ qkv,
                                                 const float* __restrict__ cs,
                                                 const float* __restrict__ sn,
                                                 _Float16* __restrict__ qh, _Float16* __restrict__ ql,
                                                 _Float16* __restrict__ kh, _Float16* __restrict__ kl,
                                                 _Float16* __restrict__ vth, _Float16* __restrict__ vtl) {
    const int bid = blockIdx.x;
    const int tid = threadIdx.x;
    if (bid < T_) {
        int t = bid;
        int b = t >> 10, s = t & 1023;
        size_t cb = (size_t)t * 64;
        const float* rowsrc = qkv + (size_t)t * NQKV_;
        for (int p = tid; p < 40 * 32; p += 256) {
            int head = p >> 5, d = p & 31;
            float c1 = cs[cb + d],      s1v = sn[cb + d];
            float c2 = cs[cb + d + 32], s2v = sn[cb + d + 32];
            float x1, x2; size_t dst;
            _Float16 *oh, *ol;
            if (head < 32) {
                const float* src = rowsrc + head * 64;
                x1 = src[d]; x2 = src[d + 32];
                dst = (((size_t)b * 32 + head) * 1024 + s) * 64 + d;
                oh = qh; ol = ql;
            } else {
                int hk = head - 32;
                const float* src = rowsrc + 2048 + hk * 64;
                x1 = src[d]; x2 = src[d + 32];
                dst = (((size_t)b * 8 + hk) * 1024 + s) * 64 + d;
                oh = kh; ol = kl;
            }
            float r1 = x1 * c1 - x2 * s1v;
            float r2 = x2 * c2 + x1 * s2v;
            _Float16 h1 = (_Float16)r1;
            oh[dst] = h1; ol[dst] = (_Float16)((r1 - (float)h1) * SPLIT_);
            _Float16 h2 = (_Float16)r2;
            oh[dst + 32] = h2; ol[dst + 32] = (_Float16)((r2 - (float)h2) * SPLIT_);
        }
    } else {
        int vb = bid - T_;
        int s0 = (vb & 31) * 32;
        int rest = vb >> 5;
        int d0 = (rest & 1) * 32;
        int bk = rest >> 1;          // b*8 + kvh
        int b = bk >> 3, kvh = bk & 7;
        __shared__ float tl[32][33];
        {
            int sr = tid >> 3, dc = (tid & 7) * 4;
            float4 v = *(const float4*)(qkv + (size_t)(b * 1024 + s0 + sr) * NQKV_ + 2560 + kvh * 64 + d0 + dc);
            tl[sr][dc] = v.x; tl[sr][dc + 1] = v.y; tl[sr][dc + 2] = v.z; tl[sr][dc + 3] = v.w;
        }
        __syncthreads();
        {
            int dr = tid >> 3, sc = (tid & 7) * 4;
            half4v h4, l4;
#pragma unroll
            for (int j = 0; j < 4; ++j) {
                float x = tl[sc + j][dr];
                _Float16 hv = (_Float16)x;
                h4[j] = hv;
                l4[j] = (_Float16)((x - (float)hv) * SPLIT_);
            }
            size_t dst = (size_t)(bk * 64 + d0 + dr) * 1024 + s0 + sc;
            *(half4v*)(vth + dst) = h4;
            *(half4v*)(vtl + dst) = l4;
        }
    }
}

// ================= MFMA flash attention (split-fp16, fp32-accurate) ===========
#define PPITCH 68
union U8h { unsigned w[4]; half8 v; };

__global__ __launch_bounds__(256, 1) void k_attn_m(
        const _Float16* __restrict__ qhg, const _Float16* __restrict__ qlg,
        const _Float16* __restrict__ khg, const _Float16* __restrict__ klg,
        const _Float16* __restrict__ vthg, const _Float16* __restrict__ vtlg,
        const float* __restrict__ sinks,
        _Float16* __restrict__ ath, _Float16* __restrict__ atl) {
    __shared__ _Float16 Khs[4096], Kls[4096], Vhs[4096], Vls[4096];
    __shared__ unsigned Pp[4][64 * PPITCH];
    const int bx = blockIdx.x;
    const int b = bx >> 7, kvh = (bx >> 4) & 7, tile = bx & 15;
    const int i0 = tile * 64;
    const int tid = threadIdx.x, lane = tid & 63, wid = tid >> 6;
    const int l15 = lane & 15, g = lane >> 4;
    const int h = kvh * 4 + wid;
    const size_t kvbase = (size_t)(b * 8 + kvh) * 1024 * 64;
    const size_t vbase  = (size_t)(b * 8 + kvh) * 64 * 1024;
    half8 aqh[4][2], aql[4][2];
    {
        const size_t qb0 = ((size_t)(b * 32 + h) * 1024 + i0) * 64;
#pragma unroll
        for (int mf = 0; mf < 4; ++mf)
#pragma unroll
            for (int ks = 0; ks < 2; ++ks) {
                size_t a = qb0 + (size_t)(16 * mf + l15) * 64 + ks * 32 + g * 8;
                aqh[mf][ks] = *(const half8*)(qhg + a);
                aql[mf][ks] = *(const half8*)(qlg + a);
            }
    }
    floatx4 o1[4][4], o2[4][4];
    float m_run[4][4], l_run[4][4];
#pragma unroll
    for (int mf = 0; mf < 4; ++mf)
#pragma unroll
        for (int x = 0; x < 4; ++x) {
            o1[mf][x] = (floatx4)0.f; o2[mf][x] = (floatx4)0.f;
            m_run[mf][x] = -1e20f; l_run[mf][x] = 0.f;
        }
    const int nch = tile >= 2 ? 3 : tile + 1;
    const int jr = tid >> 3, cc = tid & 7;
    unsigned* pw = &Pp[wid][0];
    for (int ci = 0; ci < nch; ++ci) {
        const int jb = i0 - 64 * (nch - 1 - ci);
        __syncthreads();
        {
            const int sw0 = (cc ^ (jr & 7)) * 8;
            const size_t k0 = kvbase + (size_t)(jb + jr) * 64 + sw0;
            const size_t k1 = kvbase + (size_t)(jb + jr + 32) * 64 + sw0;
            gload16(khg + k0, Khs + tid * 8);
            gload16(khg + k1, Khs + 2048 + tid * 8);
            gload16(klg + k0, Kls + tid * 8);
            gload16(klg + k1, Kls + 2048 + tid * 8);
            const size_t v0 = vbase + (size_t)jr * 1024 + jb + sw0;
            const size_t v1 = vbase + (size_t)(jr + 32) * 1024 + jb + sw0;
            gload16(vthg + v0, Vhs + tid * 8);
            gload16(vthg + v1, Vhs + 2048 + tid * 8);
            gload16(vtlg + v0, Vls + tid * 8);
            gload16(vtlg + v1, Vls + 2048 + tid * 8);
        }
        __syncthreads();
        floatx4 s1[4][4], s2[4][4];
#pragma unroll
        for (int mf = 0; mf < 4; ++mf)
#pragma unroll
            for (int nf = 0; nf < 4; ++nf) { s1[mf][nf] = (floatx4)0.f; s2[mf][nf] = (floatx4)0.f; }
#pragma unroll
        for (int ks = 0; ks < 2; ++ks) {
            half8 kbh[4], kbl[4];
#pragma unroll
            for (int nf = 0; nf < 4; ++nf) {
                int j = l15 + 16 * nf;
                int c = (g + 4 * ks) ^ (j & 7);
                kbh[nf] = *(const half8*)&Khs[j * 64 + c * 8];
                kbl[nf] = *(const half8*)&Kls[j * 64 + c * 8];
            }
#pragma unroll
            for (int mf = 0; mf < 4; ++mf)
#pragma unroll
                for (int nf = 0; nf < 4; ++nf) {
                    s1[mf][nf] = MF16(aqh[mf][ks], kbh[nf], s1[mf][nf]);
                    s2[mf][nf] = MF16(aqh[mf][ks], kbl[nf], s2[mf][nf]);
                    s2[mf][nf] = MF16(aql[mf][ks], kbh[nf], s2[mf][nf]);
                }
        }
#pragma unroll
        for (int mf = 0; mf < 4; ++mf)
#pragma unroll
            for (int reg = 0; reg < 4; ++reg) {
                int i = i0 + 16 * mf + g * 4 + reg;
                float best = -1e30f;
#pragma unroll
                for (int nf = 0; nf < 4; ++nf) {
                    int j = jb + 16 * nf + l15;
                    float sv = (s1[mf][nf][reg] + s2[mf][nf][reg] * INV_SPLIT_) * SCALE_;
                    bool ok = (j <= i) && (i - j < WIN_);
                    sv = ok ? sv : -1e30f;
                    s1[mf][nf][reg] = sv;
                    best = fmaxf(best, sv);
                }
                for (int off = 1; off < 16; off <<= 1) best = fmaxf(best, __shfl_xor(best, off));
                float nm = fmaxf(m_run[mf][reg], best);
                float sc = __expf(m_run[mf][reg] - nm);
                m_run[mf][reg] = nm;
                l_run[mf][reg] *= sc;
#pragma unroll
                for (int nf = 0; nf < 4; ++nf) { o1[mf][nf][reg] *= sc; o2[mf][nf][reg] *= sc; }
            }
#pragma unroll
        for (int mf = 0; mf < 4; ++mf)
#pragma unroll
            for (int nf = 0; nf < 4; ++nf)
#pragma unroll
                for (int reg = 0; reg < 4; ++reg) {
                    float pv = __expf(s1[mf][nf][reg] - m_run[mf][reg]);
                    l_run[mf][reg] += pv;
                    _Float16 hv = (_Float16)pv;
                    _Float16 lv = (_Float16)((pv - (float)hv) * SPLIT_);
                    union { _Float16 h; unsigned short u; } ch, cl;
                    ch.h = hv; cl.h = lv;
                    int t = 16 * mf + g * 4 + reg, jj = l15 + 16 * nf;
                    pw[t * PPITCH + jj] = (unsigned)ch.u | ((unsigned)cl.u << 16);
                }
#pragma unroll
        for (int ks = 0; ks < 2; ++ks) {
            half8 bvh[4], bvl[4];
#pragma unroll
            for (int nf = 0; nf < 4; ++nf) {
                int d = l15 + 16 * nf;
                int c = (g + 4 * ks) ^ (d & 7);
                bvh[nf] = *(const half8*)&Vhs[d * 64 + c * 8];
                bvl[nf] = *(const half8*)&Vls[d * 64 + c * 8];
            }
#pragma unroll
            for (int mf = 0; mf < 4; ++mf) {
                const unsigned* pr = &pw[(16 * mf + l15) * PPITCH + 32 * ks + g * 8];
                int4 va = *(const int4*)pr;
                int4 vb = *(const int4*)(pr + 4);
                U8h ph, pl;
                ph.w[0] = ((unsigned)va.x & 0xffffu) | ((unsigned)va.y << 16);
                ph.w[1] = ((unsigned)va.z & 0xffffu) | ((unsigned)va.w << 16);
                ph.w[2] = ((unsigned)vb.x & 0xffffu) | ((unsigned)vb.y << 16);
                ph.w[3] = ((unsigned)vb.z & 0xffffu) | ((unsigned)vb.w << 16);
                pl.w[0] = ((unsigned)va.x >> 16) | ((unsigned)va.y & 0xffff0000u);
                pl.w[1] = ((unsigned)va.z >> 16) | ((unsigned)va.w & 0xffff0000u);
                pl.w[2] = ((unsigned)vb.x >> 16) | ((unsigned)vb.y & 0xffff0000u);
                pl.w[3] = ((unsigned)vb.z >> 16) | ((unsigned)vb.w & 0xffff0000u);
#pragma unroll
                for (int nf = 0; nf < 4; ++nf) {
                    o1[mf][nf] = MF16(ph.v, bvh[nf], o1[mf][nf]);
                    o2[mf][nf] = MF16(ph.v, bvl[nf], o2[mf][nf]);
                    o2[mf][nf] = MF16(pl.v, bvh[nf], o2[mf][nf]);
                }
            }
        }
    }
    const float sinkv = sinks[h];
    float inv[4][4];
#pragma unroll
    for (int mf = 0; mf < 4; ++mf)
#pragma unroll
        for (int reg = 0; reg < 4; ++reg) {
            float l = l_run[mf][reg];
            for (int off = 1; off < 16; off <<= 1) l += __shfl_xor(l, off);
            inv[mf][reg] = 1.f / (l + __expf(sinkv - m_run[mf][reg]));
        }
#pragma unroll
    for (int mf = 0; mf < 4; ++mf)
#pragma unroll
        for (int nf = 0; nf < 4; ++nf)
#pragma unroll
            for (int reg = 0; reg < 4; ++reg) {
                int t = i0 + 16 * mf + g * 4 + reg;
                int d = l15 + 16 * nf;
                float ov = (o1[mf][nf][reg] + o2[mf][nf][reg] * INV_SPLIT_) * inv[mf][reg];
                size_t idx = ((size_t)(b * 1024 + t) * 32 + h) * 64 + d;
                _Float16 hv = (_Float16)ov;
                ath[idx] = hv;
                atl[idx] = (_Float16)((ov - (float)hv) * SPLIT_);
            }
}

// ======= fused MoE prep: hist + scan + tile table + scatter (one block) =======
__global__ __launch_bounds__(1024) void k_route_build(const int* __restrict__ topi,
                                                      const float* __restrict__ topw,
                                                      int* __restrict__ counts,
                                                      int* __restrict__ offs,
                                                      int* __restrict__ perm,
                                                      float* __restrict__ pw,
                                                      int* __restrict__ te,
                                                      int* __restrict__ tm,
                                                      int* __restrict__ ntt) {
    __shared__ int cnt[E_], cur[E_];
    const int tid = threadIdx.x;
    if (tid < E_) cnt[tid] = 0;
    __syncthreads();
    for (int g = tid; g < T_ * TOPK_; g += 1024) atomicAdd(&cnt[topi[g]], 1);
    __syncthreads();
    if (tid == 0) {
        int run = 0, t = 0;
        for (int e = 0; e < E_; e++) {
            offs[e] = run; cur[e] = run; counts[e] = cnt[e];
            for (int m0 = 0; m0 < cnt[e]; m0 += 128) { te[t] = e; tm[t] = m0; t++; }
            run += cnt[e];
        }
        ntt[0] = t;
    }
    __syncthreads();
    for (int g = tid; g < T_ * TOPK_; g += 1024) {
        int pos = atomicAdd(&cur[topi[g]], 1);
        perm[pos] = g >> 2;
        pw[pos] = topw[g];
    }
}

// ================= launch =================
extern "C" void kernel_launch(void* const* d_in, const int* in_sizes, int n_in,
                              void* d_out, int out_size, void* d_ws, size_t ws_size,
                              hipStream_t stream) {
    const float* hidden = (const float*)d_in[0];
    const float* cosp  = (const float*)d_in[1];
    const float* sinp  = (const float*)d_in[2];
    const float* ln1   = (const float*)d_in[3];
    const float* ln2   = (const float*)d_in[4];
    const float* qw    = (const float*)d_in[5];
    const float* qb    = (const float*)d_in[6];
    const float* kw    = (const float*)d_in[7];
    const float* kbia  = (const float*)d_in[8];
    const float* vw    = (const float*)d_in[9];
    const float* vbia  = (const float*)d_in[10];
    const float* ow    = (const float*)d_in[11];
    const float* ob    = (const float*)d_in[12];
    const float* sinks = (const float*)d_in[13];
    const float* rw    = (const float*)d_in[14];
    const float* rb    = (const float*)d_in[15];
    const float* gup   = (const float*)d_in[16];
    const float* gub   = (const float*)d_in[17];
    const float* dwp   = (const float*)d_in[18];
    const float* dwb   = (const float*)d_in[19];
    float* out = (float*)d_out;

    char* p = (char*)d_ws;
    auto alloc = [&](size_t bytes) { char* r = p; p += (bytes + 255) & ~(size_t)255; return r; };
    _Float16*  xh     = (_Float16*)alloc((size_t)T_ * H_ * 2);
    _Float16*  xl     = (_Float16*)alloc((size_t)T_ * H_ * 2);
    float*     qkvbuf = (float*)alloc((size_t)T_ * NQKV_ * 4);
    _Float16*  ath    = (_Float16*)alloc((size_t)T_ * NH_ * HD_ * 2);
    _Float16*  atl    = (_Float16*)alloc((size_t)T_ * NH_ * HD_ * 2);
    _Float16*  gatedh = (_Float16*)alloc((size_t)T_ * TOPK_ * ED_ * 2);
    _Float16*  qkvwh  = (_Float16*)alloc((size_t)NQKV_ * H_ * 2);
    _Float16*  qkvwl  = (_Float16*)alloc((size_t)NQKV_ * H_ * 2);
    float*     qkvbias= (float*)alloc(NQKV_ * 4);
    _Float16*  owh    = (_Float16*)alloc((size_t)H_ * 2048 * 2);
    _Float16*  owl    = (_Float16*)alloc((size_t)H_ * 2048 * 2);
    _Float16*  gupt   = (_Float16*)alloc((size_t)E_ * 2048 * H_ * 2);
    _Float16*  dwnt   = (_Float16*)alloc((size_t)E_ * H_ * ED_ * 2);
    _Float16*  qhb    = (_Float16*)alloc((size_t)T_ * NH_ * HD_ * 2);
    _Float16*  qlb    = (_Float16*)alloc((size_t)T_ * NH_ * HD_ * 2);
    _Float16*  khb    = (_Float16*)alloc((size_t)T_ * NKV_ * HD_ * 2);
    _Float16*  klb    = (_Float16*)alloc((size_t)T_ * NKV_ * HD_ * 2);
    _Float16*  vthb   = (_Float16*)alloc((size_t)T_ * NKV_ * HD_ * 2);
    _Float16*  vtlb   = (_Float16*)alloc((size_t)T_ * NKV_ * HD_ * 2);
    float*     topw   = (float*)alloc(T_ * TOPK_ * 4);
    float*     pwb    = (float*)alloc(T_ * TOPK_ * 4);
    int*       topi   = (int*)alloc(T_ * TOPK_ * 4);
    int*       perm   = (int*)alloc(T_ * TOPK_ * 4);
    int*       counts = (int*)alloc(E_ * 4);
    int*       offs   = (int*)alloc(E_ * 4);
    int*       te     = (int*)alloc(MAXT_ * 4);
    int*       tm     = (int*)alloc(MAXT_ * 4);
    int*       ntt    = (int*)alloc(4);

    // weight conversions (stacked QKV + O + expert transposes)
    k_cvts_qkv<<<NQKV_, 256, 0, stream>>>(qw, kw, vw, qb, kbia, vbia, qkvwh, qkvwl, qkvbias);
    k_cvts<<<2048, 256, 0, stream>>>(ow, owh, owl, H_ * 2048 / 8);
    k_cvt_t<<<dim3(H_ / 64, 2048 / 64, E_), 256, 0, stream>>>(gup, gupt, H_, 2048);
    k_cvt_t<<<dim3(ED_ / 64, H_ / 64, E_), 256, 0, stream>>>(dwp, dwnt, ED_, H_);

    k_rmsnorm<<<T_, 256, 0, stream>>>(hidden, ln1, nullptr, xh, xl);
    // fused QKV: no split-K, bias in epilogue, plain stores (384 blocks)
    k_gemm_qkv<<<(NQKV_ / 128) * 16, 256, 0, stream>>>(xh, xl, qkvwh, qkvwl, qkvbias, qkvbuf, NQKV_, H_);
    k_rope_vt<<<T_ + 1024, 256, 0, stream>>>(qkvbuf, cosp, sinp, qhb, qlb, khb, klb, vthb, vtlb);
    k_attn_m<<<256, 256, 0, stream>>>(qhb, qlb, khb, klb, vthb, vtlb, sinks, ath, atl);
    // O-proj: out = hidden + ob + attn @ ow^T (init + split-K=2 atomic)
    k_initc<<<4096, 256, 0, stream>>>(ob, hidden, out, 2048, T_ * 2048 / 4);
    k_gemm_spk2<<<512, 256, 0, stream>>>(ath, atl, owh, owl, out, 2048, H_);
    // fused RMSNorm2 + router
    k_rms2_router<<<T_, 256, 0, stream>>>(out, ln2, xh, xl, rw, rb, topi, topw);
    k_route_build<<<1, 1024, 0, stream>>>(topi, topw, counts, offs, perm, pwb, te, tm, ntt);
    k_moe1<<<MAXT_ * 16, 256, 0, stream>>>(xh, gupt, gub, perm, counts, offs, te, tm, ntt, gatedh);
    k_moe2<<<MAXT_ * 16, 256, 0, stream>>>(gatedh, dwnt, dwb, perm, pwb, counts, offs, te, tm, ntt, out);
}

// Round 14
// 789.320 us; speedup vs baseline: 1.3025x; 1.0204x over previous
//
#include <hip/hip_runtime.h>
#include <hip/hip_bf16.h>
#include <cstdint>

#define B_    2
#define S_    1024
#define H_    2048
#define NH_   32
#define NKV_  8
#define HD_   64
#define T_    (B_*S_)
#define E_    16
#define ED_   1024
#define TOPK_ 4
#define WIN_  128
#define LIMIT_ 7.0f
#define ALPHA_ 1.702f
#define EPS_   1e-6f
#define SCALE_ 0.125f  /* HD^-0.5 */
#define SPLIT_ 2048.0f
#define INV_SPLIT_ 4.8828125e-4f
#define MAXT_ 80      /* max MoE row-tiles of 128: 64 + 16 */
#define NQKV_ 3072    /* fused q(2048)+k(512)+v(512) */

typedef _Float16 half8 __attribute__((ext_vector_type(8)));
typedef _Float16 half4v __attribute__((ext_vector_type(4)));
typedef float floatx4 __attribute__((ext_vector_type(4)));

#define MF16(a,b,c) __builtin_amdgcn_mfma_f32_16x16x32_f16(a,b,c,0,0,0)

__device__ __forceinline__ void gload16(const void* g, void* l) {
    __builtin_amdgcn_global_load_lds((const __attribute__((address_space(1))) void*)g,
                                     (__attribute__((address_space(3))) void*)l, 16, 0, 0);
}

// bijective chunked XCD swizzle (nwg % 8 == 0)
__device__ __forceinline__ int xcd_swz(int bid, int nwg) {
    int cpx = nwg >> 3;
    return (bid & 7) * cpx + (bid >> 3);
}

// ================= C init: C = bias (+res) =================
__global__ __launch_bounds__(256) void k_initc(const float* __restrict__ bias,
                                               const float* __restrict__ res,
                                               float* __restrict__ C, int N, int n4) {
    int i = blockIdx.x * 256 + threadIdx.x;
    if (i >= n4) return;
    int c4 = (i % (N >> 2)) << 2;
    float4 v = *(const float4*)(bias + c4);
    if (res) {
        float4 r = ((const float4*)res)[i];
        v.x += r.x; v.y += r.y; v.z += r.z; v.w += r.w;
    }
    ((float4*)C)[i] = v;
}

// ===== shared dense-GEMM body: BK=32 dbuf + counted vmcnt + chunk-XOR(row&3) ====
#define DG_PROLog() \
    __shared__ _Float16 Ahs[2][128 * 32]; \
    __shared__ _Float16 Als[2][128 * 32]; \
    __shared__ _Float16 Bhs[2][128 * 32]; \
    __shared__ _Float16 Bls[2][128 * 32]; \
    const int tid = threadIdx.x; \
    const int lane = tid & 63; \
    const int wid = tid >> 6; \
    const int wr = wid >> 1, wc = wid & 1; \
    const int l15 = lane & 15, g4 = lane >> 4; \
    floatx4 acc1[4][4], acc2[4][4]; \
    for (int m = 0; m < 4; ++m) \
        for (int n = 0; n < 4; ++n) { acc1[m][n] = (floatx4)0.f; acc2[m][n] = (floatx4)0.f; } \
    const int rL = tid >> 2; \
    const int koff = (((tid & 3) ^ (rL & 3))) * 8;

#define DG_STAGE(buf, kk) do { \
        gload16(Ah + o0 + (kk), Ahs[buf] + tid * 8); gload16(Ah + o1 + (kk), Ahs[buf] + 2048 + tid * 8); \
        gload16(Al + o0 + (kk), Als[buf] + tid * 8); gload16(Al + o1 + (kk), Als[buf] + 2048 + tid * 8); \
        gload16(Bh + p0 + (kk), Bhs[buf] + tid * 8); gload16(Bh + p1 + (kk), Bhs[buf] + 2048 + tid * 8); \
        gload16(Bl + p0 + (kk), Bls[buf] + tid * 8); gload16(Bl + p1 + (kk), Bls[buf] + 2048 + tid * 8); \
    } while (0)

#define DG_KLOOP(KB, KE) \
    DG_STAGE(0, KB); \
    { int cur = 0; \
    for (int k0 = (KB); k0 < (KE); k0 += 32) { \
        if (k0 + 32 < (KE)) { \
            DG_STAGE(cur ^ 1, k0 + 32); \
            asm volatile("s_waitcnt vmcnt(8)" ::: "memory"); \
        } else { \
            asm volatile("s_waitcnt vmcnt(0)" ::: "memory"); \
        } \
        __builtin_amdgcn_s_barrier(); \
        __builtin_amdgcn_sched_barrier(0); \
        half8 ah[4], al[4], bh[4], bl[4]; \
        _Pragma("unroll") for (int m = 0; m < 4; ++m) { \
            int ra = wr * 64 + m * 16 + l15; \
            int ro = ra * 32 + ((g4 ^ (ra & 3)) * 8); \
            ah[m] = *(const half8*)&Ahs[cur][ro]; \
            al[m] = *(const half8*)&Als[cur][ro]; \
        } \
        _Pragma("unroll") for (int n = 0; n < 4; ++n) { \
            int rb = wc * 64 + n * 16 + l15; \
            int ro = rb * 32 + ((g4 ^ (rb & 3)) * 8); \
            bh[n] = *(const half8*)&Bhs[cur][ro]; \
            bl[n] = *(const half8*)&Bls[cur][ro]; \
        } \
        _Pragma("unroll") for (int m = 0; m < 4; ++m) \
            _Pragma("unroll") for (int n = 0; n < 4; ++n) { \
                acc1[m][n] = MF16(ah[m], bh[n], acc1[m][n]); \
                acc2[m][n] = MF16(ah[m], bl[n], acc2[m][n]); \
                acc2[m][n] = MF16(al[m], bh[n], acc2[m][n]); \
            } \
        __builtin_amdgcn_sched_barrier(0); \
        __builtin_amdgcn_s_barrier(); \
        cur ^= 1; \
    } }

// dense GEMM, split-K=2 (grid = (N/128)*16*2), atomicAdd into pre-initialized C
__global__ __launch_bounds__(256) void k_gemm_spk2(const _Float16* __restrict__ Ah,
                                                   const _Float16* __restrict__ Al,
                                                   const _Float16* __restrict__ Bh,
                                                   const _Float16* __restrict__ Bl,
                                                   float* __restrict__ C, int N, int K) {
    const int wg = xcd_swz(blockIdx.x, gridDim.x);
    const int col0 = (wg >> 5) * 128;
    const int row0 = ((wg >> 1) & 15) * 128;
    const int ks2 = wg & 1;
    const int kbeg = ks2 * (K >> 1), kend = kbeg + (K >> 1);
    DG_PROLog();
    const size_t o0 = (size_t)(row0 + rL) * K + koff;
    const size_t o1 = (size_t)(row0 + 64 + rL) * K + koff;
    const size_t p0 = (size_t)(col0 + rL) * K + koff;
    const size_t p1 = (size_t)(col0 + 64 + rL) * K + koff;
    DG_KLOOP(kbeg, kend);
#pragma unroll
    for (int mf = 0; mf < 4; ++mf)
#pragma unroll
        for (int i = 0; i < 4; ++i) {
            int r = row0 + wr * 64 + mf * 16 + g4 * 4 + i;
#pragma unroll
            for (int nf = 0; nf < 4; ++nf) {
                int c = col0 + wc * 64 + nf * 16 + l15;
                atomicAdd(&C[(size_t)r * N + c], acc1[mf][nf][i] + acc2[mf][nf][i] * INV_SPLIT_);
            }
        }
}

// ===== MoE MFMA core: BK=128, SINGLE-buffered (64KB LDS -> 2 blocks/CU) =====
// Each weight row contributes 256B contiguous per staging step (DRAM-burst fix).
// chunk16-XOR swizzle both sides: source chunk (c16 ^ (row&7)), read same XOR.
#define MOE_PROLOG() \
    __shared__ _Float16 As[128 * 128]; \
    __shared__ _Float16 Bs[128 * 128]; \
    const int tid = threadIdx.x; \
    const int lane = tid & 63; \
    const int wid = tid >> 6; \
    const int wr = wid >> 1, wc = wid & 1; \
    const int l15 = lane & 15, g = lane >> 4; \
    const int rrow = tid >> 4; \
    const int ksw = ((tid & 15) ^ (rrow & 7)) * 8; \
    floatx4 acc[4][4]; \
    for (int m = 0; m < 4; ++m) for (int n = 0; n < 4; ++n) acc[m][n] = (floatx4)0.f;

#define MOE_STAGE(kk) do { \
        _Pragma("unroll") for (int c = 0; c < 8; ++c) { \
            gload16(asrc[c] + (kk), As + c * 2048 + tid * 8); \
            gload16(bsrc[c] + (kk), Bs + c * 2048 + tid * 8); \
        } \
    } while (0)

#define MOE_KLOOP(KD) \
    for (int k0 = 0; k0 < (KD); k0 += 128) { \
        __syncthreads(); \
        MOE_STAGE(k0); \
        __syncthreads(); \
        _Pragma("unroll") for (int ks = 0; ks < 4; ++ks) { \
            half8 a[4], b[4]; \
            _Pragma("unroll") for (int m = 0; m < 4; ++m) { \
                int ra = wr * 64 + m * 16 + l15; \
                a[m] = *(const half8*)&As[ra * 128 + (((ks * 4 + g) ^ (ra & 7)) * 8)]; \
            } \
            _Pragma("unroll") for (int n = 0; n < 4; ++n) { \
                int rb = wc * 64 + n * 16 + l15; \
                b[n] = *(const half8*)&Bs[rb * 128 + (((ks * 4 + g) ^ (rb & 7)) * 8)]; \
            } \
            _Pragma("unroll") for (int m = 0; m < 4; ++m) \
                _Pragma("unroll") for (int n = 0; n < 4; ++n) \
                    acc[m][n] = MF16(a[m], b[n], acc[m][n]); \
        } \
    }

// MoE GEMM1: tile-table grid (80x16). gathered A rows; fused GLU -> gated f16
__global__ __launch_bounds__(256) void k_moe1(const _Float16* __restrict__ X,
                                              const _Float16* __restrict__ W,
                                              const float* __restrict__ bias,
                                              const int* __restrict__ perm,
                                              const int* __restrict__ counts,
                                              const int* __restrict__ offs,
                                              const int* __restrict__ te,
                                              const int* __restrict__ tm,
                                              const int* __restrict__ ntt,
                                              _Float16* __restrict__ gated) {
    const int wg = xcd_swz(blockIdx.x, MAXT_ * 16);
    const int tt = wg >> 4;
    if (tt >= ntt[0]) return;
    const int e = te[tt];
    const int m0 = tm[tt];
    const int ne = counts[e];
    const int base = offs[e];
    const int col0 = (wg & 15) * 128;
    MOE_PROLOG();
    const _Float16* asrc[8];
    const _Float16* bsrc[8];
#pragma unroll
    for (int c = 0; c < 8; ++c) {
        int t = perm[base + min(m0 + c * 16 + rrow, ne - 1)];
        asrc[c] = X + (size_t)t * H_ + ksw;
        bsrc[c] = W + ((size_t)e * 2048 + col0 + c * 16 + rrow) * H_ + ksw;
    }
    MOE_KLOOP(H_);
#pragma unroll
    for (int mf = 0; mf < 4; ++mf)
#pragma unroll
        for (int i = 0; i < 4; ++i) {
            int r = m0 + wr * 64 + mf * 16 + g * 4 + i;
            bool ok = r < ne;
            int slot = base + r;
#pragma unroll
            for (int nf = 0; nf < 4; ++nf) {
                int c = col0 + wc * 64 + nf * 16 + l15;
                float v = acc[mf][nf][i] + bias[e * 2048 + c];
                float o = __shfl_xor(v, 1);
                if (ok && !(lane & 1)) {
                    float gt = fminf(v, LIMIT_);
                    float up = fminf(fmaxf(o, -LIMIT_), LIMIT_);
                    float sg = 1.f / (1.f + __expf(-ALPHA_ * gt));
                    gated[(size_t)slot * ED_ + (c >> 1)] = (_Float16)((up + 1.f) * (gt * sg));
                }
            }
        }
}

__global__ __launch_bounds__(256) void k_moe2(const _Float16* __restrict__ G,
                                              const _Float16* __restrict__ W,
                                              const float* __restrict__ bias,
                                              const int* __restrict__ perm,
                                              const float* __restrict__ pw,
                                              const int* __restrict__ counts,
                                              const int* __restrict__ offs,
                                              const int* __restrict__ te,
                                              const int* __restrict__ tm,
                                              const int* __restrict__ ntt,
                                              float* __restrict__ out) {
    const int wg = xcd_swz(blockIdx.x, MAXT_ * 16);
    const int tt = wg >> 4;
    if (tt >= ntt[0]) return;
    const int e = te[tt];
    const int m0 = tm[tt];
    const int ne = counts[e];
    const int base = offs[e];
    const int col0 = (wg & 15) * 128;
    MOE_PROLOG();
    const _Float16* asrc[8];
    const _Float16* bsrc[8];
#pragma unroll
    for (int c = 0; c < 8; ++c) {
        int s = base + min(m0 + c * 16 + rrow, ne - 1);
        asrc[c] = G + (size_t)s * ED_ + ksw;
        bsrc[c] = W + ((size_t)e * H_ + col0 + c * 16 + rrow) * ED_ + ksw;
    }
    MOE_KLOOP(ED_);
#pragma unroll
    for (int mf = 0; mf < 4; ++mf)
#pragma unroll
        for (int i = 0; i < 4; ++i) {
            int r = m0 + wr * 64 + mf * 16 + g * 4 + i;
            if (r >= ne) continue;
            int slot = base + r;
            int tok = perm[slot];
            float wgt = pw[slot];
#pragma unroll
            for (int nf = 0; nf < 4; ++nf) {
                int c = col0 + wc * 64 + nf * 16 + l15;
                atomicAdd(&out[(size_t)tok * H_ + c], wgt * (acc[mf][nf][i] + bias[e * H_ + c]));
            }
        }
}

// ================= conversions =================
__global__ __launch_bounds__(256) void k_cvts_qkv(const float* __restrict__ qw,
                                                  const float* __restrict__ kw,
                                                  const float* __restrict__ vw,
                                                  const float* __restrict__ qb,
                                                  const float* __restrict__ kb,
                                                  const float* __restrict__ vb,
                                                  _Float16* __restrict__ dh,
                                                  _Float16* __restrict__ dl,
                                                  float* __restrict__ biasout) {
    const int r = blockIdx.x;
    const int tid = threadIdx.x;
    const float* src = (r < 2048) ? qw + (size_t)r * H_
                     : (r < 2560) ? kw + (size_t)(r - 2048) * H_
                                  : vw + (size_t)(r - 2560) * H_;
    float4 x = ((const float4*)src)[tid * 2], y = ((const float4*)src)[tid * 2 + 1];
    float xs[8] = {x.x, x.y, x.z, x.w, y.x, y.y, y.z, y.w};
    half8 h, l;
#pragma unroll
    for (int j = 0; j < 8; ++j) {
        _Float16 hv = (_Float16)xs[j];
        h[j] = hv;
        l[j] = (_Float16)((xs[j] - (float)hv) * SPLIT_);
    }
    ((half8*)(dh + (size_t)r * H_))[tid] = h;
    ((half8*)(dl + (size_t)r * H_))[tid] = l;
    if (r < 12) {
        int g = r * 256 + tid;
        if (g < NQKV_) {
            float bv = (g < 2048) ? qb[g] : (g < 2560) ? kb[g - 2048] : vb[g - 2560];
            biasout[g] = bv;
        }
    }
}

__global__ __launch_bounds__(256) void k_cvts(const float* __restrict__ s,
                                              _Float16* __restrict__ dh,
                                              _Float16* __restrict__ dl, int n8) {
    int i = blockIdx.x * 256 + threadIdx.x;
    if (i >= n8) return;
    float4 x = ((const float4*)s)[i * 2], y = ((const float4*)s)[i * 2 + 1];
    float xs[8] = {x.x, x.y, x.z, x.w, y.x, y.y, y.z, y.w};
    half8 h, l;
#pragma unroll
    for (int j = 0; j < 8; ++j) {
        _Float16 hv = (_Float16)xs[j];
        h[j] = hv;
        l[j] = (_Float16)((xs[j] - (float)hv) * SPLIT_);
    }
    ((half8*)dh)[i] = h;
    ((half8*)dl)[i] = l;
}

// transpose-convert: src [e][K][N] fp32 -> dst [e][N][K] f16. 64x64 tiles.
__global__ __launch_bounds__(256) void k_cvt_t(const float* __restrict__ src,
                                               _Float16* __restrict__ dst, int K, int N) {
    const int e = blockIdx.z;
    const int k0 = blockIdx.x * 64, n0 = blockIdx.y * 64;
    __shared__ float t[64][65];
    const int tid = threadIdx.x;
    {
        int kr = tid >> 4, nc = (tid & 15) * 4;
#pragma unroll
        for (int j = 0; j < 4; ++j) {
            float4 v = *(const float4*)(src + ((size_t)e * K + k0 + kr + j * 16) * N + n0 + nc);
            t[kr + j * 16][nc] = v.x; t[kr + j * 16][nc + 1] = v.y;
            t[kr + j * 16][nc + 2] = v.z; t[kr + j * 16][nc + 3] = v.w;
        }
    }
    __syncthreads();
    {
        int nr = tid >> 3, kc = (tid & 7) * 8;
#pragma unroll
        for (int j = 0; j < 2; ++j) {
            int n = nr + j * 32;
            half8 o;
#pragma unroll
            for (int i = 0; i < 8; ++i) o[i] = (_Float16)t[kc + i][n];
            *(half8*)(dst + ((size_t)e * N + n0 + n) * K + k0 + kc) = o;
        }
    }
}

// ================= RMSNorm (split f16 outputs) =================
__global__ __launch_bounds__(256) void k_rmsnorm(const float* __restrict__ x,
                                                 const float* __restrict__ w,
                                                 float* __restrict__ y,
                                                 _Float16* __restrict__ yh,
                                                 _Float16* __restrict__ yl) {
    int t = blockIdx.x;
    const float* row = x + (size_t)t * H_;
    float ss = 0.f;
    for (int i = threadIdx.x; i < H_ / 4; i += 256) {
        float4 v = ((const float4*)row)[i];
        ss += v.x * v.x + v.y * v.y + v.z * v.z + v.w * v.w;
    }
    for (int o = 32; o >= 1; o >>= 1) ss += __shfl_xor(ss, o);
    __shared__ float wsum[4];
    if ((threadIdx.x & 63) == 0) wsum[threadIdx.x >> 6] = ss;
    __syncthreads();
    float tot = wsum[0] + wsum[1] + wsum[2] + wsum[3];
    float r = rsqrtf(tot / (float)H_ + EPS_);
    _Float16* hrow = yh + (size_t)t * H_;
    _Float16* lrow = yl + (size_t)t * H_;
    for (int i = threadIdx.x; i < H_ / 4; i += 256) {
        float4 v = ((const float4*)row)[i];
        float4 g = ((const float4*)w)[i];
        float o4[4];
        o4[0] = v.x * r * g.x; o4[1] = v.y * r * g.y;
        o4[2] = v.z * r * g.z; o4[3] = v.w * r * g.w;
        if (y) ((float4*)(y + (size_t)t * H_))[i] = *(float4*)o4;
        half4v h4, l4;
#pragma unroll
        for (int j = 0; j < 4; ++j) {
            _Float16 hv = (_Float16)o4[j];
            h4[j] = hv;
            l4[j] = (_Float16)((o4[j] - (float)hv) * SPLIT_);
        }
        ((half4v*)hrow)[i] = h4;
        ((half4v*)lrow)[i] = l4;
    }
}

// ======= fused RMSNorm2 + router (fp32-accurate logits, split f16 x out) =======
__global__ __launch_bounds__(256) void k_rms2_router(const float* __restrict__ x,
                                                     const float* __restrict__ w,
                                                     _Float16* __restrict__ yh,
                                                     _Float16* __restrict__ yl,
                                                     const float* __restrict__ rw,
                                                     const float* __restrict__ rb,
                                                     int* __restrict__ topi,
                                                     float* __restrict__ topw) {
    const int t = blockIdx.x;
    const int tid = threadIdx.x;
    const float* row = x + (size_t)t * H_;
    float4 v0 = ((const float4*)row)[tid];
    float4 v1 = ((const float4*)row)[tid + 256];
    float ss = v0.x*v0.x + v0.y*v0.y + v0.z*v0.z + v0.w*v0.w
             + v1.x*v1.x + v1.y*v1.y + v1.z*v1.z + v1.w*v1.w;
    for (int o = 32; o >= 1; o >>= 1) ss += __shfl_xor(ss, o);
    __shared__ float wsum[4];
    if ((tid & 63) == 0) wsum[tid >> 6] = ss;
    __syncthreads();
    float tot = wsum[0] + wsum[1] + wsum[2] + wsum[3];
    float r = rsqrtf(tot / (float)H_ + EPS_);
    float4 g0 = ((const float4*)w)[tid];
    float4 g1 = ((const float4*)w)[tid + 256];
    float o8[8] = {v0.x*r*g0.x, v0.y*r*g0.y, v0.z*r*g0.z, v0.w*r*g0.w,
                   v1.x*r*g1.x, v1.y*r*g1.y, v1.z*r*g1.z, v1.w*r*g1.w};
    _Float16* hrow = yh + (size_t)t * H_;
    _Float16* lrow = yl + (size_t)t * H_;
    {
        half4v h4, l4;
#pragma unroll
        for (int j = 0; j < 4; ++j) {
            _Float16 hv = (_Float16)o8[j];
            h4[j] = hv; l4[j] = (_Float16)((o8[j] - (float)hv) * SPLIT_);
        }
        ((half4v*)hrow)[tid] = h4; ((half4v*)lrow)[tid] = l4;
#pragma unroll
        for (int j = 0; j < 4; ++j) {
            _Float16 hv = (_Float16)o8[4 + j];
            h4[j] = hv; l4[j] = (_Float16)((o8[4 + j] - (float)hv) * SPLIT_);
        }
        ((half4v*)hrow)[tid + 256] = h4; ((half4v*)lrow)[tid + 256] = l4;
    }
    float pe[E_];
#pragma unroll
    for (int e = 0; e < E_; ++e) {
        const float* wr = rw + (size_t)e * H_;
        float4 a = ((const float4*)wr)[tid];
        float4 b = ((const float4*)wr)[tid + 256];
        pe[e] = o8[0]*a.x + o8[1]*a.y + o8[2]*a.z + o8[3]*a.w
              + o8[4]*b.x + o8[5]*b.y + o8[6]*b.z + o8[7]*b.w;
    }
#pragma unroll
    for (int e = 0; e < E_; ++e)
        for (int o = 32; o >= 1; o >>= 1) pe[e] += __shfl_xor(pe[e], o);
    __shared__ float part[4][E_];
    if ((tid & 63) == 0)
#pragma unroll
        for (int e = 0; e < E_; ++e) part[tid >> 6][e] = pe[e];
    __syncthreads();
    __shared__ float logits[E_];
    if (tid < E_) logits[tid] = rb[tid] + part[0][tid] + part[1][tid] + part[2][tid] + part[3][tid];
    __syncthreads();
    if (tid == 0) {
        float tv[4]; int ti4[4];
        unsigned used = 0;
        for (int s3 = 0; s3 < 4; s3++) {
            float best = -3.0e38f; int bi = 0;
            for (int e2 = 0; e2 < E_; e2++)
                if (!((used >> e2) & 1) && logits[e2] > best) { best = logits[e2]; bi = e2; }
            used |= 1u << bi; tv[s3] = best; ti4[s3] = bi;
        }
        float mx = tv[0], pex[4], sum = 0.f;
        for (int s3 = 0; s3 < 4; s3++) { pex[s3] = __expf(tv[s3] - mx); sum += pex[s3]; }
        for (int s3 = 0; s3 < 4; s3++) {
            topw[t * 4 + s3] = pex[s3] / sum;
            topi[t * 4 + s3] = ti4[s3];
        }
    }
}

// ======= fused RoPE (blocks 0..2047) + V transpose-split (blocks 2048..3071) ====
__global__ __launch_bounds__(256) void k_rope_vt(const float* __restrict__ qkv,
                                                 const float* __restrict__ cs,
                                                 const float* __restrict__ sn,
                                                 _Float16* __restrict__ qh, _Float16* __restrict__ ql,
                                                 _Float16* __restrict__ kh, _Float16* __restrict__ kl,
                                                 _Float16* __restrict__ vth, _Float16* __restrict__ vtl) {
    const int bid = blockIdx.x;
    const int tid = threadIdx.x;
    if (bid < T_) {
        int t = bid;
        int b = t >> 10, s = t & 1023;
        size_t cb = (size_t)t * 64;
        const float* rowsrc = qkv + (size_t)t * NQKV_;
        for (int p = tid; p < 40 * 32; p += 256) {
            int head = p >> 5, d = p & 31;
            float c1 = cs[cb + d],      s1v = sn[cb + d];
            float c2 = cs[cb + d + 32], s2v = sn[cb + d + 32];
            float x1, x2; size_t dst;
            _Float16 *oh, *ol;
            if (head < 32) {
                const float* src = rowsrc + head * 64;
                x1 = src[d]; x2 = src[d + 32];
                dst = (((size_t)b * 32 + head) * 1024 + s) * 64 + d;
                oh = qh; ol = ql;
            } else {
                int hk = head - 32;
                const float* src = rowsrc + 2048 + hk * 64;
                x1 = src[d]; x2 = src[d + 32];
                dst = (((size_t)b * 8 + hk) * 1024 + s) * 64 + d;
                oh = kh; ol = kl;
            }
            float r1 = x1 * c1 - x2 * s1v;
            float r2 = x2 * c2 + x1 * s2v;
            _Float16 h1 = (_Float16)r1;
            oh[dst] = h1; ol[dst] = (_Float16)((r1 - (float)h1) * SPLIT_);
            _Float16 h2 = (_Float16)r2;
            oh[dst + 32] = h2; ol[dst + 32] = (_Float16)((r2 - (float)h2) * SPLIT_);
        }
    } else {
        int vb = bid - T_;
        int s0 = (vb & 31) * 32;
        int rest = vb >> 5;
        int d0 = (rest & 1) * 32;
        int bk = rest >> 1;          // b*8 + kvh
        int b = bk >> 3, kvh = bk & 7;
        __shared__ float tl[32][33];
        {
            int sr = tid >> 3, dc = (tid & 7) * 4;
            float4 v = *(const float4*)(qkv + (size_t)(b * 1024 + s0 + sr) * NQKV_ + 2560 + kvh * 64 + d0 + dc);
            tl[sr][dc] = v.x; tl[sr][dc + 1] = v.y; tl[sr][dc + 2] = v.z; tl[sr][dc + 3] = v.w;
        }
        __syncthreads();
        {
            int dr = tid >> 3, sc = (tid & 7) * 4;
            half4v h4, l4;
#pragma unroll
            for (int j = 0; j < 4; ++j) {
                float x = tl[sc + j][dr];
                _Float16 hv = (_Float16)x;
                h4[j] = hv;
                l4[j] = (_Float16)((x - (float)hv) * SPLIT_);
            }
            size_t dst = (size_t)(bk * 64 + d0 + dr) * 1024 + s0 + sc;
            *(half4v*)(vth + dst) = h4;
            *(half4v*)(vtl + dst) = l4;
        }
    }
}

// ================= MFMA flash attention (split-fp16, fp32-accurate) ===========
#define PPITCH 68
union U8h { unsigned w[4]; half8 v; };

__global__ __launch_bounds__(256, 1) void k_attn_m(
        const _Float16* __restrict__ qhg, const _Float16* __restrict__ qlg,
        const _Float16* __restrict__ khg, const _Float16* __restrict__ klg,
        const _Float16* __restrict__ vthg, const _Float16* __restrict__ vtlg,
        const float* __restrict__ sinks,
        _Float16* __restrict__ ath, _Float16* __restrict__ atl) {
    __shared__ _Float16 Khs[4096], Kls[4096], Vhs[4096], Vls[4096];
    __shared__ unsigned Pp[4][64 * PPITCH];
    const int bx = blockIdx.x;
    const int b = bx >> 7, kvh = (bx >> 4) & 7, tile = bx & 15;
    const int i0 = tile * 64;
    const int tid = threadIdx.x, lane = tid & 63, wid = tid >> 6;
    const int l15 = lane & 15, g = lane >> 4;
    const int h = kvh * 4 + wid;
    const size_t kvbase = (size_t)(b * 8 + kvh) * 1024 * 64;
    const size_t vbase  = (size_t)(b * 8 + kvh) * 64 * 1024;
    half8 aqh[4][2], aql[4][2];
    {
        const size_t qb0 = ((size_t)(b * 32 + h) * 1024 + i0) * 64;
#pragma unroll
        for (int mf = 0; mf < 4; ++mf)
#pragma unroll
            for (int ks = 0; ks < 2; ++ks) {
                size_t a = qb0 + (size_t)(16 * mf + l15) * 64 + ks * 32 + g * 8;
                aqh[mf][ks] = *(const half8*)(qhg + a);
                aql[mf][ks] = *(const half8*)(qlg + a);
            }
    }
    floatx4 o1[4][4], o2[4][4];
    float m_run[4][4], l_run[4][4];
#pragma unroll
    for (int mf = 0; mf < 4; ++mf)
#pragma unroll
        for (int x = 0; x < 4; ++x) {
            o1[mf][x] = (floatx4)0.f; o2[mf][x] = (floatx4)0.f;
            m_run[mf][x] = -1e20f; l_run[mf][x] = 0.f;
        }
    const int nch = tile >= 2 ? 3 : tile + 1;
    const int jr = tid >> 3, cc = tid & 7;
    unsigned* pw = &Pp[wid][0];
    for (int ci = 0; ci < nch; ++ci) {
        const int jb = i0 - 64 * (nch - 1 - ci);
        __syncthreads();
        {
            const int sw0 = (cc ^ (jr & 7)) * 8;
            const size_t k0 = kvbase + (size_t)(jb + jr) * 64 + sw0;
            const size_t k1 = kvbase + (size_t)(jb + jr + 32) * 64 + sw0;
            gload16(khg + k0, Khs + tid * 8);
            gload16(khg + k1, Khs + 2048 + tid * 8);
            gload16(klg + k0, Kls + tid * 8);
            gload16(klg + k1, Kls + 2048 + tid * 8);
            const size_t v0 = vbase + (size_t)jr * 1024 + jb + sw0;
            const size_t v1 = vbase + (size_t)(jr + 32) * 1024 + jb + sw0;
            gload16(vthg + v0, Vhs + tid * 8);
            gload16(vthg + v1, Vhs + 2048 + tid * 8);
            gload16(vtlg + v0, Vls + tid * 8);
            gload16(vtlg + v1, Vls + 2048 + tid * 8);
        }
        __syncthreads();
        floatx4 s1[4][4], s2[4][4];
#pragma unroll
        for (int mf = 0; mf < 4; ++mf)
#pragma unroll
            for (int nf = 0; nf < 4; ++nf) { s1[mf][nf] = (floatx4)0.f; s2[mf][nf] = (floatx4)0.f; }
#pragma unroll
        for (int ks = 0; ks < 2; ++ks) {
            half8 kbh[4], kbl[4];
#pragma unroll
            for (int nf = 0; nf < 4; ++nf) {
                int j = l15 + 16 * nf;
                int c = (g + 4 * ks) ^ (j & 7);
                kbh[nf] = *(const half8*)&Khs[j * 64 + c * 8];
                kbl[nf] = *(const half8*)&Kls[j * 64 + c * 8];
            }
#pragma unroll
            for (int mf = 0; mf < 4; ++mf)
#pragma unroll
                for (int nf = 0; nf < 4; ++nf) {
                    s1[mf][nf] = MF16(aqh[mf][ks], kbh[nf], s1[mf][nf]);
                    s2[mf][nf] = MF16(aqh[mf][ks], kbl[nf], s2[mf][nf]);
                    s2[mf][nf] = MF16(aql[mf][ks], kbh[nf], s2[mf][nf]);
                }
        }
#pragma unroll
        for (int mf = 0; mf < 4; ++mf)
#pragma unroll
            for (int reg = 0; reg < 4; ++reg) {
                int i = i0 + 16 * mf + g * 4 + reg;
                float best = -1e30f;
#pragma unroll
                for (int nf = 0; nf < 4; ++nf) {
                    int j = jb + 16 * nf + l15;
                    float sv = (s1[mf][nf][reg] + s2[mf][nf][reg] * INV_SPLIT_) * SCALE_;
                    bool ok = (j <= i) && (i - j < WIN_);
                    sv = ok ? sv : -1e30f;
                    s1[mf][nf][reg] = sv;
                    best = fmaxf(best, sv);
                }
                for (int off = 1; off < 16; off <<= 1) best = fmaxf(best, __shfl_xor(best, off));
                float nm = fmaxf(m_run[mf][reg], best);
                float sc = __expf(m_run[mf][reg] - nm);
                m_run[mf][reg] = nm;
                l_run[mf][reg] *= sc;
#pragma unroll
                for (int nf = 0; nf < 4; ++nf) { o1[mf][nf][reg] *= sc; o2[mf][nf][reg] *= sc; }
            }
#pragma unroll
        for (int mf = 0; mf < 4; ++mf)
#pragma unroll
            for (int nf = 0; nf < 4; ++nf)
#pragma unroll
                for (int reg = 0; reg < 4; ++reg) {
                    float pv = __expf(s1[mf][nf][reg] - m_run[mf][reg]);
                    l_run[mf][reg] += pv;
                    _Float16 hv = (_Float16)pv;
                    _Float16 lv = (_Float16)((pv - (float)hv) * SPLIT_);
                    union { _Float16 h; unsigned short u; } ch, cl;
                    ch.h = hv; cl.h = lv;
                    int t = 16 * mf + g * 4 + reg, jj = l15 + 16 * nf;
                    pw[t * PPITCH + jj] = (unsigned)ch.u | ((unsigned)cl.u << 16);
                }
#pragma unroll
        for (int ks = 0; ks < 2; ++ks) {
            half8 bvh[4], bvl[4];
#pragma unroll
            for (int nf = 0; nf < 4; ++nf) {
                int d = l15 + 16 * nf;
                int c = (g + 4 * ks) ^ (d & 7);
                bvh[nf] = *(const half8*)&Vhs[d * 64 + c * 8];
                bvl[nf] = *(const half8*)&Vls[d * 64 + c * 8];
            }
#pragma unroll
            for (int mf = 0; mf < 4; ++mf) {
                const unsigned* pr = &pw[(16 * mf + l15) * PPITCH + 32 * ks + g * 8];
                int4 va = *(const int4*)pr;
                int4 vb = *(const int4*)(pr + 4);
                U8h ph, pl;
                ph.w[0] = ((unsigned)va.x & 0xffffu) | ((unsigned)va.y << 16);
                ph.w[1] = ((unsigned)va.z & 0xffffu) | ((unsigned)va.w << 16);
                ph.w[2] = ((unsigned)vb.x & 0xffffu) | ((unsigned)vb.y << 16);
                ph.w[3] = ((unsigned)vb.z & 0xffffu) | ((unsigned)vb.w << 16);
                pl.w[0] = ((unsigned)va.x >> 16) | ((unsigned)va.y & 0xffff0000u);
                pl.w[1] = ((unsigned)va.z >> 16) | ((unsigned)va.w & 0xffff0000u);
                pl.w[2] = ((unsigned)vb.x >> 16) | ((unsigned)vb.y & 0xffff0000u);
                pl.w[3] = ((unsigned)vb.z >> 16) | ((unsigned)vb.w & 0xffff0000u);
#pragma unroll
                for (int nf = 0; nf < 4; ++nf) {
                    o1[mf][nf] = MF16(ph.v, bvh[nf], o1[mf][nf]);
                    o2[mf][nf] = MF16(ph.v, bvl[nf], o2[mf][nf]);
                    o2[mf][nf] = MF16(pl.v, bvh[nf], o2[mf][nf]);
                }
            }
        }
    }
    const float sinkv = sinks[h];
    float inv[4][4];
#pragma unroll
    for (int mf = 0; mf < 4; ++mf)
#pragma unroll
        for (int reg = 0; reg < 4; ++reg) {
            float l = l_run[mf][reg];
            for (int off = 1; off < 16; off <<= 1) l += __shfl_xor(l, off);
            inv[mf][reg] = 1.f / (l + __expf(sinkv - m_run[mf][reg]));
        }
#pragma unroll
    for (int mf = 0; mf < 4; ++mf)
#pragma unroll
        for (int nf = 0; nf < 4; ++nf)
#pragma unroll
            for (int reg = 0; reg < 4; ++reg) {
                int t = i0 + 16 * mf + g * 4 + reg;
                int d = l15 + 16 * nf;
                float ov = (o1[mf][nf][reg] + o2[mf][nf][reg] * INV_SPLIT_) * inv[mf][reg];
                size_t idx = ((size_t)(b * 1024 + t) * 32 + h) * 64 + d;
                _Float16 hv = (_Float16)ov;
                ath[idx] = hv;
                atl[idx] = (_Float16)((ov - (float)hv) * SPLIT_);
            }
}

// ======= fused MoE prep: hist + scan + tile table + scatter (one block) =======
__global__ __launch_bounds__(1024) void k_route_build(const int* __restrict__ topi,
                                                      const float* __restrict__ topw,
                                                      int* __restrict__ counts,
                                                      int* __restrict__ offs,
                                                      int* __restrict__ perm,
                                                      float* __restrict__ pw,
                                                      int* __restrict__ te,
                                                      int* __restrict__ tm,
                                                      int* __restrict__ ntt) {
    __shared__ int cnt[E_], cur[E_];
    const int tid = threadIdx.x;
    if (tid < E_) cnt[tid] = 0;
    __syncthreads();
    for (int g = tid; g < T_ * TOPK_; g += 1024) atomicAdd(&cnt[topi[g]], 1);
    __syncthreads();
    if (tid == 0) {
        int run = 0, t = 0;
        for (int e = 0; e < E_; e++) {
            offs[e] = run; cur[e] = run; counts[e] = cnt[e];
            for (int m0 = 0; m0 < cnt[e]; m0 += 128) { te[t] = e; tm[t] = m0; t++; }
            run += cnt[e];
        }
        ntt[0] = t;
    }
    __syncthreads();
    for (int g = tid; g < T_ * TOPK_; g += 1024) {
        int pos = atomicAdd(&cur[topi[g]], 1);
        perm[pos] = g >> 2;
        pw[pos] = topw[g];
    }
}

// ================= launch =================
extern "C" void kernel_launch(void* const* d_in, const int* in_sizes, int n_in,
                              void* d_out, int out_size, void* d_ws, size_t ws_size,
                              hipStream_t stream) {
    const float* hidden = (const float*)d_in[0];
    const float* cosp  = (const float*)d_in[1];
    const float* sinp  = (const float*)d_in[2];
    const float* ln1   = (const float*)d_in[3];
    const float* ln2   = (const float*)d_in[4];
    const float* qw    = (const float*)d_in[5];
    const float* qb    = (const float*)d_in[6];
    const float* kw    = (const float*)d_in[7];
    const float* kbia  = (const float*)d_in[8];
    const float* vw    = (const float*)d_in[9];
    const float* vbia  = (const float*)d_in[10];
    const float* ow    = (const float*)d_in[11];
    const float* ob    = (const float*)d_in[12];
    const float* sinks = (const float*)d_in[13];
    const float* rw    = (const float*)d_in[14];
    const float* rb    = (const float*)d_in[15];
    const float* gup   = (const float*)d_in[16];
    const float* gub   = (const float*)d_in[17];
    const float* dwp   = (const float*)d_in[18];
    const float* dwb   = (const float*)d_in[19];
    float* out = (float*)d_out;

    char* p = (char*)d_ws;
    auto alloc = [&](size_t bytes) { char* r = p; p += (bytes + 255) & ~(size_t)255; return r; };
    _Float16*  xh     = (_Float16*)alloc((size_t)T_ * H_ * 2);
    _Float16*  xl     = (_Float16*)alloc((size_t)T_ * H_ * 2);
    float*     qkvbuf = (float*)alloc((size_t)T_ * NQKV_ * 4);
    _Float16*  ath    = (_Float16*)alloc((size_t)T_ * NH_ * HD_ * 2);
    _Float16*  atl    = (_Float16*)alloc((size_t)T_ * NH_ * HD_ * 2);
    _Float16*  gatedh = (_Float16*)alloc((size_t)T_ * TOPK_ * ED_ * 2);
    _Float16*  qkvwh  = (_Float16*)alloc((size_t)NQKV_ * H_ * 2);
    _Float16*  qkvwl  = (_Float16*)alloc((size_t)NQKV_ * H_ * 2);
    float*     qkvbias= (float*)alloc(NQKV_ * 4);
    _Float16*  owh    = (_Float16*)alloc((size_t)H_ * 2048 * 2);
    _Float16*  owl    = (_Float16*)alloc((size_t)H_ * 2048 * 2);
    _Float16*  gupt   = (_Float16*)alloc((size_t)E_ * 2048 * H_ * 2);
    _Float16*  dwnt   = (_Float16*)alloc((size_t)E_ * H_ * ED_ * 2);
    _Float16*  qhb    = (_Float16*)alloc((size_t)T_ * NH_ * HD_ * 2);
    _Float16*  qlb    = (_Float16*)alloc((size_t)T_ * NH_ * HD_ * 2);
    _Float16*  khb    = (_Float16*)alloc((size_t)T_ * NKV_ * HD_ * 2);
    _Float16*  klb    = (_Float16*)alloc((size_t)T_ * NKV_ * HD_ * 2);
    _Float16*  vthb   = (_Float16*)alloc((size_t)T_ * NKV_ * HD_ * 2);
    _Float16*  vtlb   = (_Float16*)alloc((size_t)T_ * NKV_ * HD_ * 2);
    float*     topw   = (float*)alloc(T_ * TOPK_ * 4);
    float*     pwb    = (float*)alloc(T_ * TOPK_ * 4);
    int*       topi   = (int*)alloc(T_ * TOPK_ * 4);
    int*       perm   = (int*)alloc(T_ * TOPK_ * 4);
    int*       counts = (int*)alloc(E_ * 4);
    int*       offs   = (int*)alloc(E_ * 4);
    int*       te     = (int*)alloc(MAXT_ * 4);
    int*       tm     = (int*)alloc(MAXT_ * 4);
    int*       ntt    = (int*)alloc(4);

    // weight conversions (stacked QKV + O + expert transposes)
    k_cvts_qkv<<<NQKV_, 256, 0, stream>>>(qw, kw, vw, qb, kbia, vbia, qkvwh, qkvwl, qkvbias);
    k_cvts<<<2048, 256, 0, stream>>>(ow, owh, owl, H_ * 2048 / 8);
    k_cvt_t<<<dim3(H_ / 64, 2048 / 64, E_), 256, 0, stream>>>(gup, gupt, H_, 2048);
    k_cvt_t<<<dim3(ED_ / 64, H_ / 64, E_), 256, 0, stream>>>(dwp, dwnt, ED_, H_);

    k_rmsnorm<<<T_, 256, 0, stream>>>(hidden, ln1, nullptr, xh, xl);
    // fused QKV: init with stacked bias, split-K=2 GEMM (768 blocks = 2/CU)
    k_initc<<<(T_ * NQKV_ / 4 + 255) / 256, 256, 0, stream>>>(qkvbias, nullptr, qkvbuf, NQKV_, T_ * NQKV_ / 4);
    k_gemm_spk2<<<768, 256, 0, stream>>>(xh, xl, qkvwh, qkvwl, qkvbuf, NQKV_, H_);
    k_rope_vt<<<T_ + 1024, 256, 0, stream>>>(qkvbuf, cosp, sinp, qhb, qlb, khb, klb, vthb, vtlb);
    k_attn_m<<<256, 256, 0, stream>>>(qhb, qlb, khb, klb, vthb, vtlb, sinks, ath, atl);
    // O-proj: out = hidden + ob + attn @ ow^T (init + split-K=2 atomic)
    k_initc<<<4096, 256, 0, stream>>>(ob, hidden, out, 2048, T_ * 2048 / 4);
    k_gemm_spk2<<<512, 256, 0, stream>>>(ath, atl, owh, owl, out, 2048, H_);
    // fused RMSNorm2 + router
    k_rms2_router<<<T_, 256, 0, stream>>>(out, ln2, xh, xl, rw, rb, topi, topw);
    k_route_build<<<1, 1024, 0, stream>>>(topi, topw, counts, offs, perm, pwb, te, tm, ntt);
    k_moe1<<<MAXT_ * 16, 256, 0, stream>>>(xh, gupt, gub, perm, counts, offs, te, tm, ntt, gatedh);
    k_moe2<<<MAXT_ * 16, 256, 0, stream>>>(gatedh, dwnt, dwb, perm, pwb, counts, offs, te, tm, ntt, out);
}